// Round 1
// baseline (1414.386 us; speedup 1.0000x reference)
//
#include <hip/hip_runtime.h>
#include <hip/hip_bf16.h>

// ================= problem constants =================
#define BB 8
#define NN 1024
#define HH 768
#define NHD 12
#define ASZ 64
#define MM 256
#define QSCALE 0.125f   // AS^-0.5
#define NSLOPE 0.02f

// ============ workspace layout (float offsets) ============
#define OFF_Q     ((size_t)0)
#define OFF_KK    (OFF_Q  + (size_t)BB*NN*HH)
#define OFF_VV    (OFF_KK + (size_t)BB*NN*HH)
#define OFF_SRAW  (OFF_VV + (size_t)BB*NN*HH)
#define OFF_DIAG  (OFF_SRAW + (size_t)BB*NN)
#define OFF_BIAS4 (OFF_DIAG + (size_t)BB*NN)          // float4 aligned (offset%4==0)
#define OFF_PLIST (OFF_BIAS4 + (size_t)BB*NN*4)
#define OFF_PCNT  (OFF_PLIST + (size_t)BB*NN)
#define OFF_SUMW  (OFF_PCNT + (size_t)BB)
#define OFF_Z     (OFF_SUMW + (size_t)BB)
#define OFF_T     (OFF_Z + (size_t)2*BB*HH)
#define OFF_PM    (OFF_T + (size_t)2*BB*HH)

__device__ __forceinline__ float lrelu(float v) { return v >= 0.f ? v : NSLOPE * v; }

template<int CTRL>
__device__ __forceinline__ float dppf(float x) {  // quad_perm DPP (VALU cross-lane, no LDS pipe)
  return __int_as_float(__builtin_amdgcn_mov_dpp(__float_as_int(x), CTRL, 0xF, 0xF, true));
}

// weights for the final weighted row-sums of y (derived from pm algebra).
// c2[j]: coefficient of y[j] in sum_i w_i * y'_i ; c1[j]: in sum_i w_i * var_y'_i
__device__ __forceinline__ void coefs(const int* ppb, int j, float& c1, float& c2) {
  auto pred = [&](int tt) { return tt >= 0 && tt < NN && ppb[tt] == 1; };
  auto single = [&](int tt) { return tt == 0 || (tt >= 2 && ppb[tt - 2] == 1); };
  auto wgt = [&](int tt) {
    if (!pred(tt)) return 0.f;
    bool tri = (tt >= 1) && (tt <= 1 || !single(tt));
    return tri ? 3.f : 2.f;
  };
  float a = 0.f;
  if (pred(j + 1)) a += wgt(j + 1) * (single(j + 1) ? 0.f : 0.5f);
  if (j >= 1 && pred(j - 1)) a += wgt(j - 1) * (single(j - 1) ? 1.f : 0.5f);
  c1 = a;
  c2 = wgt(j);
}

// ============ K_pred: compact predicate list + sum of weights ============
__global__ void k_pred(const int* __restrict__ pp, int* __restrict__ plist,
                       int* __restrict__ pcnt, float* __restrict__ sumw) {
  int b = blockIdx.x;
  int lane = threadIdx.x;  // blockDim 64 (one wave)
  const int* ppb = pp + b * NN;
  int base = 0;
  float wacc = 0.f;
  for (int c = 0; c < NN; c += 64) {
    int i = c + lane;
    bool isp = ppb[i] == 1;
    unsigned long long mask = __ballot(isp);
    if (isp) {
      int pos = base + __popcll(mask & ((1ull << lane) - 1ull));
      plist[b * NN + pos] = i;
      bool sing = (i == 0) || (i >= 2 && ppb[i - 2] == 1);
      bool tri = (i >= 1) && (i <= 1 || !sing);
      wacc += tri ? 3.f : 2.f;
    }
    base += __popcll(mask);
  }
  for (int off = 32; off; off >>= 1) wacc += __shfl_xor(wacc, off);
  if (lane == 0) { pcnt[b] = base; sumw[b] = wacc; }
}

// ============ K_cross: occurrence-pair scores -> diag (VG^2 is diagonal) ============
__global__ void k_cross(const float* __restrict__ x, const int* __restrict__ occ,
                        const float* __restrict__ Wc, const float* __restrict__ bc,
                        float* __restrict__ diag) {
  int g = blockIdx.x * 4 + (threadIdx.x >> 6);  // (b,m) pair id, 4 waves/block
  int lane = threadIdx.x & 63;
  int b = g >> 8, m = g & (MM - 1);
  int o0 = occ[(b * MM + m) * 2 + 0];
  int o1 = occ[(b * MM + m) * 2 + 1];
  const float* x0 = x + (size_t)(b * NN + o0) * HH;
  const float* x1 = x + (size_t)(b * NN + o1) * HH;
  float acc = 0.f;
  for (int d = lane; d < HH; d += 64) acc += 0.5f * (x0[d] + x1[d]) * Wc[d];
  for (int off = 32; off; off >>= 1) acc += __shfl_xor(acc, off);
  if (lane == 0) {
    float sc = lrelu(acc + bc[0]);
    float sq = sc * sc;
    diag[b * NN + o0] = sq;  // pairs are disjoint (permutation) -> plain store
    diag[b * NN + o1] = sq;
  }
}

// ============ K_score: fused skinny GEMM over gathered predicate rows ============
// mode 0: A-row = var_in(i) @ W_var ; mode 1: A-row = x[i] @ W_sym.
// epilogue: tanh(feat + b) . wscore  -> atomic partial into s_raw[b][i]
__global__ __launch_bounds__(256) void k_score(
    const float* __restrict__ x, const int* __restrict__ pp,
    const int* __restrict__ plist, const int* __restrict__ pcnt,
    const float* __restrict__ W, const float* __restrict__ bvec,
    const float* __restrict__ wsc, float* __restrict__ s_raw, int mode) {
  const int b = blockIdx.z;
  const int cnt = pcnt[b];
  const int j0 = blockIdx.y * 128;
  if (j0 >= cnt) return;
  const int n0 = blockIdx.x * 128;
  __shared__ float Xs[16][128];
  __shared__ float Ws_[16][128];
  __shared__ float red[128];
  const int t = threadIdx.x;
  const int tm = t & 15, tn = t >> 4;
  const int ml = t >> 1, kh = (t & 1) * 8;
  float acc[2][4][2][4] = {};
  int j = j0 + ml;
  bool valid = j < cnt;
  int i = 2;
  if (valid) i = plist[b * NN + j];
  bool sing = (i == 0) || (i >= 2 && pp[b * NN + i - 2] == 1);
  const float* xb = x + (size_t)b * NN * HH;
  const float* rA; const float* rB; float wAc, wBc;
  if (mode == 0) {
    rA = xb + (size_t)((i - 1 + NN) % NN) * HH + kh;  // roll semantics
    rB = xb + (size_t)((i + 1) % NN) * HH + kh;
    wAc = sing ? 0.f : 0.5f; wBc = sing ? 1.f : 0.5f;
  } else {
    rA = xb + (size_t)i * HH + kh; rB = rA; wAc = 0.f; wBc = 1.f;
  }
  const float* Wg = W + (size_t)(n0 + ml) * HH + kh;
  for (int k0 = 0; k0 < HH; k0 += 16) {
    float4 pa = *(const float4*)(rA + k0);
    float4 pb = *(const float4*)(rA + k0 + 4);
    float4 qa = *(const float4*)(rB + k0);
    float4 qb = *(const float4*)(rB + k0 + 4);
    float4 wa = *(const float4*)(Wg + k0);
    float4 wb = *(const float4*)(Wg + k0 + 4);
    __syncthreads();
    Xs[kh+0][ml] = wAc*pa.x + wBc*qa.x; Xs[kh+1][ml] = wAc*pa.y + wBc*qa.y;
    Xs[kh+2][ml] = wAc*pa.z + wBc*qa.z; Xs[kh+3][ml] = wAc*pa.w + wBc*qa.w;
    Xs[kh+4][ml] = wAc*pb.x + wBc*qb.x; Xs[kh+5][ml] = wAc*pb.y + wBc*qb.y;
    Xs[kh+6][ml] = wAc*pb.z + wBc*qb.z; Xs[kh+7][ml] = wAc*pb.w + wBc*qb.w;
    Ws_[kh+0][ml] = wa.x; Ws_[kh+1][ml] = wa.y; Ws_[kh+2][ml] = wa.z; Ws_[kh+3][ml] = wa.w;
    Ws_[kh+4][ml] = wb.x; Ws_[kh+5][ml] = wb.y; Ws_[kh+6][ml] = wb.z; Ws_[kh+7][ml] = wb.w;
    __syncthreads();
#pragma unroll
    for (int k = 0; k < 16; ++k) {
      float4 a0 = *(const float4*)&Xs[k][tm * 4];
      float4 a1 = *(const float4*)&Xs[k][64 + tm * 4];
      float4 b0 = *(const float4*)&Ws_[k][tn * 4];
      float4 b1 = *(const float4*)&Ws_[k][64 + tn * 4];
      float av[2][4] = {{a0.x,a0.y,a0.z,a0.w},{a1.x,a1.y,a1.z,a1.w}};
      float bv[2][4] = {{b0.x,b0.y,b0.z,b0.w},{b1.x,b1.y,b1.z,b1.w}};
#pragma unroll
      for (int rh = 0; rh < 2; ++rh)
#pragma unroll
        for (int u = 0; u < 4; ++u)
#pragma unroll
          for (int ch = 0; ch < 2; ++ch)
#pragma unroll
            for (int vv = 0; vv < 4; ++vv)
              acc[rh][u][ch][vv] += av[rh][u] * bv[ch][vv];
    }
  }
  __syncthreads();
  if (t < 128) red[t] = 0.f;
  __syncthreads();
  float4 bb0 = *(const float4*)(bvec + n0 + tn * 4);
  float4 bb1 = *(const float4*)(bvec + n0 + 64 + tn * 4);
  float4 w0 = *(const float4*)(wsc + n0 + tn * 4);
  float4 w1 = *(const float4*)(wsc + n0 + 64 + tn * 4);
#pragma unroll
  for (int rh = 0; rh < 2; ++rh)
#pragma unroll
    for (int u = 0; u < 4; ++u) {
      float p = tanhf(acc[rh][u][0][0] + bb0.x) * w0.x + tanhf(acc[rh][u][0][1] + bb0.y) * w0.y
              + tanhf(acc[rh][u][0][2] + bb0.z) * w0.z + tanhf(acc[rh][u][0][3] + bb0.w) * w0.w
              + tanhf(acc[rh][u][1][0] + bb1.x) * w1.x + tanhf(acc[rh][u][1][1] + bb1.y) * w1.y
              + tanhf(acc[rh][u][1][2] + bb1.z) * w1.z + tanhf(acc[rh][u][1][3] + bb1.w) * w1.w;
      atomicAdd(&red[rh * 64 + tm * 4 + u], p);
    }
  __syncthreads();
  if (t < 128) {
    int j2 = j0 + t;
    if (j2 < cnt) atomicAdd(&s_raw[b * NN + plist[b * NN + j2]], red[t]);
  }
}

// ============ K_bias: per-row sparse bias window (AG' 3-col window + VG^2 diag) ============
__global__ void k_bias(const int* __restrict__ pp, const float* __restrict__ s_raw,
                       const float* __restrict__ diag, const float* __restrict__ b_score,
                       float4* __restrict__ bias4) {
  int g = blockIdx.x * 256 + threadIdx.x;  // B*N rows
  int b = g >> 10, r = g & (NN - 1);
  const int* ppb = pp + b * NN;
  int i = -1;
  if (ppb[r] == 1) i = r;
  else if (r + 1 < NN && ppb[r + 1] == 1) i = r + 1;
  else if (r >= 1 && ppb[r - 1] == 1) i = r - 1;
  float v0 = 0.f, v1 = 0.f, v2 = 0.f; int cw = r;
  if (i >= 1 && i + 1 < NN) {
    float s = lrelu(s_raw[b * NN + i] + b_score[0]);
    float s2 = s * s;
    cw = i - 1;
    if (i == r) { v0 = 0.2f * s; v1 = 1.6f * s2; v2 = 0.2f * s; }
    else       { v0 = 0.8f * s2; v1 = 0.2f * s; v2 = 0.8f * s2; }
  }
  int slot = r - cw;
  float d = diag[g];
  if (slot == 0) v0 += d; else if (slot == 1) v1 += d; else v2 += d;
  bias4[g] = make_float4(__int_as_float(cw), v0, v1, v2);
}

// ============ K_gemm: C = (X @ W^T + bias) * alpha  (fp32, 128x128x16 tiles) ============
__global__ __launch_bounds__(256) void k_gemm(const float* __restrict__ X, const float* __restrict__ W,
                                              const float* __restrict__ bias, float* __restrict__ C,
                                              float alpha) {
  __shared__ float Xs[16][128];
  __shared__ float Ws_[16][128];
  const int m0 = blockIdx.x * 128, n0 = blockIdx.y * 128;
  const int t = threadIdx.x;
  const int tm = t & 15, tn = t >> 4;
  const int ml = t >> 1, kh = (t & 1) * 8;
  float acc[2][4][2][4] = {};
  const float* Xg = X + (size_t)(m0 + ml) * HH + kh;
  const float* Wg = W + (size_t)(n0 + ml) * HH + kh;
  for (int k0 = 0; k0 < HH; k0 += 16) {
    float4 xa = *(const float4*)(Xg + k0);
    float4 xb = *(const float4*)(Xg + k0 + 4);
    float4 wa = *(const float4*)(Wg + k0);
    float4 wb = *(const float4*)(Wg + k0 + 4);
    __syncthreads();
    Xs[kh+0][ml] = xa.x; Xs[kh+1][ml] = xa.y; Xs[kh+2][ml] = xa.z; Xs[kh+3][ml] = xa.w;
    Xs[kh+4][ml] = xb.x; Xs[kh+5][ml] = xb.y; Xs[kh+6][ml] = xb.z; Xs[kh+7][ml] = xb.w;
    Ws_[kh+0][ml] = wa.x; Ws_[kh+1][ml] = wa.y; Ws_[kh+2][ml] = wa.z; Ws_[kh+3][ml] = wa.w;
    Ws_[kh+4][ml] = wb.x; Ws_[kh+5][ml] = wb.y; Ws_[kh+6][ml] = wb.z; Ws_[kh+7][ml] = wb.w;
    __syncthreads();
#pragma unroll
    for (int k = 0; k < 16; ++k) {
      float4 a0 = *(const float4*)&Xs[k][tm * 4];
      float4 a1 = *(const float4*)&Xs[k][64 + tm * 4];
      float4 b0 = *(const float4*)&Ws_[k][tn * 4];
      float4 b1 = *(const float4*)&Ws_[k][64 + tn * 4];
      float av[2][4] = {{a0.x,a0.y,a0.z,a0.w},{a1.x,a1.y,a1.z,a1.w}};
      float bv[2][4] = {{b0.x,b0.y,b0.z,b0.w},{b1.x,b1.y,b1.z,b1.w}};
#pragma unroll
      for (int rh = 0; rh < 2; ++rh)
#pragma unroll
        for (int u = 0; u < 4; ++u)
#pragma unroll
          for (int ch = 0; ch < 2; ++ch)
#pragma unroll
            for (int vv = 0; vv < 4; ++vv)
              acc[rh][u][ch][vv] += av[rh][u] * bv[ch][vv];
    }
  }
#pragma unroll
  for (int ch = 0; ch < 2; ++ch) {
    float4 bb = *(const float4*)(bias + n0 + ch * 64 + tn * 4);
#pragma unroll
    for (int rh = 0; rh < 2; ++rh)
#pragma unroll
      for (int u = 0; u < 4; ++u) {
        int m = m0 + rh * 64 + tm * 4 + u;
        float4 o;
        o.x = (acc[rh][u][ch][0] + bb.x) * alpha;
        o.y = (acc[rh][u][ch][1] + bb.y) * alpha;
        o.z = (acc[rh][u][ch][2] + bb.z) * alpha;
        o.w = (acc[rh][u][ch][3] + bb.w) * alpha;
        *(float4*)(C + (size_t)m * HH + n0 + ch * 64 + tn * 4) = o;
      }
  }
}

// ============ K_attn: flash attention + sparse bias, emits weighted row-sums z1/z2 ============
#define PV_Q(QQ, CTRL)                                                          \
  { _Pragma("unroll")                                                           \
    for (int idx = 0; idx < 16; ++idx) {                                        \
      float pa = dppf<CTRL>(p0[idx]);                                           \
      float pb = dppf<CTRL>(p1[idx]);                                           \
      const float* vrow = &Vs[QQ * 16 + idx][cq * 16];                          \
      _Pragma("unroll")                                                         \
      for (int dd4 = 0; dd4 < 4; ++dd4) {                                       \
        float4 vv4 = *(const float4*)(vrow + dd4 * 4);                          \
        y0[dd4*4+0] += pa*vv4.x; y0[dd4*4+1] += pa*vv4.y;                       \
        y0[dd4*4+2] += pa*vv4.z; y0[dd4*4+3] += pa*vv4.w;                       \
        y1[dd4*4+0] += pb*vv4.x; y1[dd4*4+1] += pb*vv4.y;                       \
        y1[dd4*4+2] += pb*vv4.z; y1[dd4*4+3] += pb*vv4.w;                       \
      } } }

__global__ __launch_bounds__(128) void k_attn(const float* __restrict__ qg, const float* __restrict__ kg,
                                              const float* __restrict__ vg, const float4* __restrict__ bias4,
                                              const int* __restrict__ pp, float* __restrict__ zz) {
  __shared__ float Qs[64][64];
  __shared__ float Ks[64][64];
  __shared__ float Vs[64][64];
  const int rb = blockIdx.x, h = blockIdx.y, b = blockIdx.z;
  const int n0 = rb * 64;
  const int t = threadIdx.x;
  const int w = t >> 6, lane = t & 63;
  const int rpair = lane >> 2, cq = lane & 3;
  const int r0 = w * 32 + rpair * 2, r1 = r0 + 1;
  const float* qb = qg + (size_t)(b * NN + n0) * HH + h * ASZ;
  const float* kb = kg + (size_t)b * NN * HH + h * ASZ;
  const float* vb = vg + (size_t)b * NN * HH + h * ASZ;
  // stage Q (XOR-swizzled by row for conflict-free b128 reads)
  for (int fi = t; fi < 1024; fi += 128) {
    int row = fi >> 4, q4 = fi & 15;
    float4 val = *(const float4*)(qb + (size_t)row * HH + q4 * 4);
    *(float4*)&Qs[row][(q4 ^ ((row >> 1) & 7)) * 4] = val;
  }
  float4 bz0 = bias4[b * NN + n0 + r0];
  float4 bz1 = bias4[b * NN + n0 + r1];
  const int cw0 = __float_as_int(bz0.x), cw1 = __float_as_int(bz1.x);
  float mr0 = -1e30f, mr1 = -1e30f, lr0 = 0.f, lr1 = 0.f;
  float y0[16], y1[16];
#pragma unroll
  for (int d = 0; d < 16; ++d) { y0[d] = 0.f; y1[d] = 0.f; }

  for (int tile = 0; tile < 16; ++tile) {
    const int c0 = tile * 64;
    __syncthreads();
    for (int fi = t; fi < 1024; fi += 128) {
      int row = fi >> 4, q4 = fi & 15;
      float4 kv = *(const float4*)(kb + (size_t)(c0 + row) * HH + q4 * 4);
      *(float4*)&Ks[row][(q4 ^ ((row >> 4) & 3)) * 4] = kv;
      float4 vv4 = *(const float4*)(vb + (size_t)(c0 + row) * HH + q4 * 4);
      *(float4*)&Vs[row][q4 * 4] = vv4;
    }
    __syncthreads();
    float p0[16], p1[16];
#pragma unroll
    for (int ci = 0; ci < 16; ++ci) { p0[ci] = 0.f; p1[ci] = 0.f; }
    const int qsw = (r0 >> 1) & 7;
    for (int d4 = 0; d4 < 16; ++d4) {
      float4 qa = *(const float4*)&Qs[r0][(d4 ^ qsw) * 4];
      float4 qc = *(const float4*)&Qs[r1][(d4 ^ qsw) * 4];
#pragma unroll
      for (int ci = 0; ci < 16; ++ci) {
        float4 ka = *(const float4*)&Ks[cq * 16 + ci][(d4 ^ cq) * 4];
        p0[ci] += qa.x * ka.x + qa.y * ka.y + qa.z * ka.z + qa.w * ka.w;
        p1[ci] += qc.x * ka.x + qc.y * ka.y + qc.z * ka.z + qc.w * ka.w;
      }
    }
    // sparse bias (3-col window per row)
#pragma unroll
    for (int ci = 0; ci < 16; ++ci) {
      int c = c0 + cq * 16 + ci;
      int d0 = c - cw0;
      if (d0 >= 0 && d0 < 3) p0[ci] += (d0 == 0) ? bz0.y : (d0 == 1 ? bz0.z : bz0.w);
      int d1 = c - cw1;
      if (d1 >= 0 && d1 < 3) p1[ci] += (d1 == 0) ? bz1.y : (d1 == 1 ? bz1.z : bz1.w);
    }
    // online softmax (rows split over 4 lanes -> quad_perm reductions)
    float t0 = p0[0], t1v = p1[0];
#pragma unroll
    for (int ci = 1; ci < 16; ++ci) { t0 = fmaxf(t0, p0[ci]); t1v = fmaxf(t1v, p1[ci]); }
    t0 = fmaxf(t0, dppf<0xB1>(t0)); t0 = fmaxf(t0, dppf<0x4E>(t0));
    t1v = fmaxf(t1v, dppf<0xB1>(t1v)); t1v = fmaxf(t1v, dppf<0x4E>(t1v));
    float mn0 = fmaxf(mr0, t0), mn1 = fmaxf(mr1, t1v);
    float f0 = __expf(mr0 - mn0), f1 = __expf(mr1 - mn1);
    mr0 = mn0; mr1 = mn1;
    float s0 = 0.f, s1 = 0.f;
#pragma unroll
    for (int ci = 0; ci < 16; ++ci) {
      p0[ci] = __expf(p0[ci] - mn0); s0 += p0[ci];
      p1[ci] = __expf(p1[ci] - mn1); s1 += p1[ci];
    }
    s0 += dppf<0xB1>(s0); s0 += dppf<0x4E>(s0);
    s1 += dppf<0xB1>(s1); s1 += dppf<0x4E>(s1);
    lr0 = lr0 * f0 + s0; lr1 = lr1 * f1 + s1;
#pragma unroll
    for (int d = 0; d < 16; ++d) { y0[d] *= f0; y1[d] *= f1; }
    PV_Q(0, 0x00) PV_Q(1, 0x55) PV_Q(2, 0xAA) PV_Q(3, 0xFF)
  }
  // epilogue: weighted row-sum contributions -> z1,z2 (atomic, small count)
  float inv0 = 1.f / lr0, inv1 = 1.f / lr1;
  float c1a, c2a, c1b, c2b;
  coefs(pp + b * NN, n0 + r0, c1a, c2a);
  coefs(pp + b * NN, n0 + r1, c1b, c2b);
  float a1[16], a2[16];
#pragma unroll
  for (int d = 0; d < 16; ++d) {
    float ya = y0[d] * inv0, yb = y1[d] * inv1;
    a1[d] = c1a * ya + c1b * yb;
    a2[d] = c2a * ya + c2b * yb;
  }
#pragma unroll
  for (int mask = 4; mask <= 32; mask <<= 1) {
#pragma unroll
    for (int d = 0; d < 16; ++d) {
      a1[d] += __shfl_xor(a1[d], mask);
      a2[d] += __shfl_xor(a2[d], mask);
    }
  }
  if (rpair == 0) {
    float* z1 = zz + b * HH + h * ASZ + cq * 16;
    float* z2 = zz + BB * HH + b * HH + h * ASZ + cq * 16;
#pragma unroll
    for (int d = 0; d < 16; ++d) {
      atomicAdd(&z1[d], a1[d]);
      atomicAdd(&z2[d], a2[d]);
    }
  }
}

// ============ F1: t_s = W_o @ (z_s / sumw) + b_o ============
__global__ void k_f1(const float* __restrict__ Wo, const float* __restrict__ bo,
                     const float* __restrict__ zz, const float* __restrict__ sumw,
                     float* __restrict__ tvec) {
  int b = blockIdx.y;
  int w = threadIdx.x >> 6, lane = threadIdx.x & 63;
  float inv = 1.f / sumw[b];
  const float* z1 = zz + b * HH;
  const float* z2 = zz + BB * HH + b * HH;
  float zr1[12], zr2[12];
#pragma unroll
  for (int m = 0; m < 12; ++m) { zr1[m] = z1[lane + 64 * m] * inv; zr2[m] = z2[lane + 64 * m] * inv; }
  for (int j = 0; j < 8; ++j) {
    int o = blockIdx.x * 32 + w * 8 + j;
    const float* wrow = Wo + (size_t)o * HH;
    float a1 = 0.f, a2 = 0.f;
#pragma unroll
    for (int m = 0; m < 12; ++m) { float wv = wrow[lane + 64 * m]; a1 += wv * zr1[m]; a2 += wv * zr2[m]; }
    for (int mask = 32; mask; mask >>= 1) { a1 += __shfl_xor(a1, mask); a2 += __shfl_xor(a2, mask); }
    if (lane == 0) { tvec[b * HH + o] = a1 + bo[o]; tvec[BB * HH + b * HH + o] = a2 + bo[o]; }
  }
}

// ============ F2: pm = WL @ t1 + WR @ t2 + b_atom ============
__global__ void k_f2(const float* __restrict__ Wa, const float* __restrict__ ba,
                     const float* __restrict__ tvec, float* __restrict__ pm) {
  int b = blockIdx.y;
  int w = threadIdx.x >> 6, lane = threadIdx.x & 63;
  const float* t1 = tvec + b * HH;
  const float* t2 = tvec + BB * HH + b * HH;
  float r1[12], r2[12];
#pragma unroll
  for (int m = 0; m < 12; ++m) { r1[m] = t1[lane + 64 * m]; r2[m] = t2[lane + 64 * m]; }
  for (int j = 0; j < 8; ++j) {
    int o = blockIdx.x * 32 + w * 8 + j;
    const float* wrow = Wa + (size_t)o * (2 * HH);
    float a = 0.f;
#pragma unroll
    for (int m = 0; m < 12; ++m) a += wrow[lane + 64 * m] * r1[m];
#pragma unroll
    for (int m = 0; m < 12; ++m) a += wrow[HH + lane + 64 * m] * r2[m];
    for (int mask = 32; mask; mask >>= 1) a += __shfl_xor(a, mask);
    if (lane == 0) pm[b * HH + o] = a + ba[o];
  }
}

// ============ F3: broadcast pm to (B,N,H) ============
__global__ void k_bcast(const float* __restrict__ pm, float* __restrict__ out) {
  size_t g = (size_t)blockIdx.x * 256 + threadIdx.x;  // one float4 each
  int b = (int)(g / ((size_t)NN * HH / 4));
  int hh4 = (int)(g % (HH / 4));
  float4 val = *(const float4*)(pm + b * HH + hh4 * 4);
  *(float4*)(out + g * 4) = val;
}

// ================= launcher =================
extern "C" void kernel_launch(void* const* d_in, const int* in_sizes, int n_in,
                              void* d_out, int out_size, void* d_ws, size_t ws_size,
                              hipStream_t stream) {
  (void)in_sizes; (void)n_in; (void)out_size; (void)ws_size;
  const float* x       = (const float*)d_in[0];
  const float* W_var   = (const float*)d_in[3];
  const float* b_var   = (const float*)d_in[4];
  const float* W_sym   = (const float*)d_in[5];
  const float* b_sym   = (const float*)d_in[6];
  const float* W_score = (const float*)d_in[7];
  const float* b_score = (const float*)d_in[8];
  const float* W_cross = (const float*)d_in[9];
  const float* b_cross = (const float*)d_in[10];
  const float* W_atom  = (const float*)d_in[11];
  const float* b_atom  = (const float*)d_in[12];
  const float* W_q     = (const float*)d_in[13];
  const float* b_q     = (const float*)d_in[14];
  const float* W_k     = (const float*)d_in[15];
  const float* b_k     = (const float*)d_in[16];
  const float* W_v     = (const float*)d_in[17];
  const float* b_v     = (const float*)d_in[18];
  const float* W_o     = (const float*)d_in[19];
  const float* b_o     = (const float*)d_in[20];
  const int*   pp      = (const int*)d_in[21];
  const int*   occ     = (const int*)d_in[24];
  float* out = (float*)d_out;
  float* ws = (float*)d_ws;
  float* q    = ws + OFF_Q;
  float* kk   = ws + OFF_KK;
  float* vv   = ws + OFF_VV;
  float* sraw = ws + OFF_SRAW;
  float* diag = ws + OFF_DIAG;
  float4* bias4 = (float4*)(ws + OFF_BIAS4);
  int* plist = (int*)(ws + OFF_PLIST);
  int* pcnt  = (int*)(ws + OFF_PCNT);
  float* sumw = ws + OFF_SUMW;
  float* zz   = ws + OFF_Z;
  float* tv   = ws + OFF_T;
  float* pm   = ws + OFF_PM;

  hipMemsetAsync(sraw, 0, BB * NN * sizeof(float), stream);
  hipMemsetAsync(diag, 0, BB * NN * sizeof(float), stream);
  hipMemsetAsync(zz, 0, 2 * BB * HH * sizeof(float), stream);

  k_pred<<<BB, 64, 0, stream>>>(pp, plist, pcnt, sumw);
  k_score<<<dim3(6, 8, BB), 256, 0, stream>>>(x, pp, plist, pcnt, W_var, b_var, W_score, sraw, 0);
  k_score<<<dim3(6, 8, BB), 256, 0, stream>>>(x, pp, plist, pcnt, W_sym, b_sym, W_score + HH, sraw, 1);
  k_cross<<<BB * MM / 4, 256, 0, stream>>>(x, occ, W_cross, b_cross, diag);
  k_bias<<<BB * NN / 256, 256, 0, stream>>>(pp, sraw, diag, b_score, bias4);
  k_gemm<<<dim3(64, 6), 256, 0, stream>>>(x, W_q, b_q, q, QSCALE);
  k_gemm<<<dim3(64, 6), 256, 0, stream>>>(x, W_k, b_k, kk, 1.f);
  k_gemm<<<dim3(64, 6), 256, 0, stream>>>(x, W_v, b_v, vv, 1.f);
  k_attn<<<dim3(16, NHD, BB), 128, 0, stream>>>(q, kk, vv, bias4, pp, zz);
  k_f1<<<dim3(24, BB), 256, 0, stream>>>(W_o, b_o, zz, sumw, tv);
  k_f2<<<dim3(24, BB), 256, 0, stream>>>(W_atom, b_atom, tv, pm);
  k_bcast<<<BB * NN * HH / 1024, 256, 0, stream>>>(pm, out);
}

// Round 3
// 550.345 us; speedup vs baseline: 2.5700x; 2.5700x over previous
//
#include <hip/hip_runtime.h>
#include <hip/hip_bf16.h>

// ================= problem constants =================
#define BB 8
#define NN 1024
#define HH 768
#define NHD 12
#define ASZ 64
#define MM 256
#define QSCALE 0.125f   // AS^-0.5
#define NSLOPE 0.02f

typedef __attribute__((ext_vector_type(8))) short bf16x8;
typedef __attribute__((ext_vector_type(4))) float f32x4;

// ============ workspace layout (byte offsets, all 16B-aligned) ============
#define OFFB_QB    ((size_t)0)            // 8*1024*768 bf16 = 12582912 B
#define OFFB_KB    ((size_t)12582912)
#define OFFB_VB    ((size_t)25165824)
#define OFFB_XB    ((size_t)37748736)     // x in bf16
#define OFFB_WQB   ((size_t)50331648)     // 768*768 bf16 = 1179648 B
#define OFFB_WKB   ((size_t)51511296)
#define OFFB_WVB   ((size_t)52690944)
#define OFFB_SRAW  ((size_t)53870592)     // 8192 f32
#define OFFB_DIAG  ((size_t)53903360)     // 8192 f32
#define OFFB_BIAS4 ((size_t)53936128)     // 8192 float4
#define OFFB_PLIST ((size_t)54067200)     // 8192 i32
#define OFFB_PCNT  ((size_t)54099968)
#define OFFB_SUMW  ((size_t)54100000)
#define OFFB_ZZ    ((size_t)54100032)     // 2*8*768 f32
#define OFFB_TV    ((size_t)54149184)
#define OFFB_PM    ((size_t)54198336)

__device__ __forceinline__ float lrelu(float v) { return v >= 0.f ? v : NSLOPE * v; }

__device__ __forceinline__ ushort f2bf(float f) {  // RNE f32->bf16
  union { float f; unsigned u; } v; v.f = f;
  unsigned r = (v.u + 0x7fffu + ((v.u >> 16) & 1u)) >> 16;
  return (ushort)r;
}

// weights for the final weighted row-sums of y (derived from pm algebra).
__device__ __forceinline__ void coefs(const int* ppb, int j, float& c1, float& c2) {
  auto pred = [&](int tt) { return tt >= 0 && tt < NN && ppb[tt] == 1; };
  auto single = [&](int tt) { return tt == 0 || (tt >= 2 && ppb[tt - 2] == 1); };
  auto wgt = [&](int tt) {
    if (!pred(tt)) return 0.f;
    bool tri = (tt >= 1) && (tt <= 1 || !single(tt));
    return tri ? 3.f : 2.f;
  };
  float a = 0.f;
  if (pred(j + 1)) a += wgt(j + 1) * (single(j + 1) ? 0.f : 0.5f);
  if (j >= 1 && pred(j - 1)) a += wgt(j - 1) * (single(j - 1) ? 1.f : 0.5f);
  c1 = a;
  c2 = wgt(j);
}

// ============ K_cvt: f32 -> bf16 (vectorized) ============
__global__ void k_cvt(const float* __restrict__ src, ushort* __restrict__ dst, int n4) {
  int i = blockIdx.x * 256 + threadIdx.x;
  if (i >= n4) return;
  float4 v = ((const float4*)src)[i];
  ushort4 o;
  o.x = f2bf(v.x); o.y = f2bf(v.y); o.z = f2bf(v.z); o.w = f2bf(v.w);
  ((ushort4*)dst)[i] = o;
}

// ============ K_pred: compact predicate list + sum of weights ============
__global__ void k_pred(const int* __restrict__ pp, int* __restrict__ plist,
                       int* __restrict__ pcnt, float* __restrict__ sumw) {
  int b = blockIdx.x;
  int lane = threadIdx.x;  // blockDim 64
  const int* ppb = pp + b * NN;
  int base = 0;
  float wacc = 0.f;
  for (int c = 0; c < NN; c += 64) {
    int i = c + lane;
    bool isp = ppb[i] == 1;
    unsigned long long mask = __ballot(isp);
    if (isp) {
      int pos = base + __popcll(mask & ((1ull << lane) - 1ull));
      plist[b * NN + pos] = i;
      bool sing = (i == 0) || (i >= 2 && ppb[i - 2] == 1);
      bool tri = (i >= 1) && (i <= 1 || !sing);
      wacc += tri ? 3.f : 2.f;
    }
    base += __popcll(mask);
  }
  for (int off = 32; off; off >>= 1) wacc += __shfl_xor(wacc, off);
  if (lane == 0) { pcnt[b] = base; sumw[b] = wacc; }
}

// ============ K_cross: occurrence-pair scores -> diag ============
__global__ void k_cross(const float* __restrict__ x, const int* __restrict__ occ,
                        const float* __restrict__ Wc, const float* __restrict__ bc,
                        float* __restrict__ diag) {
  int g = blockIdx.x * 4 + (threadIdx.x >> 6);
  int lane = threadIdx.x & 63;
  int b = g >> 8, m = g & (MM - 1);
  int o0 = occ[(b * MM + m) * 2 + 0];
  int o1 = occ[(b * MM + m) * 2 + 1];
  const float* x0 = x + (size_t)(b * NN + o0) * HH;
  const float* x1 = x + (size_t)(b * NN + o1) * HH;
  float acc = 0.f;
  for (int d = lane; d < HH; d += 64) acc += 0.5f * (x0[d] + x1[d]) * Wc[d];
  for (int off = 32; off; off >>= 1) acc += __shfl_xor(acc, off);
  if (lane == 0) {
    float sc = lrelu(acc + bc[0]);
    float sq = sc * sc;
    diag[b * NN + o0] = sq;
    diag[b * NN + o1] = sq;
  }
}

// ============ K_score: fused skinny GEMM over gathered predicate rows (fp32) ============
__global__ __launch_bounds__(256) void k_score(
    const float* __restrict__ x, const int* __restrict__ pp,
    const int* __restrict__ plist, const int* __restrict__ pcnt,
    const float* __restrict__ W, const float* __restrict__ bvec,
    const float* __restrict__ wsc, float* __restrict__ s_raw, int mode) {
  const int b = blockIdx.z;
  const int cnt = pcnt[b];
  const int j0 = blockIdx.y * 128;
  if (j0 >= cnt) return;
  const int n0 = blockIdx.x * 128;
  __shared__ float Xs[16][128];
  __shared__ float Ws_[16][128];
  __shared__ float red[128];
  const int t = threadIdx.x;
  const int tm = t & 15, tn = t >> 4;
  const int ml = t >> 1, kh = (t & 1) * 8;
  float acc[2][4][2][4] = {};
  int j = j0 + ml;
  bool valid = j < cnt;
  int i = 2;
  if (valid) i = plist[b * NN + j];
  bool sing = (i == 0) || (i >= 2 && pp[b * NN + i - 2] == 1);
  const float* xb = x + (size_t)b * NN * HH;
  const float* rA; const float* rB; float wAc, wBc;
  if (mode == 0) {
    rA = xb + (size_t)((i - 1 + NN) % NN) * HH + kh;
    rB = xb + (size_t)((i + 1) % NN) * HH + kh;
    wAc = sing ? 0.f : 0.5f; wBc = sing ? 1.f : 0.5f;
  } else {
    rA = xb + (size_t)i * HH + kh; rB = rA; wAc = 0.f; wBc = 1.f;
  }
  const float* Wg = W + (size_t)(n0 + ml) * HH + kh;
  for (int k0 = 0; k0 < HH; k0 += 16) {
    float4 pa = *(const float4*)(rA + k0);
    float4 pb = *(const float4*)(rA + k0 + 4);
    float4 qa = *(const float4*)(rB + k0);
    float4 qb = *(const float4*)(rB + k0 + 4);
    float4 wa = *(const float4*)(Wg + k0);
    float4 wb = *(const float4*)(Wg + k0 + 4);
    __syncthreads();
    Xs[kh+0][ml] = wAc*pa.x + wBc*qa.x; Xs[kh+1][ml] = wAc*pa.y + wBc*qa.y;
    Xs[kh+2][ml] = wAc*pa.z + wBc*qa.z; Xs[kh+3][ml] = wAc*pa.w + wBc*qa.w;
    Xs[kh+4][ml] = wAc*pb.x + wBc*qb.x; Xs[kh+5][ml] = wAc*pb.y + wBc*qb.y;
    Xs[kh+6][ml] = wAc*pb.z + wBc*qb.z; Xs[kh+7][ml] = wAc*pb.w + wBc*qb.w;
    Ws_[kh+0][ml] = wa.x; Ws_[kh+1][ml] = wa.y; Ws_[kh+2][ml] = wa.z; Ws_[kh+3][ml] = wa.w;
    Ws_[kh+4][ml] = wb.x; Ws_[kh+5][ml] = wb.y; Ws_[kh+6][ml] = wb.z; Ws_[kh+7][ml] = wb.w;
    __syncthreads();
#pragma unroll
    for (int k = 0; k < 16; ++k) {
      float4 a0 = *(const float4*)&Xs[k][tm * 4];
      float4 a1 = *(const float4*)&Xs[k][64 + tm * 4];
      float4 b0 = *(const float4*)&Ws_[k][tn * 4];
      float4 b1 = *(const float4*)&Ws_[k][64 + tn * 4];
      float av[2][4] = {{a0.x,a0.y,a0.z,a0.w},{a1.x,a1.y,a1.z,a1.w}};
      float bv[2][4] = {{b0.x,b0.y,b0.z,b0.w},{b1.x,b1.y,b1.z,b1.w}};
#pragma unroll
      for (int rh = 0; rh < 2; ++rh)
#pragma unroll
        for (int u = 0; u < 4; ++u)
#pragma unroll
          for (int ch = 0; ch < 2; ++ch)
#pragma unroll
            for (int vv = 0; vv < 4; ++vv)
              acc[rh][u][ch][vv] += av[rh][u] * bv[ch][vv];
    }
  }
  __syncthreads();
  if (t < 128) red[t] = 0.f;
  __syncthreads();
  float4 bb0 = *(const float4*)(bvec + n0 + tn * 4);
  float4 bb1 = *(const float4*)(bvec + n0 + 64 + tn * 4);
  float4 w0 = *(const float4*)(wsc + n0 + tn * 4);
  float4 w1 = *(const float4*)(wsc + n0 + 64 + tn * 4);
#pragma unroll
  for (int rh = 0; rh < 2; ++rh)
#pragma unroll
    for (int u = 0; u < 4; ++u) {
      float p = tanhf(acc[rh][u][0][0] + bb0.x) * w0.x + tanhf(acc[rh][u][0][1] + bb0.y) * w0.y
              + tanhf(acc[rh][u][0][2] + bb0.z) * w0.z + tanhf(acc[rh][u][0][3] + bb0.w) * w0.w
              + tanhf(acc[rh][u][1][0] + bb1.x) * w1.x + tanhf(acc[rh][u][1][1] + bb1.y) * w1.y
              + tanhf(acc[rh][u][1][2] + bb1.z) * w1.z + tanhf(acc[rh][u][1][3] + bb1.w) * w1.w;
      atomicAdd(&red[rh * 64 + tm * 4 + u], p);
    }
  __syncthreads();
  if (t < 128) {
    int j2 = j0 + t;
    if (j2 < cnt) atomicAdd(&s_raw[b * NN + plist[b * NN + j2]], red[t]);
  }
}

// ============ K_bias: per-row sparse bias window ============
__global__ void k_bias(const int* __restrict__ pp, const float* __restrict__ s_raw,
                       const float* __restrict__ diag, const float* __restrict__ b_score,
                       float4* __restrict__ bias4) {
  int g = blockIdx.x * 256 + threadIdx.x;
  int b = g >> 10, r = g & (NN - 1);
  const int* ppb = pp + b * NN;
  int i = -1;
  if (ppb[r] == 1) i = r;
  else if (r + 1 < NN && ppb[r + 1] == 1) i = r + 1;
  else if (r >= 1 && ppb[r - 1] == 1) i = r - 1;
  float v0 = 0.f, v1 = 0.f, v2 = 0.f; int cw = r;
  if (i >= 1 && i + 1 < NN) {
    float s = lrelu(s_raw[b * NN + i] + b_score[0]);
    float s2 = s * s;
    cw = i - 1;
    if (i == r) { v0 = 0.2f * s; v1 = 1.6f * s2; v2 = 0.2f * s; }
    else       { v0 = 0.8f * s2; v1 = 0.2f * s; v2 = 0.8f * s2; }
  }
  int slot = r - cw;
  float d = diag[g];
  if (slot == 0) v0 += d; else if (slot == 1) v1 += d; else v2 += d;
  bias4[g] = make_float4(__int_as_float(cw), v0, v1, v2);
}

// ============ K_gemm_bf: fused QKV bf16 MFMA GEMM ============
// C_z = (Xb @ W_z^T + bias_z) * alpha_z, bf16 out. 128x128 tile, BK=64, 4 waves (2x2).
__global__ __launch_bounds__(256, 2) void k_gemm_bf(
    const ushort* __restrict__ X,
    const ushort* __restrict__ W0, const ushort* __restrict__ W1, const ushort* __restrict__ W2,
    const float* __restrict__ b0, const float* __restrict__ b1, const float* __restrict__ b2,
    ushort* __restrict__ C0, ushort* __restrict__ C1, ushort* __restrict__ C2) {
  const int z = blockIdx.z;
  const ushort* W = z == 0 ? W0 : (z == 1 ? W1 : W2);
  const float* bias = z == 0 ? b0 : (z == 1 ? b1 : b2);
  ushort* C = z == 0 ? C0 : (z == 1 ? C1 : C2);
  const float alpha = z == 0 ? QSCALE : 1.f;
  __shared__ ushort As[128 * 64];
  __shared__ ushort Bs[128 * 64];
  const int m0 = blockIdx.x * 128, n0 = blockIdx.y * 128;
  const int t = threadIdx.x;
  const int w = t >> 6, lane = t & 63, lg = lane >> 4, lm = lane & 15;
  const int wm = (w >> 1) * 64, wn = (w & 1) * 64;
  f32x4 acc[4][4] = {};
  for (int k0 = 0; k0 < HH; k0 += 64) {
    __syncthreads();
#pragma unroll
    for (int it = 0; it < 4; ++it) {   // 128 rows x 8 chunks = 1024 slots = 4 x 256
      int slot = t + it * 256;
      int row = slot >> 3, c = slot & 7;
      uint4 va = *(const uint4*)(X + (size_t)(m0 + row) * HH + k0 + c * 8);
      *(uint4*)&As[row * 64 + ((c ^ (row & 7)) * 8)] = va;
      uint4 vb = *(const uint4*)(W + (size_t)(n0 + row) * HH + k0 + c * 8);
      *(uint4*)&Bs[row * 64 + ((c ^ (row & 7)) * 8)] = vb;
    }
    __syncthreads();
    bf16x8 af[4][2], bfr[4][2];
#pragma unroll
    for (int mt = 0; mt < 4; ++mt)
#pragma unroll
      for (int kt = 0; kt < 2; ++kt) {
        int row = wm + mt * 16 + lm, ch = lg + kt * 4;
        af[mt][kt] = *(bf16x8*)&As[row * 64 + ((ch ^ (row & 7)) * 8)];
      }
#pragma unroll
    for (int nt = 0; nt < 4; ++nt)
#pragma unroll
      for (int kt = 0; kt < 2; ++kt) {
        int row = wn + nt * 16 + lm, ch = lg + kt * 4;
        bfr[nt][kt] = *(bf16x8*)&Bs[row * 64 + ((ch ^ (row & 7)) * 8)];
      }
#pragma unroll
    for (int mt = 0; mt < 4; ++mt)
#pragma unroll
      for (int nt = 0; nt < 4; ++nt)
#pragma unroll
        for (int kt = 0; kt < 2; ++kt)
          acc[mt][nt] = __builtin_amdgcn_mfma_f32_16x16x32_bf16(af[mt][kt], bfr[nt][kt], acc[mt][nt], 0, 0, 0);
  }
#pragma unroll
  for (int nt = 0; nt < 4; ++nt) {
    int col = n0 + wn + nt * 16 + lm;
    float bcol = bias[col];
#pragma unroll
    for (int mt = 0; mt < 4; ++mt)
#pragma unroll
      for (int r = 0; r < 4; ++r) {
        int row = m0 + wm + mt * 16 + lg * 4 + r;
        C[(size_t)row * HH + col] = f2bf((acc[mt][nt][r] + bcol) * alpha);
      }
  }
}

// ============ K_attn2: bf16 MFMA flash attention + sparse bias -> z1/z2 ============
// 4 waves x 16 q-rows; KVBLK=64; K swizzled row-major, V swizzled-transposed,
// P routed through per-wave swizzled LDS (C-layout -> A-layout).
__global__ __launch_bounds__(256, 4) void k_attn2(
    const ushort* __restrict__ qg, const ushort* __restrict__ kg, const ushort* __restrict__ vg,
    const float4* __restrict__ bias4, const int* __restrict__ pp, float* __restrict__ zz) {
  __shared__ ushort Ks[64 * 64];
  __shared__ ushort Vt[64 * 64];
  __shared__ ushort Pl[4][16 * 64];
  const int rb = blockIdx.x, h = blockIdx.y, b = blockIdx.z;
  const int n0 = rb * 64;
  const int t = threadIdx.x, w = t >> 6, lane = t & 63, lg = lane >> 4, lm = lane & 15;
  const int qbase = n0 + w * 16;
  const ushort* qrow = qg + (size_t)(b * NN + qbase + lm) * HH + h * ASZ;
  bf16x8 qf[2];
  qf[0] = *(const bf16x8*)(qrow + lg * 8);
  qf[1] = *(const bf16x8*)(qrow + lg * 8 + 32);
  int cw[4]; float bw[4][3];
#pragma unroll
  for (int r = 0; r < 4; ++r) {
    float4 bz = bias4[b * NN + qbase + lg * 4 + r];
    cw[r] = __float_as_int(bz.x); bw[r][0] = bz.y; bw[r][1] = bz.z; bw[r][2] = bz.w;
  }
  float mr[4] = {-1e30f, -1e30f, -1e30f, -1e30f};
  float lr[4] = {0.f, 0.f, 0.f, 0.f};
  f32x4 y[4] = {};
  const ushort* kb = kg + (size_t)(b * NN) * HH + h * ASZ;
  const ushort* vb = vg + (size_t)(b * NN) * HH + h * ASZ;
  for (int tile = 0; tile < 16; ++tile) {
    const int c0 = tile * 64;
    __syncthreads();
#pragma unroll
    for (int it = 0; it < 2; ++it) {
      int slot = t + it * 256;
      int row = slot >> 3, c = slot & 7;
      uint4 kv = *(const uint4*)(kb + (size_t)(c0 + row) * HH + c * 8);
      *(uint4*)&Ks[row * 64 + ((c ^ (row & 7)) * 8)] = kv;
      uint4 vv = *(const uint4*)(vb + (size_t)(c0 + row) * HH + c * 8);
      const ushort* pv = (const ushort*)&vv;
#pragma unroll
      for (int j = 0; j < 8; ++j) {
        int d = c * 8 + j;
        Vt[d * 64 + (((row >> 3) ^ (d & 7)) * 8) + (row & 7)] = pv[j];
      }
    }
    __syncthreads();
    f32x4 s[4] = {};
#pragma unroll
    for (int nt = 0; nt < 4; ++nt) {
      int krow = lm + nt * 16, sw = krow & 7;
#pragma unroll
      for (int kt = 0; kt < 2; ++kt) {
        bf16x8 kf = *(bf16x8*)&Ks[krow * 64 + (((lg + kt * 4) ^ sw) * 8)];
        s[nt] = __builtin_amdgcn_mfma_f32_16x16x32_bf16(qf[kt], kf, s[nt], 0, 0, 0);
      }
    }
    // sparse bias windows
#pragma unroll
    for (int nt = 0; nt < 4; ++nt) {
      int kcol = c0 + nt * 16 + lm;
#pragma unroll
      for (int r = 0; r < 4; ++r) {
        int dd = kcol - cw[r];
        if (dd >= 0 && dd < 3) s[nt][r] += bw[r][dd];
      }
    }
    // online softmax (reduce over lm lanes; row = lg*4+r)
    float f[4], ts[4];
#pragma unroll
    for (int r = 0; r < 4; ++r) {
      float tm = fmaxf(fmaxf(s[0][r], s[1][r]), fmaxf(s[2][r], s[3][r]));
      tm = fmaxf(tm, __shfl_xor(tm, 1));
      tm = fmaxf(tm, __shfl_xor(tm, 2));
      tm = fmaxf(tm, __shfl_xor(tm, 4));
      tm = fmaxf(tm, __shfl_xor(tm, 8));
      float mn = fmaxf(mr[r], tm);
      f[r] = __expf(mr[r] - mn);
      mr[r] = mn;
      ts[r] = 0.f;
    }
#pragma unroll
    for (int nt = 0; nt < 4; ++nt)
#pragma unroll
      for (int r = 0; r < 4; ++r) {
        float p = __expf(s[nt][r] - mr[r]);
        s[nt][r] = p; ts[r] += p;
      }
#pragma unroll
    for (int r = 0; r < 4; ++r) {
      float v = ts[r];
      v += __shfl_xor(v, 1); v += __shfl_xor(v, 2);
      v += __shfl_xor(v, 4); v += __shfl_xor(v, 8);
      lr[r] = lr[r] * f[r] + v;
    }
#pragma unroll
    for (int nt = 0; nt < 4; ++nt)
#pragma unroll
      for (int r = 0; r < 4; ++r) y[nt][r] *= f[r];
    // P: C-layout -> per-wave swizzled LDS -> A-layout
#pragma unroll
    for (int nt = 0; nt < 4; ++nt)
#pragma unroll
      for (int r = 0; r < 4; ++r) {
        int prow = lg * 4 + r, pcol = lm + nt * 16;
        Pl[w][prow * 64 + (((pcol >> 3) ^ (prow & 7)) * 8) + (pcol & 7)] = f2bf(s[nt][r]);
      }
    asm volatile("s_waitcnt lgkmcnt(0)" ::: "memory");
    __builtin_amdgcn_sched_barrier(0);
    bf16x8 pa[2];
#pragma unroll
    for (int kt = 0; kt < 2; ++kt)
      pa[kt] = *(bf16x8*)&Pl[w][lm * 64 + (((lg + kt * 4) ^ (lm & 7)) * 8)];
#pragma unroll
    for (int nt = 0; nt < 4; ++nt) {
      int vrow = lm + nt * 16, sw = vrow & 7;
#pragma unroll
      for (int kt = 0; kt < 2; ++kt) {
        bf16x8 vf = *(bf16x8*)&Vt[vrow * 64 + (((lg + kt * 4) ^ sw) * 8)];
        y[nt] = __builtin_amdgcn_mfma_f32_16x16x32_bf16(pa[kt], vf, y[nt], 0, 0, 0);
      }
    }
  }
  // epilogue: weighted row-sums into z1/z2
  float inv[4], c1v[4], c2v[4];
#pragma unroll
  for (int r = 0; r < 4; ++r) {
    inv[r] = 1.f / lr[r];
    coefs(pp + b * NN, qbase + lg * 4 + r, c1v[r], c2v[r]);
  }
  float a1[4], a2[4];
#pragma unroll
  for (int nt = 0; nt < 4; ++nt) {
    float u1 = 0.f, u2 = 0.f;
#pragma unroll
    for (int r = 0; r < 4; ++r) {
      float yv = y[nt][r] * inv[r];
      u1 += c1v[r] * yv;
      u2 += c2v[r] * yv;
    }
    u1 += __shfl_xor(u1, 16); u1 += __shfl_xor(u1, 32);
    u2 += __shfl_xor(u2, 16); u2 += __shfl_xor(u2, 32);
    a1[nt] = u1; a2[nt] = u2;
  }
  if (lg == 0) {
#pragma unroll
    for (int nt = 0; nt < 4; ++nt) {
      atomicAdd(&zz[b * HH + h * ASZ + nt * 16 + lm], a1[nt]);
      atomicAdd(&zz[BB * HH + b * HH + h * ASZ + nt * 16 + lm], a2[nt]);
    }
  }
}

// ============ F1: t_s = W_o @ (z_s / sumw) + b_o ============
__global__ void k_f1(const float* __restrict__ Wo, const float* __restrict__ bo,
                     const float* __restrict__ zz, const float* __restrict__ sumw,
                     float* __restrict__ tvec) {
  int b = blockIdx.y;
  int w = threadIdx.x >> 6, lane = threadIdx.x & 63;
  float inv = 1.f / sumw[b];
  const float* z1 = zz + b * HH;
  const float* z2 = zz + BB * HH + b * HH;
  float zr1[12], zr2[12];
#pragma unroll
  for (int m = 0; m < 12; ++m) { zr1[m] = z1[lane + 64 * m] * inv; zr2[m] = z2[lane + 64 * m] * inv; }
  for (int j = 0; j < 8; ++j) {
    int o = blockIdx.x * 32 + w * 8 + j;
    const float* wrow = Wo + (size_t)o * HH;
    float a1 = 0.f, a2 = 0.f;
#pragma unroll
    for (int m = 0; m < 12; ++m) { float wv = wrow[lane + 64 * m]; a1 += wv * zr1[m]; a2 += wv * zr2[m]; }
    for (int mask = 32; mask; mask >>= 1) { a1 += __shfl_xor(a1, mask); a2 += __shfl_xor(a2, mask); }
    if (lane == 0) { tvec[b * HH + o] = a1 + bo[o]; tvec[BB * HH + b * HH + o] = a2 + bo[o]; }
  }
}

// ============ F2: pm = WL @ t1 + WR @ t2 + b_atom ============
__global__ void k_f2(const float* __restrict__ Wa, const float* __restrict__ ba,
                     const float* __restrict__ tvec, float* __restrict__ pm) {
  int b = blockIdx.y;
  int w = threadIdx.x >> 6, lane = threadIdx.x & 63;
  const float* t1 = tvec + b * HH;
  const float* t2 = tvec + BB * HH + b * HH;
  float r1[12], r2[12];
#pragma unroll
  for (int m = 0; m < 12; ++m) { r1[m] = t1[lane + 64 * m]; r2[m] = t2[lane + 64 * m]; }
  for (int j = 0; j < 8; ++j) {
    int o = blockIdx.x * 32 + w * 8 + j;
    const float* wrow = Wa + (size_t)o * (2 * HH);
    float a = 0.f;
#pragma unroll
    for (int m = 0; m < 12; ++m) a += wrow[lane + 64 * m] * r1[m];
#pragma unroll
    for (int m = 0; m < 12; ++m) a += wrow[HH + lane + 64 * m] * r2[m];
    for (int mask = 32; mask; mask >>= 1) a += __shfl_xor(a, mask);
    if (lane == 0) pm[b * HH + o] = a + ba[o];
  }
}

// ============ F3: broadcast pm to (B,N,H) ============
__global__ void k_bcast(const float* __restrict__ pm, float* __restrict__ out) {
  size_t g = (size_t)blockIdx.x * 256 + threadIdx.x;
  int b = (int)(g / ((size_t)NN * HH / 4));
  int hh4 = (int)(g % (HH / 4));
  float4 val = *(const float4*)(pm + b * HH + hh4 * 4);
  *(float4*)(out + g * 4) = val;
}

// ================= launcher =================
extern "C" void kernel_launch(void* const* d_in, const int* in_sizes, int n_in,
                              void* d_out, int out_size, void* d_ws, size_t ws_size,
                              hipStream_t stream) {
  (void)in_sizes; (void)n_in; (void)out_size; (void)ws_size;
  const float* x       = (const float*)d_in[0];
  const float* W_var   = (const float*)d_in[3];
  const float* b_var   = (const float*)d_in[4];
  const float* W_sym   = (const float*)d_in[5];
  const float* b_sym   = (const float*)d_in[6];
  const float* W_score = (const float*)d_in[7];
  const float* b_score = (const float*)d_in[8];
  const float* W_cross = (const float*)d_in[9];
  const float* b_cross = (const float*)d_in[10];
  const float* W_atom  = (const float*)d_in[11];
  const float* b_atom  = (const float*)d_in[12];
  const float* W_q     = (const float*)d_in[13];
  const float* b_q     = (const float*)d_in[14];
  const float* W_k     = (const float*)d_in[15];
  const float* b_k     = (const float*)d_in[16];
  const float* W_v     = (const float*)d_in[17];
  const float* b_v     = (const float*)d_in[18];
  const float* W_o     = (const float*)d_in[19];
  const float* b_o     = (const float*)d_in[20];
  const int*   pp      = (const int*)d_in[21];
  const int*   occ     = (const int*)d_in[24];
  float* out = (float*)d_out;
  char* wsb = (char*)d_ws;
  ushort* qb  = (ushort*)(wsb + OFFB_QB);
  ushort* kbf = (ushort*)(wsb + OFFB_KB);
  ushort* vbf = (ushort*)(wsb + OFFB_VB);
  ushort* xb  = (ushort*)(wsb + OFFB_XB);
  ushort* wqb = (ushort*)(wsb + OFFB_WQB);
  ushort* wkb = (ushort*)(wsb + OFFB_WKB);
  ushort* wvb = (ushort*)(wsb + OFFB_WVB);
  float* sraw = (float*)(wsb + OFFB_SRAW);
  float* diag = (float*)(wsb + OFFB_DIAG);
  float4* bias4 = (float4*)(wsb + OFFB_BIAS4);
  int* plist = (int*)(wsb + OFFB_PLIST);
  int* pcnt  = (int*)(wsb + OFFB_PCNT);
  float* sumw = (float*)(wsb + OFFB_SUMW);
  float* zz   = (float*)(wsb + OFFB_ZZ);
  float* tv   = (float*)(wsb + OFFB_TV);
  float* pm   = (float*)(wsb + OFFB_PM);

  hipMemsetAsync(sraw, 0, BB * NN * sizeof(float), stream);
  hipMemsetAsync(diag, 0, BB * NN * sizeof(float), stream);
  hipMemsetAsync(zz, 0, 2 * BB * HH * sizeof(float), stream);

  k_pred<<<BB, 64, 0, stream>>>(pp, plist, pcnt, sumw);
  // f32 -> bf16 conversions
  k_cvt<<<(BB * NN * HH / 4 + 255) / 256, 256, 0, stream>>>(x, xb, BB * NN * HH / 4);
  k_cvt<<<(HH * HH / 4 + 255) / 256, 256, 0, stream>>>(W_q, wqb, HH * HH / 4);
  k_cvt<<<(HH * HH / 4 + 255) / 256, 256, 0, stream>>>(W_k, wkb, HH * HH / 4);
  k_cvt<<<(HH * HH / 4 + 255) / 256, 256, 0, stream>>>(W_v, wvb, HH * HH / 4);
  // score path (fp32)
  k_score<<<dim3(6, 8, BB), 256, 0, stream>>>(x, pp, plist, pcnt, W_var, b_var, W_score, sraw, 0);
  k_score<<<dim3(6, 8, BB), 256, 0, stream>>>(x, pp, plist, pcnt, W_sym, b_sym, W_score + HH, sraw, 1);
  k_cross<<<BB * MM / 4, 256, 0, stream>>>(x, occ, W_cross, b_cross, diag);
  k_bias<<<BB * NN / 256, 256, 0, stream>>>(pp, sraw, diag, b_score, bias4);
  // fused QKV MFMA GEMM (bf16)
  k_gemm_bf<<<dim3(64, 6, 3), 256, 0, stream>>>(xb, wqb, wkb, wvb, b_q, b_k, b_v, qb, kbf, vbf);
  // MFMA flash attention
  k_attn2<<<dim3(16, NHD, BB), 256, 0, stream>>>(qb, kbf, vbf, bias4, pp, zz);
  k_f1<<<dim3(24, BB), 256, 0, stream>>>(W_o, b_o, zz, sumw, tv);
  k_f2<<<dim3(24, BB), 256, 0, stream>>>(W_atom, b_atom, tv, pm);
  k_bcast<<<BB * NN * HH / 1024, 256, 0, stream>>>(pm, out);
}

// Round 4
// 307.511 us; speedup vs baseline: 4.5995x; 1.7897x over previous
//
#include <hip/hip_runtime.h>
#include <hip/hip_bf16.h>

// ================= problem constants =================
#define BB 8
#define NN 1024
#define HH 768
#define NHD 12
#define ASZ 64
#define MM 256
#define QSCALE 0.125f   // AS^-0.5
#define NSLOPE 0.02f

typedef __attribute__((ext_vector_type(8))) short bf16x8;
typedef __attribute__((ext_vector_type(4))) float f32x4;

// ============ workspace layout (byte offsets, all 16B-aligned) ============
#define OFFB_QB    ((size_t)0)            // 8*1024*768 bf16
#define OFFB_KB    ((size_t)12582912)
#define OFFB_VB    ((size_t)25165824)
#define OFFB_XB    ((size_t)37748736)     // x in bf16
#define OFFB_WQB   ((size_t)50331648)     // 768*768 bf16
#define OFFB_WKB   ((size_t)51511296)
#define OFFB_WVB   ((size_t)52690944)
#define OFFB_WVAR  ((size_t)53870592)     // W_var bf16
#define OFFB_WSYM  ((size_t)55050240)     // W_sym bf16
#define OFFB_SRAW  ((size_t)56229888)     // 8192 f32
#define OFFB_DIAG  ((size_t)56262656)     // 8192 f32
#define OFFB_BIAS4 ((size_t)56295424)     // 8192 float4
#define OFFB_PLIST ((size_t)56426496)     // 8192 i32
#define OFFB_PCNT  ((size_t)56459264)
#define OFFB_SUMW  ((size_t)56459296)
#define OFFB_ZZ    ((size_t)56459328)     // 2*8*768 f32
#define OFFB_TV    ((size_t)56508480)
#define OFFB_PM    ((size_t)56557632)

__device__ __forceinline__ float lrelu(float v) { return v >= 0.f ? v : NSLOPE * v; }

__device__ __forceinline__ ushort f2bf(float f) {  // RNE f32->bf16
  union { float f; unsigned u; } v; v.f = f;
  unsigned r = (v.u + 0x7fffu + ((v.u >> 16) & 1u)) >> 16;
  return (ushort)r;
}
__device__ __forceinline__ float bf2f(ushort u) {
  union { unsigned u; float f; } v; v.u = (unsigned)u << 16;
  return v.f;
}

// weights for the final weighted row-sums of y (derived from pm algebra).
__device__ __forceinline__ void coefs(const int* ppb, int j, float& c1, float& c2) {
  auto pred = [&](int tt) { return tt >= 0 && tt < NN && ppb[tt] == 1; };
  auto single = [&](int tt) { return tt == 0 || (tt >= 2 && ppb[tt - 2] == 1); };
  auto wgt = [&](int tt) {
    if (!pred(tt)) return 0.f;
    bool tri = (tt >= 1) && (tt <= 1 || !single(tt));
    return tri ? 3.f : 2.f;
  };
  float a = 0.f;
  if (pred(j + 1)) a += wgt(j + 1) * (single(j + 1) ? 0.f : 0.5f);
  if (j >= 1 && pred(j - 1)) a += wgt(j - 1) * (single(j - 1) ? 1.f : 0.5f);
  c1 = a;
  c2 = wgt(j);
}

// ============ K_cvt: f32 -> bf16 (vectorized) ============
__global__ void k_cvt(const float* __restrict__ src, ushort* __restrict__ dst, int n4) {
  int i = blockIdx.x * 256 + threadIdx.x;
  if (i >= n4) return;
  float4 v = ((const float4*)src)[i];
  ushort4 o;
  o.x = f2bf(v.x); o.y = f2bf(v.y); o.z = f2bf(v.z); o.w = f2bf(v.w);
  ((ushort4*)dst)[i] = o;
}

// ============ K_pred: compact predicate list + sum of weights ============
__global__ void k_pred(const int* __restrict__ pp, int* __restrict__ plist,
                       int* __restrict__ pcnt, float* __restrict__ sumw) {
  int b = blockIdx.x;
  int lane = threadIdx.x;  // blockDim 64
  const int* ppb = pp + b * NN;
  int base = 0;
  float wacc = 0.f;
  for (int c = 0; c < NN; c += 64) {
    int i = c + lane;
    bool isp = ppb[i] == 1;
    unsigned long long mask = __ballot(isp);
    if (isp) {
      int pos = base + __popcll(mask & ((1ull << lane) - 1ull));
      plist[b * NN + pos] = i;
      bool sing = (i == 0) || (i >= 2 && ppb[i - 2] == 1);
      bool tri = (i >= 1) && (i <= 1 || !sing);
      wacc += tri ? 3.f : 2.f;
    }
    base += __popcll(mask);
  }
  for (int off = 32; off; off >>= 1) wacc += __shfl_xor(wacc, off);
  if (lane == 0) { pcnt[b] = base; sumw[b] = wacc; }
}

// ============ K_cross: occurrence-pair scores -> diag ============
__global__ void k_cross(const float* __restrict__ x, const int* __restrict__ occ,
                        const float* __restrict__ Wc, const float* __restrict__ bc,
                        float* __restrict__ diag) {
  int g = blockIdx.x * 4 + (threadIdx.x >> 6);
  int lane = threadIdx.x & 63;
  int b = g >> 8, m = g & (MM - 1);
  int o0 = occ[(b * MM + m) * 2 + 0];
  int o1 = occ[(b * MM + m) * 2 + 1];
  const float* x0 = x + (size_t)(b * NN + o0) * HH;
  const float* x1 = x + (size_t)(b * NN + o1) * HH;
  float acc = 0.f;
  for (int d = lane; d < HH; d += 64) acc += 0.5f * (x0[d] + x1[d]) * Wc[d];
  for (int off = 32; off; off >>= 1) acc += __shfl_xor(acc, off);
  if (lane == 0) {
    float sc = lrelu(acc + bc[0]);
    float sq = sc * sc;
    diag[b * NN + o0] = sq;
    diag[b * NN + o1] = sq;
  }
}

// ============ K_score_mf: bf16 MFMA score GEMM over gathered predicate rows ============
// Cols [0,768): var_in @ W_var^T + b_var ; cols [768,1536): x @ W_sym^T + b_sym.
// Epilogue: sum_cols tanh(feat)*W_score[col] -> atomicAdd s_raw[b][i].
__global__ __launch_bounds__(256, 2) void k_score_mf(
    const ushort* __restrict__ xb, const int* __restrict__ pp,
    const int* __restrict__ plist, const int* __restrict__ pcnt,
    const ushort* __restrict__ Wvar, const ushort* __restrict__ Wsym,
    const float* __restrict__ bvar, const float* __restrict__ bsym,
    const float* __restrict__ wscore, float* __restrict__ s_raw) {
  const int b = blockIdx.z;
  const int cnt = pcnt[b];
  const int j0 = blockIdx.y * 128;
  if (j0 >= cnt) return;
  const int n0g = blockIdx.x * 128;           // global col in [0,1536)
  const bool symh = n0g >= HH;
  const int n0 = symh ? n0g - HH : n0g;
  const ushort* W = symh ? Wsym : Wvar;
  const float* bias = symh ? bsym : bvar;
  __shared__ ushort As[128 * 64];
  __shared__ ushort Bs[128 * 64];
  __shared__ int pl[128];
  __shared__ float wA_[128], wB_[128];
  __shared__ float red[128];
  const int t = threadIdx.x;
  const int w = t >> 6, lane = t & 63, lg = lane >> 4, lm = lane & 15;
  const int wm = (w >> 1) * 64, wn = (w & 1) * 64;
  if (t < 128) {
    int j = j0 + t;
    int i = (j < cnt) ? plist[b * NN + j] : 2;
    pl[t] = i;
    bool sing = (i == 0) || (i >= 2 && pp[b * NN + i - 2] == 1);
    wA_[t] = sing ? 0.f : 0.5f;
    wB_[t] = sing ? 1.f : 0.5f;
    red[t] = 0.f;
  }
  __syncthreads();
  f32x4 acc[4][4] = {};
  const ushort* xbb = xb + (size_t)b * NN * HH;
  for (int k0 = 0; k0 < HH; k0 += 64) {
    if (k0) __syncthreads();
#pragma unroll
    for (int it = 0; it < 4; ++it) {   // 128 rows x 8 chunks = 1024 slots
      int slot = t + it * 256;
      int row = slot >> 3, c = slot & 7;
      uint4 vb = *(const uint4*)(W + (size_t)(n0 + row) * HH + k0 + c * 8);
      *(uint4*)&Bs[row * 64 + ((c ^ (row & 7)) * 8)] = vb;
      int i = pl[row];
      uint4 va;
      if (symh) {
        va = *(const uint4*)(xbb + (size_t)i * HH + k0 + c * 8);
      } else {
        uint4 vp = *(const uint4*)(xbb + (size_t)((i - 1) & (NN - 1)) * HH + k0 + c * 8);
        uint4 vn = *(const uint4*)(xbb + (size_t)((i + 1) & (NN - 1)) * HH + k0 + c * 8);
        float wa = wA_[row], wb2 = wB_[row];
        const ushort* pu = (const ushort*)&vp;
        const ushort* nu = (const ushort*)&vn;
        ushort* ou = (ushort*)&va;
#pragma unroll
        for (int e = 0; e < 8; ++e)
          ou[e] = f2bf(wa * bf2f(pu[e]) + wb2 * bf2f(nu[e]));
      }
      *(uint4*)&As[row * 64 + ((c ^ (row & 7)) * 8)] = va;
    }
    __syncthreads();
    bf16x8 af[4][2], bfr[4][2];
#pragma unroll
    for (int mt = 0; mt < 4; ++mt)
#pragma unroll
      for (int kt = 0; kt < 2; ++kt) {
        int row = wm + mt * 16 + lm, ch = lg + kt * 4;
        af[mt][kt] = *(bf16x8*)&As[row * 64 + ((ch ^ (row & 7)) * 8)];
      }
#pragma unroll
    for (int nt = 0; nt < 4; ++nt)
#pragma unroll
      for (int kt = 0; kt < 2; ++kt) {
        int row = wn + nt * 16 + lm, ch = lg + kt * 4;
        bfr[nt][kt] = *(bf16x8*)&Bs[row * 64 + ((ch ^ (row & 7)) * 8)];
      }
#pragma unroll
    for (int mt = 0; mt < 4; ++mt)
#pragma unroll
      for (int nt = 0; nt < 4; ++nt)
#pragma unroll
        for (int kt = 0; kt < 2; ++kt)
          acc[mt][nt] = __builtin_amdgcn_mfma_f32_16x16x32_bf16(af[mt][kt], bfr[nt][kt], acc[mt][nt], 0, 0, 0);
  }
  // epilogue: tanh + dot with W_score, reduce cols
  float bcol[4], wcol[4];
#pragma unroll
  for (int nt = 0; nt < 4; ++nt) {
    int cl = wn + nt * 16 + lm;
    bcol[nt] = bias[n0 + cl];
    wcol[nt] = wscore[n0g + cl];
  }
#pragma unroll
  for (int mt = 0; mt < 4; ++mt)
#pragma unroll
    for (int r = 0; r < 4; ++r) {
      float p = 0.f;
#pragma unroll
      for (int nt = 0; nt < 4; ++nt)
        p += tanhf(acc[mt][nt][r] + bcol[nt]) * wcol[nt];
      p += __shfl_xor(p, 1); p += __shfl_xor(p, 2);
      p += __shfl_xor(p, 4); p += __shfl_xor(p, 8);
      if (lm == 0) atomicAdd(&red[wm + mt * 16 + lg * 4 + r], p);
    }
  __syncthreads();
  if (t < 128) {
    int j2 = j0 + t;
    if (j2 < cnt) atomicAdd(&s_raw[b * NN + pl[t]], red[t]);
  }
}

// ============ K_bias: per-row sparse bias window ============
__global__ void k_bias(const int* __restrict__ pp, const float* __restrict__ s_raw,
                       const float* __restrict__ diag, const float* __restrict__ b_score,
                       float4* __restrict__ bias4) {
  int g = blockIdx.x * 256 + threadIdx.x;
  int b = g >> 10, r = g & (NN - 1);
  const int* ppb = pp + b * NN;
  int i = -1;
  if (ppb[r] == 1) i = r;
  else if (r + 1 < NN && ppb[r + 1] == 1) i = r + 1;
  else if (r >= 1 && ppb[r - 1] == 1) i = r - 1;
  float v0 = 0.f, v1 = 0.f, v2 = 0.f; int cw = r;
  if (i >= 1 && i + 1 < NN) {
    float s = lrelu(s_raw[b * NN + i] + b_score[0]);
    float s2 = s * s;
    cw = i - 1;
    if (i == r) { v0 = 0.2f * s; v1 = 1.6f * s2; v2 = 0.2f * s; }
    else       { v0 = 0.8f * s2; v1 = 0.2f * s; v2 = 0.8f * s2; }
  }
  int slot = r - cw;
  float d = diag[g];
  if (slot == 0) v0 += d; else if (slot == 1) v1 += d; else v2 += d;
  bias4[g] = make_float4(__int_as_float(cw), v0, v1, v2);
}

// ============ K_gemm_bf: fused QKV bf16 MFMA GEMM ============
__global__ __launch_bounds__(256, 2) void k_gemm_bf(
    const ushort* __restrict__ X,
    const ushort* __restrict__ W0, const ushort* __restrict__ W1, const ushort* __restrict__ W2,
    const float* __restrict__ b0, const float* __restrict__ b1, const float* __restrict__ b2,
    ushort* __restrict__ C0, ushort* __restrict__ C1, ushort* __restrict__ C2) {
  const int z = blockIdx.z;
  const ushort* W = z == 0 ? W0 : (z == 1 ? W1 : W2);
  const float* bias = z == 0 ? b0 : (z == 1 ? b1 : b2);
  ushort* C = z == 0 ? C0 : (z == 1 ? C1 : C2);
  const float alpha = z == 0 ? QSCALE : 1.f;
  __shared__ ushort As[128 * 64];
  __shared__ ushort Bs[128 * 64];
  const int m0 = blockIdx.x * 128, n0 = blockIdx.y * 128;
  const int t = threadIdx.x;
  const int w = t >> 6, lane = t & 63, lg = lane >> 4, lm = lane & 15;
  const int wm = (w >> 1) * 64, wn = (w & 1) * 64;
  f32x4 acc[4][4] = {};
  for (int k0 = 0; k0 < HH; k0 += 64) {
    __syncthreads();
#pragma unroll
    for (int it = 0; it < 4; ++it) {
      int slot = t + it * 256;
      int row = slot >> 3, c = slot & 7;
      uint4 va = *(const uint4*)(X + (size_t)(m0 + row) * HH + k0 + c * 8);
      *(uint4*)&As[row * 64 + ((c ^ (row & 7)) * 8)] = va;
      uint4 vb = *(const uint4*)(W + (size_t)(n0 + row) * HH + k0 + c * 8);
      *(uint4*)&Bs[row * 64 + ((c ^ (row & 7)) * 8)] = vb;
    }
    __syncthreads();
    bf16x8 af[4][2], bfr[4][2];
#pragma unroll
    for (int mt = 0; mt < 4; ++mt)
#pragma unroll
      for (int kt = 0; kt < 2; ++kt) {
        int row = wm + mt * 16 + lm, ch = lg + kt * 4;
        af[mt][kt] = *(bf16x8*)&As[row * 64 + ((ch ^ (row & 7)) * 8)];
      }
#pragma unroll
    for (int nt = 0; nt < 4; ++nt)
#pragma unroll
      for (int kt = 0; kt < 2; ++kt) {
        int row = wn + nt * 16 + lm, ch = lg + kt * 4;
        bfr[nt][kt] = *(bf16x8*)&Bs[row * 64 + ((ch ^ (row & 7)) * 8)];
      }
#pragma unroll
    for (int mt = 0; mt < 4; ++mt)
#pragma unroll
      for (int nt = 0; nt < 4; ++nt)
#pragma unroll
        for (int kt = 0; kt < 2; ++kt)
          acc[mt][nt] = __builtin_amdgcn_mfma_f32_16x16x32_bf16(af[mt][kt], bfr[nt][kt], acc[mt][nt], 0, 0, 0);
  }
#pragma unroll
  for (int nt = 0; nt < 4; ++nt) {
    int col = n0 + wn + nt * 16 + lm;
    float bcol = bias[col];
#pragma unroll
    for (int mt = 0; mt < 4; ++mt)
#pragma unroll
      for (int r = 0; r < 4; ++r) {
        int row = m0 + wm + mt * 16 + lg * 4 + r;
        C[(size_t)row * HH + col] = f2bf((acc[mt][nt][r] + bcol) * alpha);
      }
  }
}

// ============ K_attn2: bf16 MFMA flash attention + sparse bias -> z1/z2 ============
__global__ __launch_bounds__(256, 4) void k_attn2(
    const ushort* __restrict__ qg, const ushort* __restrict__ kg, const ushort* __restrict__ vg,
    const float4* __restrict__ bias4, const int* __restrict__ pp, float* __restrict__ zz) {
  __shared__ ushort Ks[64 * 64];
  __shared__ ushort Vt[64 * 64];
  __shared__ ushort Pl[4][16 * 64];
  const int rb = blockIdx.x, h = blockIdx.y, b = blockIdx.z;
  const int n0 = rb * 64;
  const int t = threadIdx.x, w = t >> 6, lane = t & 63, lg = lane >> 4, lm = lane & 15;
  const int qbase = n0 + w * 16;
  const ushort* qrow = qg + (size_t)(b * NN + qbase + lm) * HH + h * ASZ;
  bf16x8 qf[2];
  qf[0] = *(const bf16x8*)(qrow + lg * 8);
  qf[1] = *(const bf16x8*)(qrow + lg * 8 + 32);
  int cw[4]; float bw[4][3];
#pragma unroll
  for (int r = 0; r < 4; ++r) {
    float4 bz = bias4[b * NN + qbase + lg * 4 + r];
    cw[r] = __float_as_int(bz.x); bw[r][0] = bz.y; bw[r][1] = bz.z; bw[r][2] = bz.w;
  }
  float mr[4] = {-1e30f, -1e30f, -1e30f, -1e30f};
  float lr[4] = {0.f, 0.f, 0.f, 0.f};
  f32x4 y[4] = {};
  const ushort* kb = kg + (size_t)(b * NN) * HH + h * ASZ;
  const ushort* vb = vg + (size_t)(b * NN) * HH + h * ASZ;
  for (int tile = 0; tile < 16; ++tile) {
    const int c0 = tile * 64;
    __syncthreads();
#pragma unroll
    for (int it = 0; it < 2; ++it) {
      int slot = t + it * 256;
      int row = slot >> 3, c = slot & 7;
      uint4 kv = *(const uint4*)(kb + (size_t)(c0 + row) * HH + c * 8);
      *(uint4*)&Ks[row * 64 + ((c ^ (row & 7)) * 8)] = kv;
      uint4 vv = *(const uint4*)(vb + (size_t)(c0 + row) * HH + c * 8);
      const ushort* pv = (const ushort*)&vv;
#pragma unroll
      for (int j = 0; j < 8; ++j) {
        int d = c * 8 + j;
        Vt[d * 64 + (((row >> 3) ^ (d & 7)) * 8) + (row & 7)] = pv[j];
      }
    }
    __syncthreads();
    f32x4 s[4] = {};
#pragma unroll
    for (int nt = 0; nt < 4; ++nt) {
      int krow = lm + nt * 16, sw = krow & 7;
#pragma unroll
      for (int kt = 0; kt < 2; ++kt) {
        bf16x8 kf = *(bf16x8*)&Ks[krow * 64 + (((lg + kt * 4) ^ sw) * 8)];
        s[nt] = __builtin_amdgcn_mfma_f32_16x16x32_bf16(qf[kt], kf, s[nt], 0, 0, 0);
      }
    }
#pragma unroll
    for (int nt = 0; nt < 4; ++nt) {
      int kcol = c0 + nt * 16 + lm;
#pragma unroll
      for (int r = 0; r < 4; ++r) {
        int dd = kcol - cw[r];
        if (dd >= 0 && dd < 3) s[nt][r] += bw[r][dd];
      }
    }
    float f[4], ts[4];
#pragma unroll
    for (int r = 0; r < 4; ++r) {
      float tm = fmaxf(fmaxf(s[0][r], s[1][r]), fmaxf(s[2][r], s[3][r]));
      tm = fmaxf(tm, __shfl_xor(tm, 1));
      tm = fmaxf(tm, __shfl_xor(tm, 2));
      tm = fmaxf(tm, __shfl_xor(tm, 4));
      tm = fmaxf(tm, __shfl_xor(tm, 8));
      float mn = fmaxf(mr[r], tm);
      f[r] = __expf(mr[r] - mn);
      mr[r] = mn;
      ts[r] = 0.f;
    }
#pragma unroll
    for (int nt = 0; nt < 4; ++nt)
#pragma unroll
      for (int r = 0; r < 4; ++r) {
        float p = __expf(s[nt][r] - mr[r]);
        s[nt][r] = p; ts[r] += p;
      }
#pragma unroll
    for (int r = 0; r < 4; ++r) {
      float v = ts[r];
      v += __shfl_xor(v, 1); v += __shfl_xor(v, 2);
      v += __shfl_xor(v, 4); v += __shfl_xor(v, 8);
      lr[r] = lr[r] * f[r] + v;
    }
#pragma unroll
    for (int nt = 0; nt < 4; ++nt)
#pragma unroll
      for (int r = 0; r < 4; ++r) y[nt][r] *= f[r];
#pragma unroll
    for (int nt = 0; nt < 4; ++nt)
#pragma unroll
      for (int r = 0; r < 4; ++r) {
        int prow = lg * 4 + r, pcol = lm + nt * 16;
        Pl[w][prow * 64 + (((pcol >> 3) ^ (prow & 7)) * 8) + (pcol & 7)] = f2bf(s[nt][r]);
      }
    asm volatile("s_waitcnt lgkmcnt(0)" ::: "memory");
    __builtin_amdgcn_sched_barrier(0);
    bf16x8 pa[2];
#pragma unroll
    for (int kt = 0; kt < 2; ++kt)
      pa[kt] = *(bf16x8*)&Pl[w][lm * 64 + (((lg + kt * 4) ^ (lm & 7)) * 8)];
#pragma unroll
    for (int nt = 0; nt < 4; ++nt) {
      int vrow = lm + nt * 16, sw = vrow & 7;
#pragma unroll
      for (int kt = 0; kt < 2; ++kt) {
        bf16x8 vf = *(bf16x8*)&Vt[vrow * 64 + (((lg + kt * 4) ^ sw) * 8)];
        y[nt] = __builtin_amdgcn_mfma_f32_16x16x32_bf16(pa[kt], vf, y[nt], 0, 0, 0);
      }
    }
  }
  float inv[4], c1v[4], c2v[4];
#pragma unroll
  for (int r = 0; r < 4; ++r) {
    inv[r] = 1.f / lr[r];
    coefs(pp + b * NN, qbase + lg * 4 + r, c1v[r], c2v[r]);
  }
  float a1[4], a2[4];
#pragma unroll
  for (int nt = 0; nt < 4; ++nt) {
    float u1 = 0.f, u2 = 0.f;
#pragma unroll
    for (int r = 0; r < 4; ++r) {
      float yv = y[nt][r] * inv[r];
      u1 += c1v[r] * yv;
      u2 += c2v[r] * yv;
    }
    u1 += __shfl_xor(u1, 16); u1 += __shfl_xor(u1, 32);
    u2 += __shfl_xor(u2, 16); u2 += __shfl_xor(u2, 32);
    a1[nt] = u1; a2[nt] = u2;
  }
  if (lg == 0) {
#pragma unroll
    for (int nt = 0; nt < 4; ++nt) {
      atomicAdd(&zz[b * HH + h * ASZ + nt * 16 + lm], a1[nt]);
      atomicAdd(&zz[BB * HH + b * HH + h * ASZ + nt * 16 + lm], a2[nt]);
    }
  }
}

// ============ F1: t_s = W_o @ (z_s / sumw) + b_o ============
__global__ void k_f1(const float* __restrict__ Wo, const float* __restrict__ bo,
                     const float* __restrict__ zz, const float* __restrict__ sumw,
                     float* __restrict__ tvec) {
  int b = blockIdx.y;
  int w = threadIdx.x >> 6, lane = threadIdx.x & 63;
  float inv = 1.f / sumw[b];
  const float* z1 = zz + b * HH;
  const float* z2 = zz + BB * HH + b * HH;
  float zr1[12], zr2[12];
#pragma unroll
  for (int m = 0; m < 12; ++m) { zr1[m] = z1[lane + 64 * m] * inv; zr2[m] = z2[lane + 64 * m] * inv; }
  for (int j = 0; j < 8; ++j) {
    int o = blockIdx.x * 32 + w * 8 + j;
    const float* wrow = Wo + (size_t)o * HH;
    float a1 = 0.f, a2 = 0.f;
#pragma unroll
    for (int m = 0; m < 12; ++m) { float wv = wrow[lane + 64 * m]; a1 += wv * zr1[m]; a2 += wv * zr2[m]; }
    for (int mask = 32; mask; mask >>= 1) { a1 += __shfl_xor(a1, mask); a2 += __shfl_xor(a2, mask); }
    if (lane == 0) { tvec[b * HH + o] = a1 + bo[o]; tvec[BB * HH + b * HH + o] = a2 + bo[o]; }
  }
}

// ============ F2: pm = WL @ t1 + WR @ t2 + b_atom ============
__global__ void k_f2(const float* __restrict__ Wa, const float* __restrict__ ba,
                     const float* __restrict__ tvec, float* __restrict__ pm) {
  int b = blockIdx.y;
  int w = threadIdx.x >> 6, lane = threadIdx.x & 63;
  const float* t1 = tvec + b * HH;
  const float* t2 = tvec + BB * HH + b * HH;
  float r1[12], r2[12];
#pragma unroll
  for (int m = 0; m < 12; ++m) { r1[m] = t1[lane + 64 * m]; r2[m] = t2[lane + 64 * m]; }
  for (int j = 0; j < 8; ++j) {
    int o = blockIdx.x * 32 + w * 8 + j;
    const float* wrow = Wa + (size_t)o * (2 * HH);
    float a = 0.f;
#pragma unroll
    for (int m = 0; m < 12; ++m) a += wrow[lane + 64 * m] * r1[m];
#pragma unroll
    for (int m = 0; m < 12; ++m) a += wrow[HH + lane + 64 * m] * r2[m];
    for (int mask = 32; mask; mask >>= 1) a += __shfl_xor(a, mask);
    if (lane == 0) pm[b * HH + o] = a + ba[o];
  }
}

// ============ F3: broadcast pm to (B,N,H) ============
__global__ void k_bcast(const float* __restrict__ pm, float* __restrict__ out) {
  size_t g = (size_t)blockIdx.x * 256 + threadIdx.x;
  int b = (int)(g / ((size_t)NN * HH / 4));
  int hh4 = (int)(g % (HH / 4));
  float4 val = *(const float4*)(pm + b * HH + hh4 * 4);
  *(float4*)(out + g * 4) = val;
}

// ================= launcher =================
extern "C" void kernel_launch(void* const* d_in, const int* in_sizes, int n_in,
                              void* d_out, int out_size, void* d_ws, size_t ws_size,
                              hipStream_t stream) {
  (void)in_sizes; (void)n_in; (void)out_size; (void)ws_size;
  const float* x       = (const float*)d_in[0];
  const float* W_var   = (const float*)d_in[3];
  const float* b_var   = (const float*)d_in[4];
  const float* W_sym   = (const float*)d_in[5];
  const float* b_sym   = (const float*)d_in[6];
  const float* W_score = (const float*)d_in[7];
  const float* b_score = (const float*)d_in[8];
  const float* W_cross = (const float*)d_in[9];
  const float* b_cross = (const float*)d_in[10];
  const float* W_atom  = (const float*)d_in[11];
  const float* b_atom  = (const float*)d_in[12];
  const float* W_q     = (const float*)d_in[13];
  const float* b_q     = (const float*)d_in[14];
  const float* W_k     = (const float*)d_in[15];
  const float* b_k     = (const float*)d_in[16];
  const float* W_v     = (const float*)d_in[17];
  const float* b_v     = (const float*)d_in[18];
  const float* W_o     = (const float*)d_in[19];
  const float* b_o     = (const float*)d_in[20];
  const int*   pp      = (const int*)d_in[21];
  const int*   occ     = (const int*)d_in[24];
  float* out = (float*)d_out;
  char* wsb = (char*)d_ws;
  ushort* qb  = (ushort*)(wsb + OFFB_QB);
  ushort* kbf = (ushort*)(wsb + OFFB_KB);
  ushort* vbf = (ushort*)(wsb + OFFB_VB);
  ushort* xb  = (ushort*)(wsb + OFFB_XB);
  ushort* wqb = (ushort*)(wsb + OFFB_WQB);
  ushort* wkb = (ushort*)(wsb + OFFB_WKB);
  ushort* wvb = (ushort*)(wsb + OFFB_WVB);
  ushort* wvar = (ushort*)(wsb + OFFB_WVAR);
  ushort* wsym = (ushort*)(wsb + OFFB_WSYM);
  float* sraw = (float*)(wsb + OFFB_SRAW);
  float* diag = (float*)(wsb + OFFB_DIAG);
  float4* bias4 = (float4*)(wsb + OFFB_BIAS4);
  int* plist = (int*)(wsb + OFFB_PLIST);
  int* pcnt  = (int*)(wsb + OFFB_PCNT);
  float* sumw = (float*)(wsb + OFFB_SUMW);
  float* zz   = (float*)(wsb + OFFB_ZZ);
  float* tv   = (float*)(wsb + OFFB_TV);
  float* pm   = (float*)(wsb + OFFB_PM);

  hipMemsetAsync(sraw, 0, BB * NN * sizeof(float), stream);
  hipMemsetAsync(diag, 0, BB * NN * sizeof(float), stream);
  hipMemsetAsync(zz, 0, 2 * BB * HH * sizeof(float), stream);

  k_pred<<<BB, 64, 0, stream>>>(pp, plist, pcnt, sumw);
  // f32 -> bf16 conversions
  k_cvt<<<(BB * NN * HH / 4 + 255) / 256, 256, 0, stream>>>(x, xb, BB * NN * HH / 4);
  k_cvt<<<(HH * HH / 4 + 255) / 256, 256, 0, stream>>>(W_q, wqb, HH * HH / 4);
  k_cvt<<<(HH * HH / 4 + 255) / 256, 256, 0, stream>>>(W_k, wkb, HH * HH / 4);
  k_cvt<<<(HH * HH / 4 + 255) / 256, 256, 0, stream>>>(W_v, wvb, HH * HH / 4);
  k_cvt<<<(HH * HH / 4 + 255) / 256, 256, 0, stream>>>(W_var, wvar, HH * HH / 4);
  k_cvt<<<(HH * HH / 4 + 255) / 256, 256, 0, stream>>>(W_sym, wsym, HH * HH / 4);
  // score path (bf16 MFMA, fused var+sym over 1536 cols)
  k_score_mf<<<dim3(12, 8, BB), 256, 0, stream>>>(xb, pp, plist, pcnt, wvar, wsym,
                                                  b_var, b_sym, W_score, sraw);
  k_cross<<<BB * MM / 4, 256, 0, stream>>>(x, occ, W_cross, b_cross, diag);
  k_bias<<<BB * NN / 256, 256, 0, stream>>>(pp, sraw, diag, b_score, bias4);
  // fused QKV MFMA GEMM (bf16)
  k_gemm_bf<<<dim3(64, 6, 3), 256, 0, stream>>>(xb, wqb, wkb, wvb, b_q, b_k, b_v, qb, kbf, vbf);
  // MFMA flash attention
  k_attn2<<<dim3(16, NHD, BB), 256, 0, stream>>>(qb, kbf, vbf, bias4, pp, zz);
  k_f1<<<dim3(24, BB), 256, 0, stream>>>(W_o, b_o, zz, sumw, tv);
  k_f2<<<dim3(24, BB), 256, 0, stream>>>(W_atom, b_atom, tv, pm);
  k_bcast<<<BB * NN * HH / 1024, 256, 0, stream>>>(pm, out);
}

// Round 5
// 250.728 us; speedup vs baseline: 5.6411x; 1.2265x over previous
//
#include <hip/hip_runtime.h>
#include <hip/hip_bf16.h>

// ================= problem constants =================
#define BB 8
#define NN 1024
#define HH 768
#define NHD 12
#define ASZ 64
#define MM 256
#define QSCALE 0.125f   // AS^-0.5
#define NSLOPE 0.02f

typedef __attribute__((ext_vector_type(8))) short bf16x8;
typedef __attribute__((ext_vector_type(4))) float f32x4;

// ============ workspace layout (byte offsets, all 16B-aligned) ============
#define OFFB_QB    ((size_t)0)            // 8*1024*768 bf16
#define OFFB_KB    ((size_t)12582912)
#define OFFB_VB    ((size_t)25165824)     // V^T: [b][h][d][n] bf16
#define OFFB_XB    ((size_t)37748736)     // x in bf16
#define OFFB_WQB   ((size_t)50331648)     // 768*768 bf16
#define OFFB_WKB   ((size_t)51511296)
#define OFFB_WVB   ((size_t)52690944)
#define OFFB_WVAR  ((size_t)53870592)     // W_var bf16
#define OFFB_WSYM  ((size_t)55050240)     // W_sym bf16
#define OFFB_SRAW  ((size_t)56229888)     // 8192 f32
#define OFFB_DIAG  ((size_t)56262656)     // 8192 f32
#define OFFB_BIAS4 ((size_t)56295424)     // 8192 float4
#define OFFB_PLIST ((size_t)56426496)     // 8192 i32
#define OFFB_PCNT  ((size_t)56459264)
#define OFFB_SUMW  ((size_t)56459296)
#define OFFB_ZZ    ((size_t)56459328)     // 2*8*768 f32
#define OFFB_TV    ((size_t)56508480)
#define OFFB_PM    ((size_t)56557632)

__device__ __forceinline__ float lrelu(float v) { return v >= 0.f ? v : NSLOPE * v; }

__device__ __forceinline__ ushort f2bf(float f) {  // RNE f32->bf16
  union { float f; unsigned u; } v; v.f = f;
  unsigned r = (v.u + 0x7fffu + ((v.u >> 16) & 1u)) >> 16;
  return (ushort)r;
}
__device__ __forceinline__ float bf2f(ushort u) {
  union { unsigned u; float f; } v; v.u = (unsigned)u << 16;
  return v.f;
}

// weights for the final weighted row-sums of y (derived from pm algebra).
__device__ __forceinline__ void coefs(const int* ppb, int j, float& c1, float& c2) {
  auto pred = [&](int tt) { return tt >= 0 && tt < NN && ppb[tt] == 1; };
  auto single = [&](int tt) { return tt == 0 || (tt >= 2 && ppb[tt - 2] == 1); };
  auto wgt = [&](int tt) {
    if (!pred(tt)) return 0.f;
    bool tri = (tt >= 1) && (tt <= 1 || !single(tt));
    return tri ? 3.f : 2.f;
  };
  float a = 0.f;
  if (pred(j + 1)) a += wgt(j + 1) * (single(j + 1) ? 0.f : 0.5f);
  if (j >= 1 && pred(j - 1)) a += wgt(j - 1) * (single(j - 1) ? 1.f : 0.5f);
  c1 = a;
  c2 = wgt(j);
}

// ============ K_cvt: f32 -> bf16 (vectorized) ============
__global__ void k_cvt(const float* __restrict__ src, ushort* __restrict__ dst, int n4) {
  int i = blockIdx.x * 256 + threadIdx.x;
  if (i >= n4) return;
  float4 v = ((const float4*)src)[i];
  ushort4 o;
  o.x = f2bf(v.x); o.y = f2bf(v.y); o.z = f2bf(v.z); o.w = f2bf(v.w);
  ((ushort4*)dst)[i] = o;
}

// ============ K_pred: compact predicate list + sum of weights ============
__global__ void k_pred(const int* __restrict__ pp, int* __restrict__ plist,
                       int* __restrict__ pcnt, float* __restrict__ sumw) {
  int b = blockIdx.x;
  int lane = threadIdx.x;  // blockDim 64
  const int* ppb = pp + b * NN;
  int base = 0;
  float wacc = 0.f;
  for (int c = 0; c < NN; c += 64) {
    int i = c + lane;
    bool isp = ppb[i] == 1;
    unsigned long long mask = __ballot(isp);
    if (isp) {
      int pos = base + __popcll(mask & ((1ull << lane) - 1ull));
      plist[b * NN + pos] = i;
      bool sing = (i == 0) || (i >= 2 && ppb[i - 2] == 1);
      bool tri = (i >= 1) && (i <= 1 || !sing);
      wacc += tri ? 3.f : 2.f;
    }
    base += __popcll(mask);
  }
  for (int off = 32; off; off >>= 1) wacc += __shfl_xor(wacc, off);
  if (lane == 0) { pcnt[b] = base; sumw[b] = wacc; }
}

// ============ K_cross: occurrence-pair scores -> diag ============
__global__ void k_cross(const float* __restrict__ x, const int* __restrict__ occ,
                        const float* __restrict__ Wc, const float* __restrict__ bc,
                        float* __restrict__ diag) {
  int g = blockIdx.x * 4 + (threadIdx.x >> 6);
  int lane = threadIdx.x & 63;
  int b = g >> 8, m = g & (MM - 1);
  int o0 = occ[(b * MM + m) * 2 + 0];
  int o1 = occ[(b * MM + m) * 2 + 1];
  const float* x0 = x + (size_t)(b * NN + o0) * HH;
  const float* x1 = x + (size_t)(b * NN + o1) * HH;
  float acc = 0.f;
  for (int d = lane; d < HH; d += 64) acc += 0.5f * (x0[d] + x1[d]) * Wc[d];
  for (int off = 32; off; off >>= 1) acc += __shfl_xor(acc, off);
  if (lane == 0) {
    float sc = lrelu(acc + bc[0]);
    float sq = sc * sc;
    diag[b * NN + o0] = sq;
    diag[b * NN + o1] = sq;
  }
}

// ============ K_score_mf: bf16 MFMA score GEMM over gathered predicate rows ============
__global__ __launch_bounds__(256, 2) void k_score_mf(
    const ushort* __restrict__ xb, const int* __restrict__ pp,
    const int* __restrict__ plist, const int* __restrict__ pcnt,
    const ushort* __restrict__ Wvar, const ushort* __restrict__ Wsym,
    const float* __restrict__ bvar, const float* __restrict__ bsym,
    const float* __restrict__ wscore, float* __restrict__ s_raw) {
  const int b = blockIdx.z;
  const int cnt = pcnt[b];
  const int j0 = blockIdx.y * 128;
  if (j0 >= cnt) return;
  const int n0g = blockIdx.x * 128;           // global col in [0,1536)
  const bool symh = n0g >= HH;
  const int n0 = symh ? n0g - HH : n0g;
  const ushort* W = symh ? Wsym : Wvar;
  const float* bias = symh ? bsym : bvar;
  __shared__ ushort As[128 * 64];
  __shared__ ushort Bs[128 * 64];
  __shared__ int pl[128];
  __shared__ float wA_[128], wB_[128];
  __shared__ float red[128];
  const int t = threadIdx.x;
  const int w = t >> 6, lane = t & 63, lg = lane >> 4, lm = lane & 15;
  const int wm = (w >> 1) * 64, wn = (w & 1) * 64;
  if (t < 128) {
    int j = j0 + t;
    int i = (j < cnt) ? plist[b * NN + j] : 2;
    pl[t] = i;
    bool sing = (i == 0) || (i >= 2 && pp[b * NN + i - 2] == 1);
    wA_[t] = sing ? 0.f : 0.5f;
    wB_[t] = sing ? 1.f : 0.5f;
    red[t] = 0.f;
  }
  __syncthreads();
  f32x4 acc[4][4] = {};
  const ushort* xbb = xb + (size_t)b * NN * HH;
  for (int k0 = 0; k0 < HH; k0 += 64) {
    if (k0) __syncthreads();
#pragma unroll
    for (int it = 0; it < 4; ++it) {   // 128 rows x 8 chunks = 1024 slots
      int slot = t + it * 256;
      int row = slot >> 3, c = slot & 7;
      uint4 vb = *(const uint4*)(W + (size_t)(n0 + row) * HH + k0 + c * 8);
      *(uint4*)&Bs[row * 64 + ((c ^ (row & 7)) * 8)] = vb;
      int i = pl[row];
      uint4 va;
      if (symh) {
        va = *(const uint4*)(xbb + (size_t)i * HH + k0 + c * 8);
      } else {
        uint4 vp = *(const uint4*)(xbb + (size_t)((i - 1) & (NN - 1)) * HH + k0 + c * 8);
        uint4 vn = *(const uint4*)(xbb + (size_t)((i + 1) & (NN - 1)) * HH + k0 + c * 8);
        float wa = wA_[row], wb2 = wB_[row];
        const ushort* pu = (const ushort*)&vp;
        const ushort* nu = (const ushort*)&vn;
        ushort* ou = (ushort*)&va;
#pragma unroll
        for (int e = 0; e < 8; ++e)
          ou[e] = f2bf(wa * bf2f(pu[e]) + wb2 * bf2f(nu[e]));
      }
      *(uint4*)&As[row * 64 + ((c ^ (row & 7)) * 8)] = va;
    }
    __syncthreads();
    bf16x8 af[4][2], bfr[4][2];
#pragma unroll
    for (int mt = 0; mt < 4; ++mt)
#pragma unroll
      for (int kt = 0; kt < 2; ++kt) {
        int row = wm + mt * 16 + lm, ch = lg + kt * 4;
        af[mt][kt] = *(bf16x8*)&As[row * 64 + ((ch ^ (row & 7)) * 8)];
      }
#pragma unroll
    for (int nt = 0; nt < 4; ++nt)
#pragma unroll
      for (int kt = 0; kt < 2; ++kt) {
        int row = wn + nt * 16 + lm, ch = lg + kt * 4;
        bfr[nt][kt] = *(bf16x8*)&Bs[row * 64 + ((ch ^ (row & 7)) * 8)];
      }
#pragma unroll
    for (int mt = 0; mt < 4; ++mt)
#pragma unroll
      for (int nt = 0; nt < 4; ++nt)
#pragma unroll
        for (int kt = 0; kt < 2; ++kt)
          acc[mt][nt] = __builtin_amdgcn_mfma_f32_16x16x32_bf16(af[mt][kt], bfr[nt][kt], acc[mt][nt], 0, 0, 0);
  }
  // epilogue: tanh + dot with W_score, reduce cols
  float bcol[4], wcol[4];
#pragma unroll
  for (int nt = 0; nt < 4; ++nt) {
    int cl = wn + nt * 16 + lm;
    bcol[nt] = bias[n0 + cl];
    wcol[nt] = wscore[n0g + cl];
  }
#pragma unroll
  for (int mt = 0; mt < 4; ++mt)
#pragma unroll
    for (int r = 0; r < 4; ++r) {
      float p = 0.f;
#pragma unroll
      for (int nt = 0; nt < 4; ++nt)
        p += tanhf(acc[mt][nt][r] + bcol[nt]) * wcol[nt];
      p += __shfl_xor(p, 1); p += __shfl_xor(p, 2);
      p += __shfl_xor(p, 4); p += __shfl_xor(p, 8);
      if (lm == 0) atomicAdd(&red[wm + mt * 16 + lg * 4 + r], p);
    }
  __syncthreads();
  if (t < 128) {
    int j2 = j0 + t;
    if (j2 < cnt) atomicAdd(&s_raw[b * NN + pl[t]], red[t]);
  }
}

// ============ K_bias: per-row sparse bias window ============
__global__ void k_bias(const int* __restrict__ pp, const float* __restrict__ s_raw,
                       const float* __restrict__ diag, const float* __restrict__ b_score,
                       float4* __restrict__ bias4) {
  int g = blockIdx.x * 256 + threadIdx.x;
  int b = g >> 10, r = g & (NN - 1);
  const int* ppb = pp + b * NN;
  int i = -1;
  if (ppb[r] == 1) i = r;
  else if (r + 1 < NN && ppb[r + 1] == 1) i = r + 1;
  else if (r >= 1 && ppb[r - 1] == 1) i = r - 1;
  float v0 = 0.f, v1 = 0.f, v2 = 0.f; int cw = r;
  if (i >= 1 && i + 1 < NN) {
    float s = lrelu(s_raw[b * NN + i] + b_score[0]);
    float s2 = s * s;
    cw = i - 1;
    if (i == r) { v0 = 0.2f * s; v1 = 1.6f * s2; v2 = 0.2f * s; }
    else       { v0 = 0.8f * s2; v1 = 0.2f * s; v2 = 0.8f * s2; }
  }
  int slot = r - cw;
  float d = diag[g];
  if (slot == 0) v0 += d; else if (slot == 1) v1 += d; else v2 += d;
  bias4[g] = make_float4(__int_as_float(cw), v0, v1, v2);
}

// ============ K_gemm_bf: fused QKV bf16 MFMA GEMM ============
// z=0: Q row-major *QSCALE ; z=1: K row-major ; z=2: V^T [b][h][d][n]
__global__ __launch_bounds__(256, 2) void k_gemm_bf(
    const ushort* __restrict__ X,
    const ushort* __restrict__ W0, const ushort* __restrict__ W1, const ushort* __restrict__ W2,
    const float* __restrict__ b0, const float* __restrict__ b1, const float* __restrict__ b2,
    ushort* __restrict__ C0, ushort* __restrict__ C1, ushort* __restrict__ C2) {
  const int z = blockIdx.z;
  const ushort* W = z == 0 ? W0 : (z == 1 ? W1 : W2);
  const float* bias = z == 0 ? b0 : (z == 1 ? b1 : b2);
  ushort* C = z == 0 ? C0 : (z == 1 ? C1 : C2);
  const float alpha = z == 0 ? QSCALE : 1.f;
  __shared__ ushort As[128 * 64];
  __shared__ ushort Bs[128 * 64];
  const int m0 = blockIdx.x * 128, n0 = blockIdx.y * 128;
  const int t = threadIdx.x;
  const int w = t >> 6, lane = t & 63, lg = lane >> 4, lm = lane & 15;
  const int wm = (w >> 1) * 64, wn = (w & 1) * 64;
  f32x4 acc[4][4] = {};
  for (int k0 = 0; k0 < HH; k0 += 64) {
    __syncthreads();
#pragma unroll
    for (int it = 0; it < 4; ++it) {
      int slot = t + it * 256;
      int row = slot >> 3, c = slot & 7;
      uint4 va = *(const uint4*)(X + (size_t)(m0 + row) * HH + k0 + c * 8);
      *(uint4*)&As[row * 64 + ((c ^ (row & 7)) * 8)] = va;
      uint4 vb = *(const uint4*)(W + (size_t)(n0 + row) * HH + k0 + c * 8);
      *(uint4*)&Bs[row * 64 + ((c ^ (row & 7)) * 8)] = vb;
    }
    __syncthreads();
    bf16x8 af[4][2], bfr[4][2];
#pragma unroll
    for (int mt = 0; mt < 4; ++mt)
#pragma unroll
      for (int kt = 0; kt < 2; ++kt) {
        int row = wm + mt * 16 + lm, ch = lg + kt * 4;
        af[mt][kt] = *(bf16x8*)&As[row * 64 + ((ch ^ (row & 7)) * 8)];
      }
#pragma unroll
    for (int nt = 0; nt < 4; ++nt)
#pragma unroll
      for (int kt = 0; kt < 2; ++kt) {
        int row = wn + nt * 16 + lm, ch = lg + kt * 4;
        bfr[nt][kt] = *(bf16x8*)&Bs[row * 64 + ((ch ^ (row & 7)) * 8)];
      }
#pragma unroll
    for (int mt = 0; mt < 4; ++mt)
#pragma unroll
      for (int nt = 0; nt < 4; ++nt)
#pragma unroll
        for (int kt = 0; kt < 2; ++kt)
          acc[mt][nt] = __builtin_amdgcn_mfma_f32_16x16x32_bf16(af[mt][kt], bfr[nt][kt], acc[mt][nt], 0, 0, 0);
  }
  if (z == 2) {
    // V^T write: 4 consecutive token rows packed per store
#pragma unroll
    for (int nt = 0; nt < 4; ++nt) {
      int col = n0 + wn + nt * 16 + lm;
      int hh = col >> 6, dd = col & 63;
      float bcol = bias[col];
#pragma unroll
      for (int mt = 0; mt < 4; ++mt) {
        int row0 = m0 + wm + mt * 16 + lg * 4;
        int bb2 = row0 >> 10, nr = row0 & (NN - 1);
        ushort4 o;
        o.x = f2bf(acc[mt][nt][0] + bcol);
        o.y = f2bf(acc[mt][nt][1] + bcol);
        o.z = f2bf(acc[mt][nt][2] + bcol);
        o.w = f2bf(acc[mt][nt][3] + bcol);
        *(ushort4*)(C + ((size_t)(bb2 * NHD + hh) * ASZ + dd) * NN + nr) = o;
      }
    }
  } else {
#pragma unroll
    for (int nt = 0; nt < 4; ++nt) {
      int col = n0 + wn + nt * 16 + lm;
      float bcol = bias[col];
#pragma unroll
      for (int mt = 0; mt < 4; ++mt)
#pragma unroll
        for (int r = 0; r < 4; ++r) {
          int row = m0 + wm + mt * 16 + lg * 4 + r;
          C[(size_t)row * HH + col] = f2bf((acc[mt][nt][r] + bcol) * alpha);
        }
    }
  }
}

// ============ K_attn2: bf16 MFMA flash attention + sparse bias -> z1/z2 ============
// 8 waves x 16 q-rows (128 q/block); K row-major swizzled, V^T staged directly.
__global__ __launch_bounds__(512, 4) void k_attn2(
    const ushort* __restrict__ qg, const ushort* __restrict__ kg, const ushort* __restrict__ vtg,
    const float4* __restrict__ bias4, const int* __restrict__ pp, float* __restrict__ zz) {
  __shared__ ushort Ks[64 * 64];
  __shared__ ushort Vts[64 * 64];
  __shared__ ushort Pl[8][16 * 64];
  const int rb = blockIdx.x, h = blockIdx.y, b = blockIdx.z;
  const int n0 = rb * 128;
  const int t = threadIdx.x, w = t >> 6, lane = t & 63, lg = lane >> 4, lm = lane & 15;
  const int qbase = n0 + w * 16;
  const ushort* qrow = qg + (size_t)(b * NN + qbase + lm) * HH + h * ASZ;
  bf16x8 qf[2];
  qf[0] = *(const bf16x8*)(qrow + lg * 8);
  qf[1] = *(const bf16x8*)(qrow + lg * 8 + 32);
  int cw[4]; float bw[4][3];
#pragma unroll
  for (int r = 0; r < 4; ++r) {
    float4 bz = bias4[b * NN + qbase + lg * 4 + r];
    cw[r] = __float_as_int(bz.x); bw[r][0] = bz.y; bw[r][1] = bz.z; bw[r][2] = bz.w;
  }
  float mr[4] = {-1e30f, -1e30f, -1e30f, -1e30f};
  float lr[4] = {0.f, 0.f, 0.f, 0.f};
  f32x4 y[4] = {};
  const ushort* kb = kg + (size_t)(b * NN) * HH + h * ASZ;
  const ushort* vtb = vtg + (size_t)(b * NHD + h) * ASZ * NN;
  const int srow = t >> 3, sc = t & 7;   // 512 threads = 64 rows x 8 chunks
  for (int tile = 0; tile < 16; ++tile) {
    const int c0 = tile * 64;
    __syncthreads();
    {
      uint4 kv = *(const uint4*)(kb + (size_t)(c0 + srow) * HH + sc * 8);
      *(uint4*)&Ks[srow * 64 + ((sc ^ (srow & 7)) * 8)] = kv;
      uint4 vv = *(const uint4*)(vtb + (size_t)srow * NN + c0 + sc * 8);
      *(uint4*)&Vts[srow * 64 + ((sc ^ (srow & 7)) * 8)] = vv;
    }
    __syncthreads();
    f32x4 s[4] = {};
#pragma unroll
    for (int nt = 0; nt < 4; ++nt) {
      int krow = lm + nt * 16, sw = krow & 7;
#pragma unroll
      for (int kt = 0; kt < 2; ++kt) {
        bf16x8 kf = *(bf16x8*)&Ks[krow * 64 + (((lg + kt * 4) ^ sw) * 8)];
        s[nt] = __builtin_amdgcn_mfma_f32_16x16x32_bf16(qf[kt], kf, s[nt], 0, 0, 0);
      }
    }
    // sparse bias windows (only tiles overlapping [qbase-2, qbase+17])
    if (c0 <= qbase + 17 && qbase <= c0 + 65) {
#pragma unroll
      for (int nt = 0; nt < 4; ++nt) {
        int kcol = c0 + nt * 16 + lm;
#pragma unroll
        for (int r = 0; r < 4; ++r) {
          int dd = kcol - cw[r];
          if (dd >= 0 && dd < 3) s[nt][r] += bw[r][dd];
        }
      }
    }
    // online softmax; exact rescale-skip when no row's max grew
    float tmx[4];
    int needi = 0;
#pragma unroll
    for (int r = 0; r < 4; ++r) {
      float tm = fmaxf(fmaxf(s[0][r], s[1][r]), fmaxf(s[2][r], s[3][r]));
      tm = fmaxf(tm, __shfl_xor(tm, 1));
      tm = fmaxf(tm, __shfl_xor(tm, 2));
      tm = fmaxf(tm, __shfl_xor(tm, 4));
      tm = fmaxf(tm, __shfl_xor(tm, 8));
      tmx[r] = tm;
      needi |= (tm > mr[r]) ? 1 : 0;
    }
    if (__any(needi)) {
#pragma unroll
      for (int r = 0; r < 4; ++r) {
        float mn = fmaxf(mr[r], tmx[r]);
        float f = __expf(mr[r] - mn);
        mr[r] = mn;
        lr[r] *= f;
#pragma unroll
        for (int nt = 0; nt < 4; ++nt) y[nt][r] *= f;
      }
    }
    float ts[4] = {0.f, 0.f, 0.f, 0.f};
#pragma unroll
    for (int nt = 0; nt < 4; ++nt)
#pragma unroll
      for (int r = 0; r < 4; ++r) {
        float p = __expf(s[nt][r] - mr[r]);
        s[nt][r] = p; ts[r] += p;
      }
#pragma unroll
    for (int r = 0; r < 4; ++r) {
      float v = ts[r];
      v += __shfl_xor(v, 1); v += __shfl_xor(v, 2);
      v += __shfl_xor(v, 4); v += __shfl_xor(v, 8);
      lr[r] += v;
    }
    // P: C-layout -> per-wave swizzled LDS -> A-layout
#pragma unroll
    for (int nt = 0; nt < 4; ++nt)
#pragma unroll
      for (int r = 0; r < 4; ++r) {
        int prow = lg * 4 + r, pcol = lm + nt * 16;
        Pl[w][prow * 64 + (((pcol >> 3) ^ (prow & 7)) * 8) + (pcol & 7)] = f2bf(s[nt][r]);
      }
    asm volatile("s_waitcnt lgkmcnt(0)" ::: "memory");
    __builtin_amdgcn_sched_barrier(0);
    bf16x8 pa[2];
#pragma unroll
    for (int kt = 0; kt < 2; ++kt)
      pa[kt] = *(bf16x8*)&Pl[w][lm * 64 + (((lg + kt * 4) ^ (lm & 7)) * 8)];
#pragma unroll
    for (int nt = 0; nt < 4; ++nt) {
      int vrow = lm + nt * 16, sw = vrow & 7;
#pragma unroll
      for (int kt = 0; kt < 2; ++kt) {
        bf16x8 vf = *(bf16x8*)&Vts[vrow * 64 + (((lg + kt * 4) ^ sw) * 8)];
        y[nt] = __builtin_amdgcn_mfma_f32_16x16x32_bf16(pa[kt], vf, y[nt], 0, 0, 0);
      }
    }
  }
  // epilogue: weighted row-sums into z1/z2
  float inv[4], c1v[4], c2v[4];
#pragma unroll
  for (int r = 0; r < 4; ++r) {
    inv[r] = 1.f / lr[r];
    coefs(pp + b * NN, qbase + lg * 4 + r, c1v[r], c2v[r]);
  }
  float a1[4], a2[4];
#pragma unroll
  for (int nt = 0; nt < 4; ++nt) {
    float u1 = 0.f, u2 = 0.f;
#pragma unroll
    for (int r = 0; r < 4; ++r) {
      float yv = y[nt][r] * inv[r];
      u1 += c1v[r] * yv;
      u2 += c2v[r] * yv;
    }
    u1 += __shfl_xor(u1, 16); u1 += __shfl_xor(u1, 32);
    u2 += __shfl_xor(u2, 16); u2 += __shfl_xor(u2, 32);
    a1[nt] = u1; a2[nt] = u2;
  }
  if (lg == 0) {
#pragma unroll
    for (int nt = 0; nt < 4; ++nt) {
      atomicAdd(&zz[b * HH + h * ASZ + nt * 16 + lm], a1[nt]);
      atomicAdd(&zz[BB * HH + b * HH + h * ASZ + nt * 16 + lm], a2[nt]);
    }
  }
}

// ============ F1: t_s = W_o @ (z_s / sumw) + b_o ============
__global__ void k_f1(const float* __restrict__ Wo, const float* __restrict__ bo,
                     const float* __restrict__ zz, const float* __restrict__ sumw,
                     float* __restrict__ tvec) {
  int b = blockIdx.y;
  int w = threadIdx.x >> 6, lane = threadIdx.x & 63;
  float inv = 1.f / sumw[b];
  const float* z1 = zz + b * HH;
  const float* z2 = zz + BB * HH + b * HH;
  float zr1[12], zr2[12];
#pragma unroll
  for (int m = 0; m < 12; ++m) { zr1[m] = z1[lane + 64 * m] * inv; zr2[m] = z2[lane + 64 * m] * inv; }
  for (int j = 0; j < 8; ++j) {
    int o = blockIdx.x * 32 + w * 8 + j;
    const float* wrow = Wo + (size_t)o * HH;
    float a1 = 0.f, a2 = 0.f;
#pragma unroll
    for (int m = 0; m < 12; ++m) { float wv = wrow[lane + 64 * m]; a1 += wv * zr1[m]; a2 += wv * zr2[m]; }
    for (int mask = 32; mask; mask >>= 1) { a1 += __shfl_xor(a1, mask); a2 += __shfl_xor(a2, mask); }
    if (lane == 0) { tvec[b * HH + o] = a1 + bo[o]; tvec[BB * HH + b * HH + o] = a2 + bo[o]; }
  }
}

// ============ F2: pm = WL @ t1 + WR @ t2 + b_atom ============
__global__ void k_f2(const float* __restrict__ Wa, const float* __restrict__ ba,
                     const float* __restrict__ tvec, float* __restrict__ pm) {
  int b = blockIdx.y;
  int w = threadIdx.x >> 6, lane = threadIdx.x & 63;
  const float* t1 = tvec + b * HH;
  const float* t2 = tvec + BB * HH + b * HH;
  float r1[12], r2[12];
#pragma unroll
  for (int m = 0; m < 12; ++m) { r1[m] = t1[lane + 64 * m]; r2[m] = t2[lane + 64 * m]; }
  for (int j = 0; j < 8; ++j) {
    int o = blockIdx.x * 32 + w * 8 + j;
    const float* wrow = Wa + (size_t)o * (2 * HH);
    float a = 0.f;
#pragma unroll
    for (int m = 0; m < 12; ++m) a += wrow[lane + 64 * m] * r1[m];
#pragma unroll
    for (int m = 0; m < 12; ++m) a += wrow[HH + lane + 64 * m] * r2[m];
    for (int mask = 32; mask; mask >>= 1) a += __shfl_xor(a, mask);
    if (lane == 0) pm[b * HH + o] = a + ba[o];
  }
}

// ============ F3: broadcast pm to (B,N,H) ============
__global__ void k_bcast(const float* __restrict__ pm, float* __restrict__ out) {
  size_t g = (size_t)blockIdx.x * 256 + threadIdx.x;
  int b = (int)(g / ((size_t)NN * HH / 4));
  int hh4 = (int)(g % (HH / 4));
  float4 val = *(const float4*)(pm + b * HH + hh4 * 4);
  *(float4*)(out + g * 4) = val;
}

// ================= launcher =================
extern "C" void kernel_launch(void* const* d_in, const int* in_sizes, int n_in,
                              void* d_out, int out_size, void* d_ws, size_t ws_size,
                              hipStream_t stream) {
  (void)in_sizes; (void)n_in; (void)out_size; (void)ws_size;
  const float* x       = (const float*)d_in[0];
  const float* W_var   = (const float*)d_in[3];
  const float* b_var   = (const float*)d_in[4];
  const float* W_sym   = (const float*)d_in[5];
  const float* b_sym   = (const float*)d_in[6];
  const float* W_score = (const float*)d_in[7];
  const float* b_score = (const float*)d_in[8];
  const float* W_cross = (const float*)d_in[9];
  const float* b_cross = (const float*)d_in[10];
  const float* W_atom  = (const float*)d_in[11];
  const float* b_atom  = (const float*)d_in[12];
  const float* W_q     = (const float*)d_in[13];
  const float* b_q     = (const float*)d_in[14];
  const float* W_k     = (const float*)d_in[15];
  const float* b_k     = (const float*)d_in[16];
  const float* W_v     = (const float*)d_in[17];
  const float* b_v     = (const float*)d_in[18];
  const float* W_o     = (const float*)d_in[19];
  const float* b_o     = (const float*)d_in[20];
  const int*   pp      = (const int*)d_in[21];
  const int*   occ     = (const int*)d_in[24];
  float* out = (float*)d_out;
  char* wsb = (char*)d_ws;
  ushort* qb  = (ushort*)(wsb + OFFB_QB);
  ushort* kbf = (ushort*)(wsb + OFFB_KB);
  ushort* vtb = (ushort*)(wsb + OFFB_VB);
  ushort* xb  = (ushort*)(wsb + OFFB_XB);
  ushort* wqb = (ushort*)(wsb + OFFB_WQB);
  ushort* wkb = (ushort*)(wsb + OFFB_WKB);
  ushort* wvb = (ushort*)(wsb + OFFB_WVB);
  ushort* wvar = (ushort*)(wsb + OFFB_WVAR);
  ushort* wsym = (ushort*)(wsb + OFFB_WSYM);
  float* sraw = (float*)(wsb + OFFB_SRAW);
  float* diag = (float*)(wsb + OFFB_DIAG);
  float4* bias4 = (float4*)(wsb + OFFB_BIAS4);
  int* plist = (int*)(wsb + OFFB_PLIST);
  int* pcnt  = (int*)(wsb + OFFB_PCNT);
  float* sumw = (float*)(wsb + OFFB_SUMW);
  float* zz   = (float*)(wsb + OFFB_ZZ);
  float* tv   = (float*)(wsb + OFFB_TV);
  float* pm   = (float*)(wsb + OFFB_PM);

  hipMemsetAsync(sraw, 0, BB * NN * sizeof(float), stream);
  hipMemsetAsync(diag, 0, BB * NN * sizeof(float), stream);
  hipMemsetAsync(zz, 0, 2 * BB * HH * sizeof(float), stream);

  k_pred<<<BB, 64, 0, stream>>>(pp, plist, pcnt, sumw);
  // f32 -> bf16 conversions
  k_cvt<<<(BB * NN * HH / 4 + 255) / 256, 256, 0, stream>>>(x, xb, BB * NN * HH / 4);
  k_cvt<<<(HH * HH / 4 + 255) / 256, 256, 0, stream>>>(W_q, wqb, HH * HH / 4);
  k_cvt<<<(HH * HH / 4 + 255) / 256, 256, 0, stream>>>(W_k, wkb, HH * HH / 4);
  k_cvt<<<(HH * HH / 4 + 255) / 256, 256, 0, stream>>>(W_v, wvb, HH * HH / 4);
  k_cvt<<<(HH * HH / 4 + 255) / 256, 256, 0, stream>>>(W_var, wvar, HH * HH / 4);
  k_cvt<<<(HH * HH / 4 + 255) / 256, 256, 0, stream>>>(W_sym, wsym, HH * HH / 4);
  // score path (bf16 MFMA, fused var+sym over 1536 cols)
  k_score_mf<<<dim3(12, 8, BB), 256, 0, stream>>>(xb, pp, plist, pcnt, wvar, wsym,
                                                  b_var, b_sym, W_score, sraw);
  k_cross<<<BB * MM / 4, 256, 0, stream>>>(x, occ, W_cross, b_cross, diag);
  k_bias<<<BB * NN / 256, 256, 0, stream>>>(pp, sraw, diag, b_score, bias4);
  // fused QKV MFMA GEMM (bf16); V written transposed
  k_gemm_bf<<<dim3(64, 6, 3), 256, 0, stream>>>(xb, wqb, wkb, wvb, b_q, b_k, b_v, qb, kbf, vtb);
  // MFMA flash attention (128 q-rows/block, 8 waves)
  k_attn2<<<dim3(NN / 128, NHD, BB), 512, 0, stream>>>(qb, kbf, vtb, bias4, pp, zz);
  k_f1<<<dim3(24, BB), 256, 0, stream>>>(W_o, b_o, zz, sumw, tv);
  k_f2<<<dim3(24, BB), 256, 0, stream>>>(W_atom, b_atom, tv, pm);
  k_bcast<<<BB * NN * HH / 1024, 256, 0, stream>>>(pm, out);
}

// Round 6
// 218.572 us; speedup vs baseline: 6.4710x; 1.1471x over previous
//
#include <hip/hip_runtime.h>
#include <hip/hip_bf16.h>

// ================= problem constants =================
#define BB 8
#define NN 1024
#define HH 768
#define NHD 12
#define ASZ 64
#define MM 256
#define QSCALE 0.125f   // AS^-0.5
#define NSLOPE 0.02f

typedef __attribute__((ext_vector_type(8))) short bf16x8;
typedef __attribute__((ext_vector_type(4))) float f32x4;

// ============ workspace layout (byte offsets, all 16B-aligned) ============
#define OFFB_QB    ((size_t)0)            // 8*1024*768 bf16
#define OFFB_KB    ((size_t)12582912)
#define OFFB_VB    ((size_t)25165824)     // V^T: [b][h][d][n] bf16
#define OFFB_XB    ((size_t)37748736)     // x in bf16
#define OFFB_WQB   ((size_t)50331648)     // 768*768 bf16
#define OFFB_WKB   ((size_t)51511296)
#define OFFB_WVB   ((size_t)52690944)
#define OFFB_WVAR  ((size_t)53870592)     // W_var bf16
#define OFFB_WSYM  ((size_t)55050240)     // W_sym bf16
#define OFFB_SRAW  ((size_t)56229888)     // 8192 f32
#define OFFB_DIAG  ((size_t)56262656)     // 8192 f32
#define OFFB_BIAS4 ((size_t)56295424)     // 8192 float4
#define OFFB_PLIST ((size_t)56426496)     // 8192 i32
#define OFFB_PCNT  ((size_t)56459264)
#define OFFB_SUMW  ((size_t)56459296)
#define OFFB_ZZ    ((size_t)56459328)     // 2*8*768 f32
#define OFFB_TV    ((size_t)56508480)
#define OFFB_PM    ((size_t)56557632)

__device__ __forceinline__ float lrelu(float v) { return v >= 0.f ? v : NSLOPE * v; }

__device__ __forceinline__ ushort f2bf(float f) {  // RNE f32->bf16
  union { float f; unsigned u; } v; v.f = f;
  unsigned r = (v.u + 0x7fffu + ((v.u >> 16) & 1u)) >> 16;
  return (ushort)r;
}
__device__ __forceinline__ float bf2f(ushort u) {
  union { unsigned u; float f; } v; v.u = (unsigned)u << 16;
  return v.f;
}

// weights for the final weighted row-sums of y (derived from pm algebra).
__device__ __forceinline__ void coefs(const int* ppb, int j, float& c1, float& c2) {
  auto pred = [&](int tt) { return tt >= 0 && tt < NN && ppb[tt] == 1; };
  auto single = [&](int tt) { return tt == 0 || (tt >= 2 && ppb[tt - 2] == 1); };
  auto wgt = [&](int tt) {
    if (!pred(tt)) return 0.f;
    bool tri = (tt >= 1) && (tt <= 1 || !single(tt));
    return tri ? 3.f : 2.f;
  };
  float a = 0.f;
  if (pred(j + 1)) a += wgt(j + 1) * (single(j + 1) ? 0.f : 0.5f);
  if (j >= 1 && pred(j - 1)) a += wgt(j - 1) * (single(j - 1) ? 1.f : 0.5f);
  c1 = a;
  c2 = wgt(j);
}

// ============ K_cvt: f32 -> bf16 (vectorized) ============
__global__ void k_cvt(const float* __restrict__ src, ushort* __restrict__ dst, int n4) {
  int i = blockIdx.x * 256 + threadIdx.x;
  if (i >= n4) return;
  float4 v = ((const float4*)src)[i];
  ushort4 o;
  o.x = f2bf(v.x); o.y = f2bf(v.y); o.z = f2bf(v.z); o.w = f2bf(v.w);
  ((ushort4*)dst)[i] = o;
}

// ============ K_cvt5: five HHxHH weights in one dispatch ============
__global__ void k_cvt5(const float* __restrict__ s0, const float* __restrict__ s1,
                       const float* __restrict__ s2, const float* __restrict__ s3,
                       const float* __restrict__ s4,
                       ushort* __restrict__ d0, ushort* __restrict__ d1,
                       ushort* __restrict__ d2, ushort* __restrict__ d3,
                       ushort* __restrict__ d4) {
  int z = blockIdx.y;
  const float* src = z == 0 ? s0 : z == 1 ? s1 : z == 2 ? s2 : z == 3 ? s3 : s4;
  ushort* dst = z == 0 ? d0 : z == 1 ? d1 : z == 2 ? d2 : z == 3 ? d3 : d4;
  int i = blockIdx.x * 256 + threadIdx.x;   // HH*HH/4 = 147456, grid.x = 576
  float4 v = ((const float4*)src)[i];
  ushort4 o;
  o.x = f2bf(v.x); o.y = f2bf(v.y); o.z = f2bf(v.z); o.w = f2bf(v.w);
  ((ushort4*)dst)[i] = o;
}

// ============ K_pred: compact predicate list + sum of weights ============
__global__ void k_pred(const int* __restrict__ pp, int* __restrict__ plist,
                       int* __restrict__ pcnt, float* __restrict__ sumw) {
  int b = blockIdx.x;
  int lane = threadIdx.x;  // blockDim 64
  const int* ppb = pp + b * NN;
  int base = 0;
  float wacc = 0.f;
  for (int c = 0; c < NN; c += 64) {
    int i = c + lane;
    bool isp = ppb[i] == 1;
    unsigned long long mask = __ballot(isp);
    if (isp) {
      int pos = base + __popcll(mask & ((1ull << lane) - 1ull));
      plist[b * NN + pos] = i;
      bool sing = (i == 0) || (i >= 2 && ppb[i - 2] == 1);
      bool tri = (i >= 1) && (i <= 1 || !sing);
      wacc += tri ? 3.f : 2.f;
    }
    base += __popcll(mask);
  }
  for (int off = 32; off; off >>= 1) wacc += __shfl_xor(wacc, off);
  if (lane == 0) { pcnt[b] = base; sumw[b] = wacc; }
}

// ============ K_cross: occurrence-pair scores -> diag ============
__global__ void k_cross(const float* __restrict__ x, const int* __restrict__ occ,
                        const float* __restrict__ Wc, const float* __restrict__ bc,
                        float* __restrict__ diag) {
  int g = blockIdx.x * 4 + (threadIdx.x >> 6);
  int lane = threadIdx.x & 63;
  int b = g >> 8, m = g & (MM - 1);
  int o0 = occ[(b * MM + m) * 2 + 0];
  int o1 = occ[(b * MM + m) * 2 + 1];
  const float* x0 = x + (size_t)(b * NN + o0) * HH;
  const float* x1 = x + (size_t)(b * NN + o1) * HH;
  float acc = 0.f;
  for (int d = lane; d < HH; d += 64) acc += 0.5f * (x0[d] + x1[d]) * Wc[d];
  for (int off = 32; off; off >>= 1) acc += __shfl_xor(acc, off);
  if (lane == 0) {
    float sc = lrelu(acc + bc[0]);
    float sq = sc * sc;
    diag[b * NN + o0] = sq;
    diag[b * NN + o1] = sq;
  }
}

// ============ K_score_mf: bf16 MFMA score GEMM over gathered predicate rows ============
__global__ __launch_bounds__(256, 2) void k_score_mf(
    const ushort* __restrict__ xb, const int* __restrict__ pp,
    const int* __restrict__ plist, const int* __restrict__ pcnt,
    const ushort* __restrict__ Wvar, const ushort* __restrict__ Wsym,
    const float* __restrict__ bvar, const float* __restrict__ bsym,
    const float* __restrict__ wscore, float* __restrict__ s_raw) {
  const int b = blockIdx.z;
  const int cnt = pcnt[b];
  const int j0 = blockIdx.y * 128;
  if (j0 >= cnt) return;
  const int n0g = blockIdx.x * 128;           // global col in [0,1536)
  const bool symh = n0g >= HH;
  const int n0 = symh ? n0g - HH : n0g;
  const ushort* W = symh ? Wsym : Wvar;
  const float* bias = symh ? bsym : bvar;
  __shared__ ushort As[128 * 64];
  __shared__ ushort Bs[128 * 64];
  __shared__ int pl[128];
  __shared__ float wA_[128], wB_[128];
  __shared__ float red[128];
  const int t = threadIdx.x;
  const int w = t >> 6, lane = t & 63, lg = lane >> 4, lm = lane & 15;
  const int wm = (w >> 1) * 64, wn = (w & 1) * 64;
  if (t < 128) {
    int j = j0 + t;
    int i = (j < cnt) ? plist[b * NN + j] : 2;
    pl[t] = i;
    bool sing = (i == 0) || (i >= 2 && pp[b * NN + i - 2] == 1);
    wA_[t] = sing ? 0.f : 0.5f;
    wB_[t] = sing ? 1.f : 0.5f;
    red[t] = 0.f;
  }
  __syncthreads();
  f32x4 acc[4][4] = {};
  const ushort* xbb = xb + (size_t)b * NN * HH;
  for (int k0 = 0; k0 < HH; k0 += 64) {
    if (k0) __syncthreads();
#pragma unroll
    for (int it = 0; it < 4; ++it) {   // 128 rows x 8 chunks = 1024 slots
      int slot = t + it * 256;
      int row = slot >> 3, c = slot & 7;
      uint4 vb = *(const uint4*)(W + (size_t)(n0 + row) * HH + k0 + c * 8);
      *(uint4*)&Bs[row * 64 + ((c ^ (row & 7)) * 8)] = vb;
      int i = pl[row];
      uint4 va;
      if (symh) {
        va = *(const uint4*)(xbb + (size_t)i * HH + k0 + c * 8);
      } else {
        uint4 vp = *(const uint4*)(xbb + (size_t)((i - 1) & (NN - 1)) * HH + k0 + c * 8);
        uint4 vn = *(const uint4*)(xbb + (size_t)((i + 1) & (NN - 1)) * HH + k0 + c * 8);
        float wa = wA_[row], wb2 = wB_[row];
        const ushort* pu = (const ushort*)&vp;
        const ushort* nu = (const ushort*)&vn;
        ushort* ou = (ushort*)&va;
#pragma unroll
        for (int e = 0; e < 8; ++e)
          ou[e] = f2bf(wa * bf2f(pu[e]) + wb2 * bf2f(nu[e]));
      }
      *(uint4*)&As[row * 64 + ((c ^ (row & 7)) * 8)] = va;
    }
    __syncthreads();
    bf16x8 af[4][2], bfr[4][2];
#pragma unroll
    for (int mt = 0; mt < 4; ++mt)
#pragma unroll
      for (int kt = 0; kt < 2; ++kt) {
        int row = wm + mt * 16 + lm, ch = lg + kt * 4;
        af[mt][kt] = *(bf16x8*)&As[row * 64 + ((ch ^ (row & 7)) * 8)];
      }
#pragma unroll
    for (int nt = 0; nt < 4; ++nt)
#pragma unroll
      for (int kt = 0; kt < 2; ++kt) {
        int row = wn + nt * 16 + lm, ch = lg + kt * 4;
        bfr[nt][kt] = *(bf16x8*)&Bs[row * 64 + ((ch ^ (row & 7)) * 8)];
      }
#pragma unroll
    for (int mt = 0; mt < 4; ++mt)
#pragma unroll
      for (int nt = 0; nt < 4; ++nt)
#pragma unroll
        for (int kt = 0; kt < 2; ++kt)
          acc[mt][nt] = __builtin_amdgcn_mfma_f32_16x16x32_bf16(af[mt][kt], bfr[nt][kt], acc[mt][nt], 0, 0, 0);
  }
  // epilogue: tanh + dot with W_score, reduce cols
  float bcol[4], wcol[4];
#pragma unroll
  for (int nt = 0; nt < 4; ++nt) {
    int cl = wn + nt * 16 + lm;
    bcol[nt] = bias[n0 + cl];
    wcol[nt] = wscore[n0g + cl];
  }
#pragma unroll
  for (int mt = 0; mt < 4; ++mt)
#pragma unroll
    for (int r = 0; r < 4; ++r) {
      float p = 0.f;
#pragma unroll
      for (int nt = 0; nt < 4; ++nt)
        p += tanhf(acc[mt][nt][r] + bcol[nt]) * wcol[nt];
      p += __shfl_xor(p, 1); p += __shfl_xor(p, 2);
      p += __shfl_xor(p, 4); p += __shfl_xor(p, 8);
      if (lm == 0) atomicAdd(&red[wm + mt * 16 + lg * 4 + r], p);
    }
  __syncthreads();
  if (t < 128) {
    int j2 = j0 + t;
    if (j2 < cnt) atomicAdd(&s_raw[b * NN + pl[t]], red[t]);
  }
}

// ============ K_bias: per-row sparse bias window ============
__global__ void k_bias(const int* __restrict__ pp, const float* __restrict__ s_raw,
                       const float* __restrict__ diag, const float* __restrict__ b_score,
                       float4* __restrict__ bias4) {
  int g = blockIdx.x * 256 + threadIdx.x;
  int b = g >> 10, r = g & (NN - 1);
  const int* ppb = pp + b * NN;
  int i = -1;
  if (ppb[r] == 1) i = r;
  else if (r + 1 < NN && ppb[r + 1] == 1) i = r + 1;
  else if (r >= 1 && ppb[r - 1] == 1) i = r - 1;
  float v0 = 0.f, v1 = 0.f, v2 = 0.f; int cw = r;
  if (i >= 1 && i + 1 < NN) {
    float s = lrelu(s_raw[b * NN + i] + b_score[0]);
    float s2 = s * s;
    cw = i - 1;
    if (i == r) { v0 = 0.2f * s; v1 = 1.6f * s2; v2 = 0.2f * s; }
    else       { v0 = 0.8f * s2; v1 = 0.2f * s; v2 = 0.8f * s2; }
  }
  int slot = r - cw;
  float d = diag[g];
  if (slot == 0) v0 += d; else if (slot == 1) v1 += d; else v2 += d;
  bias4[g] = make_float4(__int_as_float(cw), v0, v1, v2);
}

// ============ K_gemm_bf: fused QKV bf16 MFMA GEMM ============
// z=0: Q row-major *QSCALE ; z=1: K row-major ; z=2: V^T [b][h][d][n]
__global__ __launch_bounds__(256, 2) void k_gemm_bf(
    const ushort* __restrict__ X,
    const ushort* __restrict__ W0, const ushort* __restrict__ W1, const ushort* __restrict__ W2,
    const float* __restrict__ b0, const float* __restrict__ b1, const float* __restrict__ b2,
    ushort* __restrict__ C0, ushort* __restrict__ C1, ushort* __restrict__ C2) {
  const int z = blockIdx.z;
  const ushort* W = z == 0 ? W0 : (z == 1 ? W1 : W2);
  const float* bias = z == 0 ? b0 : (z == 1 ? b1 : b2);
  ushort* C = z == 0 ? C0 : (z == 1 ? C1 : C2);
  const float alpha = z == 0 ? QSCALE : 1.f;
  __shared__ ushort As[128 * 64];
  __shared__ ushort Bs[128 * 64];
  const int m0 = blockIdx.x * 128, n0 = blockIdx.y * 128;
  const int t = threadIdx.x;
  const int w = t >> 6, lane = t & 63, lg = lane >> 4, lm = lane & 15;
  const int wm = (w >> 1) * 64, wn = (w & 1) * 64;
  f32x4 acc[4][4] = {};
  for (int k0 = 0; k0 < HH; k0 += 64) {
    __syncthreads();
#pragma unroll
    for (int it = 0; it < 4; ++it) {
      int slot = t + it * 256;
      int row = slot >> 3, c = slot & 7;
      uint4 va = *(const uint4*)(X + (size_t)(m0 + row) * HH + k0 + c * 8);
      *(uint4*)&As[row * 64 + ((c ^ (row & 7)) * 8)] = va;
      uint4 vb = *(const uint4*)(W + (size_t)(n0 + row) * HH + k0 + c * 8);
      *(uint4*)&Bs[row * 64 + ((c ^ (row & 7)) * 8)] = vb;
    }
    __syncthreads();
    bf16x8 af[4][2], bfr[4][2];
#pragma unroll
    for (int mt = 0; mt < 4; ++mt)
#pragma unroll
      for (int kt = 0; kt < 2; ++kt) {
        int row = wm + mt * 16 + lm, ch = lg + kt * 4;
        af[mt][kt] = *(bf16x8*)&As[row * 64 + ((ch ^ (row & 7)) * 8)];
      }
#pragma unroll
    for (int nt = 0; nt < 4; ++nt)
#pragma unroll
      for (int kt = 0; kt < 2; ++kt) {
        int row = wn + nt * 16 + lm, ch = lg + kt * 4;
        bfr[nt][kt] = *(bf16x8*)&Bs[row * 64 + ((ch ^ (row & 7)) * 8)];
      }
#pragma unroll
    for (int mt = 0; mt < 4; ++mt)
#pragma unroll
      for (int nt = 0; nt < 4; ++nt)
#pragma unroll
        for (int kt = 0; kt < 2; ++kt)
          acc[mt][nt] = __builtin_amdgcn_mfma_f32_16x16x32_bf16(af[mt][kt], bfr[nt][kt], acc[mt][nt], 0, 0, 0);
  }
  if (z == 2) {
    // V^T write: 4 consecutive token rows packed per store
#pragma unroll
    for (int nt = 0; nt < 4; ++nt) {
      int col = n0 + wn + nt * 16 + lm;
      int hh = col >> 6, dd = col & 63;
      float bcol = bias[col];
#pragma unroll
      for (int mt = 0; mt < 4; ++mt) {
        int row0 = m0 + wm + mt * 16 + lg * 4;
        int bb2 = row0 >> 10, nr = row0 & (NN - 1);
        ushort4 o;
        o.x = f2bf(acc[mt][nt][0] + bcol);
        o.y = f2bf(acc[mt][nt][1] + bcol);
        o.z = f2bf(acc[mt][nt][2] + bcol);
        o.w = f2bf(acc[mt][nt][3] + bcol);
        *(ushort4*)(C + ((size_t)(bb2 * NHD + hh) * ASZ + dd) * NN + nr) = o;
      }
    }
  } else {
#pragma unroll
    for (int nt = 0; nt < 4; ++nt) {
      int col = n0 + wn + nt * 16 + lm;
      float bcol = bias[col];
#pragma unroll
      for (int mt = 0; mt < 4; ++mt)
#pragma unroll
        for (int r = 0; r < 4; ++r) {
          int row = m0 + wm + mt * 16 + lg * 4 + r;
          C[(size_t)row * HH + col] = f2bf((acc[mt][nt][r] + bcol) * alpha);
        }
    }
  }
}

// ============ K_attn2: swapped-QK^T MFMA flash attention, in-register P ============
// 8 waves x 16 q-rows (128 q/block). s = mfma(K,Q): lane owns q-row (qbase+lm),
// k-slots = physical K rows nt*16+lg*4+r. K staged with row permutation
// a(t)=[t5,t2,t4,t3,t1,t0] so P registers ARE the PV A-frag after bf16 pack.
__global__ __launch_bounds__(512, 2) void k_attn2(
    const ushort* __restrict__ qg, const ushort* __restrict__ kg, const ushort* __restrict__ vtg,
    const float4* __restrict__ bias4, const int* __restrict__ pp, float* __restrict__ zz) {
  __shared__ ushort Ks[64 * 64];
  __shared__ ushort Vts[64 * 64];
  const int rb = blockIdx.y, h = blockIdx.x >> 3, b = blockIdx.x & 7;
  const int n0 = rb * 128;
  const int t = threadIdx.x, w = t >> 6, lane = t & 63, lg = lane >> 4, lm = lane & 15;
  const int qbase = n0 + w * 16;
  const ushort* qrow = qg + (size_t)(b * NN + qbase + lm) * HH + h * ASZ;
  bf16x8 qf[2];
  qf[0] = *(const bf16x8*)(qrow + lg * 8);
  qf[1] = *(const bf16x8*)(qrow + lg * 8 + 32);
  // per-lane single q-row bias window
  float4 bz = bias4[b * NN + qbase + lm];
  const int cwq = __float_as_int(bz.x);
  float mr = -1e30f, lr = 0.f;   // online softmax state for q = qbase+lm
  f32x4 y[4] = {};
  const ushort* kb = kg + (size_t)(b * NN) * HH + h * ASZ;
  const ushort* vtb = vtg + (size_t)(b * NHD + h) * ASZ * NN;
  const int srow = t >> 3, sc = t & 7;   // 512 threads = 64 rows x 8 chunks
  const int arow = (srow & 35) | ((srow & 4) << 2) | ((srow & 24) >> 1);  // K row permutation
  for (int tile = 0; tile < 16; ++tile) {
    const int c0 = tile * 64;
    __syncthreads();
    {
      uint4 kv = *(const uint4*)(kb + (size_t)(c0 + srow) * HH + sc * 8);
      *(uint4*)&Ks[arow * 64 + ((sc ^ (arow & 7)) * 8)] = kv;
      uint4 vv = *(const uint4*)(vtb + (size_t)srow * NN + c0 + sc * 8);
      *(uint4*)&Vts[srow * 64 + ((sc ^ (srow & 7)) * 8)] = vv;
    }
    __syncthreads();
    f32x4 s[4] = {};
#pragma unroll
    for (int nt = 0; nt < 4; ++nt) {
      int krow = lm + nt * 16, sw = krow & 7;
#pragma unroll
      for (int kt = 0; kt < 2; ++kt) {
        bf16x8 kf = *(bf16x8*)&Ks[krow * 64 + (((lg + kt * 4) ^ sw) * 8)];
        s[nt] = __builtin_amdgcn_mfma_f32_16x16x32_bf16(kf, qf[kt], s[nt], 0, 0, 0);
      }
    }
    // sparse bias: token of s[nt][r] = c0 + (nt>>1)*32 + lg*8 + (nt&1)*4 + r
    if (c0 <= qbase + 17 && qbase <= c0 + 65) {
#pragma unroll
      for (int nt = 0; nt < 4; ++nt) {
        int kb2 = c0 + (nt >> 1) * 32 + lg * 8 + (nt & 1) * 4;
#pragma unroll
        for (int r = 0; r < 4; ++r) {
          int dd = kb2 + r - cwq;
          if (dd >= 0 && dd < 3) s[nt][r] += (dd == 0) ? bz.y : (dd == 1 ? bz.z : bz.w);
        }
      }
    }
    // online softmax: row is lane-local (16 regs) + 2 shfl over lg groups
    f32x4 m4;
#pragma unroll
    for (int e = 0; e < 4; ++e)
      m4[e] = fmaxf(fmaxf(s[0][e], s[1][e]), fmaxf(s[2][e], s[3][e]));
    float tm = fmaxf(fmaxf(m4[0], m4[1]), fmaxf(m4[2], m4[3]));
    tm = fmaxf(tm, __shfl_xor(tm, 16));
    tm = fmaxf(tm, __shfl_xor(tm, 32));
    int need = tm > mr;
    if (__any(need)) {
      float mn = fmaxf(mr, tm);
      float f = __expf(mr - mn);
      mr = mn;
      lr *= f;
      float fr[4];
#pragma unroll
      for (int r = 0; r < 4; ++r) fr[r] = __shfl(f, lg * 4 + r);
#pragma unroll
      for (int nt = 0; nt < 4; ++nt)
#pragma unroll
        for (int r = 0; r < 4; ++r) y[nt][r] *= fr[r];
    }
    f32x4 sum4 = {0.f, 0.f, 0.f, 0.f};
#pragma unroll
    for (int nt = 0; nt < 4; ++nt)
#pragma unroll
      for (int e = 0; e < 4; ++e) {
        float p = __expf(s[nt][e] - mr);
        s[nt][e] = p;
        sum4[e] += p;
      }
    float ts = (sum4[0] + sum4[1]) + (sum4[2] + sum4[3]);
    ts += __shfl_xor(ts, 16);
    ts += __shfl_xor(ts, 32);
    lr += ts;
    // pack P into PV A-frags (register-local, no cross-lane)
    bf16x8 pa[2];
#pragma unroll
    for (int kt = 0; kt < 2; ++kt) {
      ushort* pu = (ushort*)&pa[kt];
#pragma unroll
      for (int r = 0; r < 4; ++r) {
        pu[r] = f2bf(s[2 * kt][r]);
        pu[4 + r] = f2bf(s[2 * kt + 1][r]);
      }
    }
#pragma unroll
    for (int nt = 0; nt < 4; ++nt) {
      int vrow = lm + nt * 16, sw = vrow & 7;
#pragma unroll
      for (int kt = 0; kt < 2; ++kt) {
        bf16x8 vf = *(bf16x8*)&Vts[vrow * 64 + (((lg + kt * 4) ^ sw) * 8)];
        y[nt] = __builtin_amdgcn_mfma_f32_16x16x32_bf16(pa[kt], vf, y[nt], 0, 0, 0);
      }
    }
  }
  // epilogue: weighted row-sums into z1/z2 (y: col lm = d, row lg*4+r = q)
  float invl = 1.f / lr;
  float invq[4], c1v[4], c2v[4];
#pragma unroll
  for (int r = 0; r < 4; ++r) {
    invq[r] = __shfl(invl, lg * 4 + r);
    coefs(pp + b * NN, qbase + lg * 4 + r, c1v[r], c2v[r]);
  }
  float a1[4], a2[4];
#pragma unroll
  for (int nt = 0; nt < 4; ++nt) {
    float u1 = 0.f, u2 = 0.f;
#pragma unroll
    for (int r = 0; r < 4; ++r) {
      float yv = y[nt][r] * invq[r];
      u1 += c1v[r] * yv;
      u2 += c2v[r] * yv;
    }
    u1 += __shfl_xor(u1, 16); u1 += __shfl_xor(u1, 32);
    u2 += __shfl_xor(u2, 16); u2 += __shfl_xor(u2, 32);
    a1[nt] = u1; a2[nt] = u2;
  }
  if (lg == 0) {
#pragma unroll
    for (int nt = 0; nt < 4; ++nt) {
      atomicAdd(&zz[b * HH + h * ASZ + nt * 16 + lm], a1[nt]);
      atomicAdd(&zz[BB * HH + b * HH + h * ASZ + nt * 16 + lm], a2[nt]);
    }
  }
}

// ============ F1: t_s = W_o @ (z_s / sumw) + b_o ============
__global__ void k_f1(const float* __restrict__ Wo, const float* __restrict__ bo,
                     const float* __restrict__ zz, const float* __restrict__ sumw,
                     float* __restrict__ tvec) {
  int b = blockIdx.y;
  int w = threadIdx.x >> 6, lane = threadIdx.x & 63;
  float inv = 1.f / sumw[b];
  const float* z1 = zz + b * HH;
  const float* z2 = zz + BB * HH + b * HH;
  float zr1[12], zr2[12];
#pragma unroll
  for (int m = 0; m < 12; ++m) { zr1[m] = z1[lane + 64 * m] * inv; zr2[m] = z2[lane + 64 * m] * inv; }
  for (int j = 0; j < 8; ++j) {
    int o = blockIdx.x * 32 + w * 8 + j;
    const float* wrow = Wo + (size_t)o * HH;
    float a1 = 0.f, a2 = 0.f;
#pragma unroll
    for (int m = 0; m < 12; ++m) { float wv = wrow[lane + 64 * m]; a1 += wv * zr1[m]; a2 += wv * zr2[m]; }
    for (int mask = 32; mask; mask >>= 1) { a1 += __shfl_xor(a1, mask); a2 += __shfl_xor(a2, mask); }
    if (lane == 0) { tvec[b * HH + o] = a1 + bo[o]; tvec[BB * HH + b * HH + o] = a2 + bo[o]; }
  }
}

// ============ F2: pm = WL @ t1 + WR @ t2 + b_atom ============
__global__ void k_f2(const float* __restrict__ Wa, const float* __restrict__ ba,
                     const float* __restrict__ tvec, float* __restrict__ pm) {
  int b = blockIdx.y;
  int w = threadIdx.x >> 6, lane = threadIdx.x & 63;
  const float* t1 = tvec + b * HH;
  const float* t2 = tvec + BB * HH + b * HH;
  float r1[12], r2[12];
#pragma unroll
  for (int m = 0; m < 12; ++m) { r1[m] = t1[lane + 64 * m]; r2[m] = t2[lane + 64 * m]; }
  for (int j = 0; j < 8; ++j) {
    int o = blockIdx.x * 32 + w * 8 + j;
    const float* wrow = Wa + (size_t)o * (2 * HH);
    float a = 0.f;
#pragma unroll
    for (int m = 0; m < 12; ++m) a += wrow[lane + 64 * m] * r1[m];
#pragma unroll
    for (int m = 0; m < 12; ++m) a += wrow[HH + lane + 64 * m] * r2[m];
    for (int mask = 32; mask; mask >>= 1) a += __shfl_xor(a, mask);
    if (lane == 0) pm[b * HH + o] = a + ba[o];
  }
}

// ============ F3: broadcast pm to (B,N,H) ============
__global__ void k_bcast(const float* __restrict__ pm, float* __restrict__ out) {
  size_t g = (size_t)blockIdx.x * 256 + threadIdx.x;
  int b = (int)(g / ((size_t)NN * HH / 4));
  int hh4 = (int)(g % (HH / 4));
  float4 val = *(const float4*)(pm + b * HH + hh4 * 4);
  *(float4*)(out + g * 4) = val;
}

// ================= launcher =================
extern "C" void kernel_launch(void* const* d_in, const int* in_sizes, int n_in,
                              void* d_out, int out_size, void* d_ws, size_t ws_size,
                              hipStream_t stream) {
  (void)in_sizes; (void)n_in; (void)out_size; (void)ws_size;
  const float* x       = (const float*)d_in[0];
  const float* W_var   = (const float*)d_in[3];
  const float* b_var   = (const float*)d_in[4];
  const float* W_sym   = (const float*)d_in[5];
  const float* b_sym   = (const float*)d_in[6];
  const float* W_score = (const float*)d_in[7];
  const float* b_score = (const float*)d_in[8];
  const float* W_cross = (const float*)d_in[9];
  const float* b_cross = (const float*)d_in[10];
  const float* W_atom  = (const float*)d_in[11];
  const float* b_atom  = (const float*)d_in[12];
  const float* W_q     = (const float*)d_in[13];
  const float* b_q     = (const float*)d_in[14];
  const float* W_k     = (const float*)d_in[15];
  const float* b_k     = (const float*)d_in[16];
  const float* W_v     = (const float*)d_in[17];
  const float* b_v     = (const float*)d_in[18];
  const float* W_o     = (const float*)d_in[19];
  const float* b_o     = (const float*)d_in[20];
  const int*   pp      = (const int*)d_in[21];
  const int*   occ     = (const int*)d_in[24];
  float* out = (float*)d_out;
  char* wsb = (char*)d_ws;
  ushort* qb  = (ushort*)(wsb + OFFB_QB);
  ushort* kbf = (ushort*)(wsb + OFFB_KB);
  ushort* vtb = (ushort*)(wsb + OFFB_VB);
  ushort* xb  = (ushort*)(wsb + OFFB_XB);
  ushort* wqb = (ushort*)(wsb + OFFB_WQB);
  ushort* wkb = (ushort*)(wsb + OFFB_WKB);
  ushort* wvb = (ushort*)(wsb + OFFB_WVB);
  ushort* wvar = (ushort*)(wsb + OFFB_WVAR);
  ushort* wsym = (ushort*)(wsb + OFFB_WSYM);
  float* sraw = (float*)(wsb + OFFB_SRAW);
  float* diag = (float*)(wsb + OFFB_DIAG);
  float4* bias4 = (float4*)(wsb + OFFB_BIAS4);
  int* plist = (int*)(wsb + OFFB_PLIST);
  int* pcnt  = (int*)(wsb + OFFB_PCNT);
  float* sumw = (float*)(wsb + OFFB_SUMW);
  float* zz   = (float*)(wsb + OFFB_ZZ);
  float* tv   = (float*)(wsb + OFFB_TV);
  float* pm   = (float*)(wsb + OFFB_PM);

  hipMemsetAsync(sraw, 0, BB * NN * sizeof(float), stream);
  hipMemsetAsync(diag, 0, BB * NN * sizeof(float), stream);
  hipMemsetAsync(zz, 0, 2 * BB * HH * sizeof(float), stream);

  k_pred<<<BB, 64, 0, stream>>>(pp, plist, pcnt, sumw);
  // f32 -> bf16 conversions
  k_cvt<<<(BB * NN * HH / 4 + 255) / 256, 256, 0, stream>>>(x, xb, BB * NN * HH / 4);
  k_cvt5<<<dim3(HH * HH / 4 / 256, 5), 256, 0, stream>>>(W_q, W_k, W_v, W_var, W_sym,
                                                          wqb, wkb, wvb, wvar, wsym);
  // score path (bf16 MFMA, fused var+sym over 1536 cols)
  k_score_mf<<<dim3(12, 8, BB), 256, 0, stream>>>(xb, pp, plist, pcnt, wvar, wsym,
                                                  b_var, b_sym, W_score, sraw);
  k_cross<<<BB * MM / 4, 256, 0, stream>>>(x, occ, W_cross, b_cross, diag);
  k_bias<<<BB * NN / 256, 256, 0, stream>>>(pp, sraw, diag, b_score, bias4);
  // fused QKV MFMA GEMM (bf16); V written transposed
  k_gemm_bf<<<dim3(64, 6, 3), 256, 0, stream>>>(xb, wqb, wkb, wvb, b_q, b_k, b_v, qb, kbf, vtb);
  // MFMA flash attention (128 q-rows/block, 8 waves); grid x=(h,b) so same-(b,h)
  // blocks land on one XCD (ids differ by 96 = 0 mod 8) for K/V L2 reuse
  k_attn2<<<dim3(NHD * BB, NN / 128), 512, 0, stream>>>(qb, kbf, vtb, bias4, pp, zz);
  k_f1<<<dim3(24, BB), 256, 0, stream>>>(W_o, b_o, zz, sumw, tv);
  k_f2<<<dim3(24, BB), 256, 0, stream>>>(W_atom, b_atom, tv, pm);
  k_bcast<<<BB * NN * HH / 1024, 256, 0, stream>>>(pm, out);
}

// Round 8
// 190.140 us; speedup vs baseline: 7.4387x; 1.1495x over previous
//
#include <hip/hip_runtime.h>
#include <hip/hip_bf16.h>

// ================= problem constants =================
#define BB 8
#define NN 1024
#define HH 768
#define NHD 12
#define ASZ 64
#define MM 256
#define QSCALE 0.125f   // AS^-0.5
#define NSLOPE 0.02f
#define LOG2E 1.44269504f
#define PRMAX 384       // padded predicate rows per batch

typedef __attribute__((ext_vector_type(8))) short bf16x8;
typedef __attribute__((ext_vector_type(4))) float f32x4;

#define EXP2F(x) __builtin_amdgcn_exp2f(x)

// ============ workspace layout (byte offsets, all 16B-aligned) ============
#define OFFB_QB    ((size_t)0)            // 8*1024*768 bf16
#define OFFB_KB    ((size_t)12582912)
#define OFFB_VB    ((size_t)25165824)     // V^T: [b][h][d][n] bf16
#define OFFB_XB    ((size_t)37748736)     // x in bf16
#define OFFB_WQB   ((size_t)50331648)     // 768*768 bf16
#define OFFB_WKB   ((size_t)51511296)
#define OFFB_WVB   ((size_t)52690944)
#define OFFB_WVAR  ((size_t)53870592)     // W_var bf16
#define OFFB_WSYM  ((size_t)55050240)     // W_sym bf16
#define OFFB_SRAW  ((size_t)56229888)     // 8192 f32
#define OFFB_DIAG  ((size_t)56262656)     // 8192 f32
#define OFFB_BIAS4 ((size_t)56295424)     // 8192 float4
#define OFFB_PLIST ((size_t)56426496)     // 8192 i32
#define OFFB_PCNT  ((size_t)56459264)
#define OFFB_SUMW  ((size_t)56459296)
#define OFFB_ZZ    ((size_t)56459328)     // 2*8*768 f32
#define OFFB_TV    ((size_t)56508480)
#define OFFB_PM    ((size_t)56557632)
#define OFFB_VROWS ((size_t)56582208)     // 8*384*768 bf16 gathered var rows

__device__ __forceinline__ float lrelu(float v) { return v >= 0.f ? v : NSLOPE * v; }

__device__ __forceinline__ ushort f2bf(float f) {  // round-half-up f32->bf16 (2 ops)
  return (ushort)((__float_as_uint(f) + 0x8000u) >> 16);
}
__device__ __forceinline__ float bf2f(ushort u) {
  union { unsigned u; float f; } v; v.u = (unsigned)u << 16;
  return v.f;
}
__device__ __forceinline__ unsigned packbf2(float lo, float hi) {  // (bf(hi)<<16)|bf(lo)
  unsigned a = __float_as_uint(hi) + 0x8000u;
  unsigned b = __float_as_uint(lo) + 0x8000u;
  return __builtin_amdgcn_perm(a, b, 0x07060302u);
}

// weights for the final weighted row-sums of y (derived from pm algebra).
__device__ __forceinline__ void coefs(const int* ppb, int j, float& c1, float& c2) {
  auto pred = [&](int tt) { return tt >= 0 && tt < NN && ppb[tt] == 1; };
  auto single = [&](int tt) { return tt == 0 || (tt >= 2 && ppb[tt - 2] == 1); };
  auto wgt = [&](int tt) {
    if (!pred(tt)) return 0.f;
    bool tri = (tt >= 1) && (tt <= 1 || !single(tt));
    return tri ? 3.f : 2.f;
  };
  float a = 0.f;
  if (pred(j + 1)) a += wgt(j + 1) * (single(j + 1) ? 0.f : 0.5f);
  if (j >= 1 && pred(j - 1)) a += wgt(j - 1) * (single(j - 1) ? 1.f : 0.5f);
  c1 = a;
  c2 = wgt(j);
}

// ============ K_cvt: f32 -> bf16 (vectorized) ============
__global__ void k_cvt(const float* __restrict__ src, ushort* __restrict__ dst, int n4) {
  int i = blockIdx.x * 256 + threadIdx.x;
  if (i >= n4) return;
  float4 v = ((const float4*)src)[i];
  ushort4 o;
  o.x = f2bf(v.x); o.y = f2bf(v.y); o.z = f2bf(v.z); o.w = f2bf(v.w);
  ((ushort4*)dst)[i] = o;
}

// ============ K_cvt5: five HHxHH weights in one dispatch ============
__global__ void k_cvt5(const float* __restrict__ s0, const float* __restrict__ s1,
                       const float* __restrict__ s2, const float* __restrict__ s3,
                       const float* __restrict__ s4,
                       ushort* __restrict__ d0, ushort* __restrict__ d1,
                       ushort* __restrict__ d2, ushort* __restrict__ d3,
                       ushort* __restrict__ d4) {
  int z = blockIdx.y;
  const float* src = z == 0 ? s0 : z == 1 ? s1 : z == 2 ? s2 : z == 3 ? s3 : s4;
  ushort* dst = z == 0 ? d0 : z == 1 ? d1 : z == 2 ? d2 : z == 3 ? d3 : d4;
  int i = blockIdx.x * 256 + threadIdx.x;   // HH*HH/4 = 147456, grid.x = 576
  float4 v = ((const float4*)src)[i];
  ushort4 o;
  o.x = f2bf(v.x); o.y = f2bf(v.y); o.z = f2bf(v.z); o.w = f2bf(v.w);
  ((ushort4*)dst)[i] = o;
}

// ============ K_pred: compact predicate list + sum of weights + ws zeroing ============
__global__ void k_pred(const int* __restrict__ pp, int* __restrict__ plist,
                       int* __restrict__ pcnt, float* __restrict__ sumw,
                       float* __restrict__ sraw, float* __restrict__ diag,
                       float* __restrict__ zz) {
  int b = blockIdx.x;
  int lane = threadIdx.x;  // blockDim 64
  const int* ppb = pp + b * NN;
  int base = 0;
  float wacc = 0.f;
  for (int c = 0; c < NN; c += 64) {
    int i = c + lane;
    bool isp = ppb[i] == 1;
    unsigned long long mask = __ballot(isp);
    if (isp) {
      int pos = base + __popcll(mask & ((1ull << lane) - 1ull));
      plist[b * NN + pos] = i;
      bool sing = (i == 0) || (i >= 2 && ppb[i - 2] == 1);
      bool tri = (i >= 1) && (i <= 1 || !sing);
      wacc += tri ? 3.f : 2.f;
    }
    base += __popcll(mask);
  }
  for (int off = 32; off; off >>= 1) wacc += __shfl_xor(wacc, off);
  if (lane == 0) { pcnt[b] = base; sumw[b] = wacc; }
  // zero this batch's accumulators (replaces hipMemsetAsync)
  for (int c = lane; c < NN; c += 64) { sraw[b * NN + c] = 0.f; diag[b * NN + c] = 0.f; }
  for (int c = lane; c < HH; c += 64) {
    zz[b * HH + c] = 0.f;
    zz[BB * HH + b * HH + c] = 0.f;
  }
}

// ============ K_gather: compact var_in rows (bf16) for the score GEMM ============
__global__ void k_gather(const ushort* __restrict__ xb, const int* __restrict__ pp,
                         const int* __restrict__ plist, const int* __restrict__ pcnt,
                         ushort* __restrict__ vrows) {
  int b = blockIdx.y;
  int j = blockIdx.x * 4 + (threadIdx.x >> 6);
  int lane = threadIdx.x & 63;
  if (j >= pcnt[b]) return;
  int i = plist[b * NN + j];
  bool sing = (i == 0) || (i >= 2 && pp[b * NN + i - 2] == 1);
  float wa = sing ? 0.f : 0.5f, wb = sing ? 1.f : 0.5f;
  const ushort* rp = xb + (size_t)(b * NN + ((i - 1) & (NN - 1))) * HH;
  const ushort* rn = xb + (size_t)(b * NN + ((i + 1) & (NN - 1))) * HH;
  ushort* dst = vrows + ((size_t)b * PRMAX + j) * HH;
#pragma unroll
  for (int it = 0; it < 3; ++it) {
    int d4 = lane + it * 64;   // HH/4 = 192 ushort4 groups
    ushort4 p4 = ((const ushort4*)rp)[d4];
    ushort4 n4 = ((const ushort4*)rn)[d4];
    ushort4 o;
    o.x = f2bf(wa * bf2f(p4.x) + wb * bf2f(n4.x));
    o.y = f2bf(wa * bf2f(p4.y) + wb * bf2f(n4.y));
    o.z = f2bf(wa * bf2f(p4.z) + wb * bf2f(n4.z));
    o.w = f2bf(wa * bf2f(p4.w) + wb * bf2f(n4.w));
    ((ushort4*)dst)[d4] = o;
  }
}

// ============ K_cross: occurrence-pair scores -> diag ============
__global__ void k_cross(const float* __restrict__ x, const int* __restrict__ occ,
                        const float* __restrict__ Wc, const float* __restrict__ bc,
                        float* __restrict__ diag) {
  int g = blockIdx.x * 4 + (threadIdx.x >> 6);
  int lane = threadIdx.x & 63;
  int b = g >> 8, m = g & (MM - 1);
  int o0 = occ[(b * MM + m) * 2 + 0];
  int o1 = occ[(b * MM + m) * 2 + 1];
  const float* x0 = x + (size_t)(b * NN + o0) * HH;
  const float* x1 = x + (size_t)(b * NN + o1) * HH;
  float acc = 0.f;
  for (int d = lane; d < HH; d += 64) acc += 0.5f * (x0[d] + x1[d]) * Wc[d];
  for (int off = 32; off; off >>= 1) acc += __shfl_xor(acc, off);
  if (lane == 0) {
    float sc = lrelu(acc + bc[0]);
    float sq = sc * sc;
    diag[b * NN + o0] = sq;
    diag[b * NN + o1] = sq;
  }
}

// ============ K_score_mf: bf16 MFMA score GEMM over gathered predicate rows ============
__global__ __launch_bounds__(256, 2) void k_score_mf(
    const ushort* __restrict__ xb, const ushort* __restrict__ vrows,
    const int* __restrict__ plist, const int* __restrict__ pcnt,
    const ushort* __restrict__ Wvar, const ushort* __restrict__ Wsym,
    const float* __restrict__ bvar, const float* __restrict__ bsym,
    const float* __restrict__ wscore, float* __restrict__ s_raw) {
  const int b = blockIdx.z;
  const int cnt = pcnt[b];
  const int j0 = blockIdx.y * 128;
  if (j0 >= cnt) return;
  const int n0g = blockIdx.x * 128;           // global col in [0,1536)
  const bool symh = n0g >= HH;
  const int n0 = symh ? n0g - HH : n0g;
  const ushort* W = symh ? Wsym : Wvar;
  const float* bias = symh ? bsym : bvar;
  __shared__ ushort As[128 * 64];
  __shared__ ushort Bs[128 * 64];
  __shared__ int pl[128];
  __shared__ float red[128];
  const int t = threadIdx.x;
  const int w = t >> 6, lane = t & 63, lg = lane >> 4, lm = lane & 15;
  const int wm = (w >> 1) * 64, wn = (w & 1) * 64;
  if (t < 128) {
    int j = j0 + t;
    pl[t] = (j < cnt) ? plist[b * NN + j] : 2;
    red[t] = 0.f;
  }
  __syncthreads();
  f32x4 acc[4][4] = {};
  const ushort* xbb = xb + (size_t)b * NN * HH;
  const ushort* vrb = vrows + (size_t)b * PRMAX * HH;
  for (int k0 = 0; k0 < HH; k0 += 64) {
    if (k0) __syncthreads();
#pragma unroll
    for (int it = 0; it < 4; ++it) {   // 128 rows x 8 chunks = 1024 slots
      int slot = t + it * 256;
      int row = slot >> 3, c = slot & 7;
      uint4 vb = *(const uint4*)(W + (size_t)(n0 + row) * HH + k0 + c * 8);
      *(uint4*)&Bs[row * 64 + ((c ^ (row & 7)) * 8)] = vb;
      uint4 va;
      if (symh) va = *(const uint4*)(xbb + (size_t)pl[row] * HH + k0 + c * 8);
      else      va = *(const uint4*)(vrb + (size_t)(j0 + row) * HH + k0 + c * 8);
      *(uint4*)&As[row * 64 + ((c ^ (row & 7)) * 8)] = va;
    }
    __syncthreads();
    bf16x8 af[4][2], bfr[4][2];
#pragma unroll
    for (int mt = 0; mt < 4; ++mt)
#pragma unroll
      for (int kt = 0; kt < 2; ++kt) {
        int row = wm + mt * 16 + lm, ch = lg + kt * 4;
        af[mt][kt] = *(bf16x8*)&As[row * 64 + ((ch ^ (row & 7)) * 8)];
      }
#pragma unroll
    for (int nt = 0; nt < 4; ++nt)
#pragma unroll
      for (int kt = 0; kt < 2; ++kt) {
        int row = wn + nt * 16 + lm, ch = lg + kt * 4;
        bfr[nt][kt] = *(bf16x8*)&Bs[row * 64 + ((ch ^ (row & 7)) * 8)];
      }
#pragma unroll
    for (int mt = 0; mt < 4; ++mt)
#pragma unroll
      for (int nt = 0; nt < 4; ++nt)
#pragma unroll
        for (int kt = 0; kt < 2; ++kt)
          acc[mt][nt] = __builtin_amdgcn_mfma_f32_16x16x32_bf16(af[mt][kt], bfr[nt][kt], acc[mt][nt], 0, 0, 0);
  }
  // epilogue: tanh + dot with W_score, reduce cols
  float bcol[4], wcol[4];
#pragma unroll
  for (int nt = 0; nt < 4; ++nt) {
    int cl = wn + nt * 16 + lm;
    bcol[nt] = bias[n0 + cl];
    wcol[nt] = wscore[n0g + cl];
  }
#pragma unroll
  for (int mt = 0; mt < 4; ++mt)
#pragma unroll
    for (int r = 0; r < 4; ++r) {
      float p = 0.f;
#pragma unroll
      for (int nt = 0; nt < 4; ++nt)
        p += tanhf(acc[mt][nt][r] + bcol[nt]) * wcol[nt];
      p += __shfl_xor(p, 1); p += __shfl_xor(p, 2);
      p += __shfl_xor(p, 4); p += __shfl_xor(p, 8);
      if (lm == 0) atomicAdd(&red[wm + mt * 16 + lg * 4 + r], p);
    }
  __syncthreads();
  if (t < 128) {
    int j2 = j0 + t;
    if (j2 < cnt) atomicAdd(&s_raw[b * NN + pl[t]], red[t]);
  }
}

// ============ K_bias: per-row sparse bias window (scaled by log2e for exp2 softmax) ============
__global__ void k_bias(const int* __restrict__ pp, const float* __restrict__ s_raw,
                       const float* __restrict__ diag, const float* __restrict__ b_score,
                       float4* __restrict__ bias4) {
  int g = blockIdx.x * 256 + threadIdx.x;
  int b = g >> 10, r = g & (NN - 1);
  const int* ppb = pp + b * NN;
  int i = -1;
  if (ppb[r] == 1) i = r;
  else if (r + 1 < NN && ppb[r + 1] == 1) i = r + 1;
  else if (r >= 1 && ppb[r - 1] == 1) i = r - 1;
  float v0 = 0.f, v1 = 0.f, v2 = 0.f; int cw = r;
  if (i >= 1 && i + 1 < NN) {
    float s = lrelu(s_raw[b * NN + i] + b_score[0]);
    float s2 = s * s;
    cw = i - 1;
    if (i == r) { v0 = 0.2f * s; v1 = 1.6f * s2; v2 = 0.2f * s; }
    else       { v0 = 0.8f * s2; v1 = 0.2f * s; v2 = 0.8f * s2; }
  }
  int slot = r - cw;
  float d = diag[g];
  if (slot == 0) v0 += d; else if (slot == 1) v1 += d; else v2 += d;
  bias4[g] = make_float4(__int_as_float(cw), v0 * LOG2E, v1 * LOG2E, v2 * LOG2E);
}

// ============ K_gemm_bf: fused QKV bf16 MFMA GEMM ============
// z=0: Q row-major *(QSCALE*log2e) ; z=1: K row-major ; z=2: V^T [b][h][d][n]
__global__ __launch_bounds__(256, 2) void k_gemm_bf(
    const ushort* __restrict__ X,
    const ushort* __restrict__ W0, const ushort* __restrict__ W1, const ushort* __restrict__ W2,
    const float* __restrict__ b0, const float* __restrict__ b1, const float* __restrict__ b2,
    ushort* __restrict__ C0, ushort* __restrict__ C1, ushort* __restrict__ C2) {
  const int z = blockIdx.z;
  const ushort* W = z == 0 ? W0 : (z == 1 ? W1 : W2);
  const float* bias = z == 0 ? b0 : (z == 1 ? b1 : b2);
  ushort* C = z == 0 ? C0 : (z == 1 ? C1 : C2);
  const float alpha = z == 0 ? QSCALE * LOG2E : 1.f;
  __shared__ ushort As[128 * 64];
  __shared__ ushort Bs[128 * 64];
  const int m0 = blockIdx.x * 128, n0 = blockIdx.y * 128;
  const int t = threadIdx.x;
  const int w = t >> 6, lane = t & 63, lg = lane >> 4, lm = lane & 15;
  const int wm = (w >> 1) * 64, wn = (w & 1) * 64;
  f32x4 acc[4][4] = {};
  for (int k0 = 0; k0 < HH; k0 += 64) {
    __syncthreads();
#pragma unroll
    for (int it = 0; it < 4; ++it) {
      int slot = t + it * 256;
      int row = slot >> 3, c = slot & 7;
      uint4 va = *(const uint4*)(X + (size_t)(m0 + row) * HH + k0 + c * 8);
      *(uint4*)&As[row * 64 + ((c ^ (row & 7)) * 8)] = va;
      uint4 vb = *(const uint4*)(W + (size_t)(n0 + row) * HH + k0 + c * 8);
      *(uint4*)&Bs[row * 64 + ((c ^ (row & 7)) * 8)] = vb;
    }
    __syncthreads();
    bf16x8 af[4][2], bfr[4][2];
#pragma unroll
    for (int mt = 0; mt < 4; ++mt)
#pragma unroll
      for (int kt = 0; kt < 2; ++kt) {
        int row = wm + mt * 16 + lm, ch = lg + kt * 4;
        af[mt][kt] = *(bf16x8*)&As[row * 64 + ((ch ^ (row & 7)) * 8)];
      }
#pragma unroll
    for (int nt = 0; nt < 4; ++nt)
#pragma unroll
      for (int kt = 0; kt < 2; ++kt) {
        int row = wn + nt * 16 + lm, ch = lg + kt * 4;
        bfr[nt][kt] = *(bf16x8*)&Bs[row * 64 + ((ch ^ (row & 7)) * 8)];
      }
#pragma unroll
    for (int mt = 0; mt < 4; ++mt)
#pragma unroll
      for (int nt = 0; nt < 4; ++nt)
#pragma unroll
        for (int kt = 0; kt < 2; ++kt)
          acc[mt][nt] = __builtin_amdgcn_mfma_f32_16x16x32_bf16(af[mt][kt], bfr[nt][kt], acc[mt][nt], 0, 0, 0);
  }
  if (z == 2) {
#pragma unroll
    for (int nt = 0; nt < 4; ++nt) {
      int col = n0 + wn + nt * 16 + lm;
      int hh = col >> 6, dd = col & 63;
      float bcol = bias[col];
#pragma unroll
      for (int mt = 0; mt < 4; ++mt) {
        int row0 = m0 + wm + mt * 16 + lg * 4;
        int bb2 = row0 >> 10, nr = row0 & (NN - 1);
        ushort4 o;
        o.x = f2bf(acc[mt][nt][0] + bcol);
        o.y = f2bf(acc[mt][nt][1] + bcol);
        o.z = f2bf(acc[mt][nt][2] + bcol);
        o.w = f2bf(acc[mt][nt][3] + bcol);
        *(ushort4*)(C + ((size_t)(bb2 * NHD + hh) * ASZ + dd) * NN + nr) = o;
      }
    }
  } else {
#pragma unroll
    for (int nt = 0; nt < 4; ++nt) {
      int col = n0 + wn + nt * 16 + lm;
      float bcol = bias[col];
#pragma unroll
      for (int mt = 0; mt < 4; ++mt)
#pragma unroll
        for (int r = 0; r < 4; ++r) {
          int row = m0 + wm + mt * 16 + lg * 4 + r;
          C[(size_t)row * HH + col] = f2bf((acc[mt][nt][r] + bcol) * alpha);
        }
    }
  }
}

// ============ K_attn2: swapped-QK^T MFMA flash attention, in-register P ============
// 8 waves x 16 q-rows (128 q/block). exp2-domain softmax; v_perm P-pack;
// next-tile K/V prefetched into registers during compute.
__global__ __launch_bounds__(512, 2) void k_attn2(
    const ushort* __restrict__ qg, const ushort* __restrict__ kg, const ushort* __restrict__ vtg,
    const float4* __restrict__ bias4, const int* __restrict__ pp, float* __restrict__ zz) {
  __shared__ ushort Ks[64 * 64];
  __shared__ ushort Vts[64 * 64];
  const int rb = blockIdx.y, h = blockIdx.x >> 3, b = blockIdx.x & 7;
  const int n0 = rb * 128;
  const int t = threadIdx.x, w = t >> 6, lane = t & 63, lg = lane >> 4, lm = lane & 15;
  const int qbase = n0 + w * 16;
  const ushort* qrow = qg + (size_t)(b * NN + qbase + lm) * HH + h * ASZ;
  bf16x8 qf[2];
  qf[0] = *(const bf16x8*)(qrow + lg * 8);
  qf[1] = *(const bf16x8*)(qrow + lg * 8 + 32);
  float4 bz = bias4[b * NN + qbase + lm];
  const int cwq = __float_as_int(bz.x);
  float mr = -1e30f, lr = 0.f;   // exp2-domain online softmax state for q = qbase+lm
  f32x4 y[4] = {};
  const ushort* kb = kg + (size_t)(b * NN) * HH + h * ASZ;
  const ushort* vtb = vtg + (size_t)(b * NHD + h) * ASZ * NN;
  const int srow = t >> 3, sc = t & 7;   // 512 threads = 64 rows x 8 chunks
  const int arow = (srow & 35) | ((srow & 4) << 2) | ((srow & 24) >> 1);  // K row permutation
  const ushort* kptr = kb + (size_t)srow * HH + sc * 8;
  const ushort* vptr = vtb + (size_t)srow * NN + sc * 8;
  uint4 kreg = *(const uint4*)kptr;
  uint4 vreg = *(const uint4*)vptr;
  for (int tile = 0; tile < 16; ++tile) {
    const int c0 = tile * 64;
    *(uint4*)&Ks[arow * 64 + ((sc ^ (arow & 7)) * 8)] = kreg;
    *(uint4*)&Vts[srow * 64 + ((sc ^ (srow & 7)) * 8)] = vreg;
    __syncthreads();
    if (tile < 15) {   // prefetch next tile into registers (latency hides under compute)
      kptr += 64 * HH; vptr += 64;
      kreg = *(const uint4*)kptr;
      vreg = *(const uint4*)vptr;
    }
    f32x4 s[4] = {};
#pragma unroll
    for (int nt = 0; nt < 4; ++nt) {
      int krow = lm + nt * 16, sw = krow & 7;
#pragma unroll
      for (int kt = 0; kt < 2; ++kt) {
        bf16x8 kf = *(bf16x8*)&Ks[krow * 64 + (((lg + kt * 4) ^ sw) * 8)];
        s[nt] = __builtin_amdgcn_mfma_f32_16x16x32_bf16(kf, qf[kt], s[nt], 0, 0, 0);
      }
    }
    // sparse bias: token of s[nt][r] = c0 + (nt>>1)*32 + lg*8 + (nt&1)*4 + r
    if (c0 <= qbase + 17 && qbase <= c0 + 65) {
#pragma unroll
      for (int nt = 0; nt < 4; ++nt) {
        int kb2 = c0 + (nt >> 1) * 32 + lg * 8 + (nt & 1) * 4;
#pragma unroll
        for (int r = 0; r < 4; ++r) {
          int dd = kb2 + r - cwq;
          if (dd >= 0 && dd < 3) s[nt][r] += (dd == 0) ? bz.y : (dd == 1 ? bz.z : bz.w);
        }
      }
    }
    // online softmax (exp2 domain): row lane-local + 2 shfl
    f32x4 m4;
#pragma unroll
    for (int e = 0; e < 4; ++e)
      m4[e] = fmaxf(fmaxf(s[0][e], s[1][e]), fmaxf(s[2][e], s[3][e]));
    float tm = fmaxf(fmaxf(m4[0], m4[1]), fmaxf(m4[2], m4[3]));
    tm = fmaxf(tm, __shfl_xor(tm, 16));
    tm = fmaxf(tm, __shfl_xor(tm, 32));
    int need = tm > mr;
    if (__any(need)) {
      float mn = fmaxf(mr, tm);
      float f = EXP2F(mr - mn);
      mr = mn;
      lr *= f;
      float fr[4];
#pragma unroll
      for (int r = 0; r < 4; ++r) fr[r] = __shfl(f, lg * 4 + r);
#pragma unroll
      for (int nt = 0; nt < 4; ++nt)
#pragma unroll
        for (int r = 0; r < 4; ++r) y[nt][r] *= fr[r];
    }
    f32x4 sum4 = {0.f, 0.f, 0.f, 0.f};
#pragma unroll
    for (int nt = 0; nt < 4; ++nt)
#pragma unroll
      for (int e = 0; e < 4; ++e) {
        float p = EXP2F(s[nt][e] - mr);
        s[nt][e] = p;
        sum4[e] += p;
      }
    float ts = (sum4[0] + sum4[1]) + (sum4[2] + sum4[3]);
    ts += __shfl_xor(ts, 16);
    ts += __shfl_xor(ts, 32);
    lr += ts;
    // pack P into PV A-frags via v_perm (register-local)
    union { unsigned u[4]; bf16x8 v; } pk[2];
#pragma unroll
    for (int kt = 0; kt < 2; ++kt) {
      pk[kt].u[0] = packbf2(s[2 * kt][0], s[2 * kt][1]);
      pk[kt].u[1] = packbf2(s[2 * kt][2], s[2 * kt][3]);
      pk[kt].u[2] = packbf2(s[2 * kt + 1][0], s[2 * kt + 1][1]);
      pk[kt].u[3] = packbf2(s[2 * kt + 1][2], s[2 * kt + 1][3]);
    }
#pragma unroll
    for (int nt = 0; nt < 4; ++nt) {
      int vrow = lm + nt * 16, sw = vrow & 7;
#pragma unroll
      for (int kt = 0; kt < 2; ++kt) {
        bf16x8 vf = *(bf16x8*)&Vts[vrow * 64 + (((lg + kt * 4) ^ sw) * 8)];
        y[nt] = __builtin_amdgcn_mfma_f32_16x16x32_bf16(pk[kt].v, vf, y[nt], 0, 0, 0);
      }
    }
    __syncthreads();
  }
  // epilogue: weighted row-sums into z1/z2 (y: col lm = d, row lg*4+r = q)
  float invl = 1.f / lr;
  float invq[4], c1v[4], c2v[4];
#pragma unroll
  for (int r = 0; r < 4; ++r) {
    invq[r] = __shfl(invl, lg * 4 + r);
    coefs(pp + b * NN, qbase + lg * 4 + r, c1v[r], c2v[r]);
  }
  float a1[4], a2[4];
#pragma unroll
  for (int nt = 0; nt < 4; ++nt) {
    float u1 = 0.f, u2 = 0.f;
#pragma unroll
    for (int r = 0; r < 4; ++r) {
      float yv = y[nt][r] * invq[r];
      u1 += c1v[r] * yv;
      u2 += c2v[r] * yv;
    }
    u1 += __shfl_xor(u1, 16); u1 += __shfl_xor(u1, 32);
    u2 += __shfl_xor(u2, 16); u2 += __shfl_xor(u2, 32);
    a1[nt] = u1; a2[nt] = u2;
  }
  if (lg == 0) {
#pragma unroll
    for (int nt = 0; nt < 4; ++nt) {
      atomicAdd(&zz[b * HH + h * ASZ + nt * 16 + lm], a1[nt]);
      atomicAdd(&zz[BB * HH + b * HH + h * ASZ + nt * 16 + lm], a2[nt]);
    }
  }
}

// ============ F1: t_s = W_o @ (z_s / sumw) + b_o ============
__global__ void k_f1(const float* __restrict__ Wo, const float* __restrict__ bo,
                     const float* __restrict__ zz, const float* __restrict__ sumw,
                     float* __restrict__ tvec) {
  int b = blockIdx.y;
  int w = threadIdx.x >> 6, lane = threadIdx.x & 63;
  float inv = 1.f / sumw[b];
  const float* z1 = zz + b * HH;
  const float* z2 = zz + BB * HH + b * HH;
  float zr1[12], zr2[12];
#pragma unroll
  for (int m = 0; m < 12; ++m) { zr1[m] = z1[lane + 64 * m] * inv; zr2[m] = z2[lane + 64 * m] * inv; }
  for (int j = 0; j < 8; ++j) {
    int o = blockIdx.x * 32 + w * 8 + j;
    const float* wrow = Wo + (size_t)o * HH;
    float a1 = 0.f, a2 = 0.f;
#pragma unroll
    for (int m = 0; m < 12; ++m) { float wv = wrow[lane + 64 * m]; a1 += wv * zr1[m]; a2 += wv * zr2[m]; }
    for (int mask = 32; mask; mask >>= 1) { a1 += __shfl_xor(a1, mask); a2 += __shfl_xor(a2, mask); }
    if (lane == 0) { tvec[b * HH + o] = a1 + bo[o]; tvec[BB * HH + b * HH + o] = a2 + bo[o]; }
  }
}

// ============ F2: pm = WL @ t1 + WR @ t2 + b_atom ============
__global__ void k_f2(const float* __restrict__ Wa, const float* __restrict__ ba,
                     const float* __restrict__ tvec, float* __restrict__ pm) {
  int b = blockIdx.y;
  int w = threadIdx.x >> 6, lane = threadIdx.x & 63;
  const float* t1 = tvec + b * HH;
  const float* t2 = tvec + BB * HH + b * HH;
  float r1[12], r2[12];
#pragma unroll
  for (int m = 0; m < 12; ++m) { r1[m] = t1[lane + 64 * m]; r2[m] = t2[lane + 64 * m]; }
  for (int j = 0; j < 8; ++j) {
    int o = blockIdx.x * 32 + w * 8 + j;
    const float* wrow = Wa + (size_t)o * (2 * HH);
    float a = 0.f;
#pragma unroll
    for (int m = 0; m < 12; ++m) a += wrow[lane + 64 * m] * r1[m];
#pragma unroll
    for (int m = 0; m < 12; ++m) a += wrow[HH + lane + 64 * m] * r2[m];
    for (int mask = 32; mask; mask >>= 1) a += __shfl_xor(a, mask);
    if (lane == 0) pm[b * HH + o] = a + ba[o];
  }
}

// ============ F3: broadcast pm to (B,N,H) ============
__global__ void k_bcast(const float* __restrict__ pm, float* __restrict__ out) {
  size_t g = (size_t)blockIdx.x * 256 + threadIdx.x;
  int b = (int)(g / ((size_t)NN * HH / 4));
  int hh4 = (int)(g % (HH / 4));
  float4 val = *(const float4*)(pm + b * HH + hh4 * 4);
  *(float4*)(out + g * 4) = val;
}

// ================= launcher =================
extern "C" void kernel_launch(void* const* d_in, const int* in_sizes, int n_in,
                              void* d_out, int out_size, void* d_ws, size_t ws_size,
                              hipStream_t stream) {
  (void)in_sizes; (void)n_in; (void)out_size; (void)ws_size;
  const float* x       = (const float*)d_in[0];
  const float* W_var   = (const float*)d_in[3];
  const float* b_var   = (const float*)d_in[4];
  const float* W_sym   = (const float*)d_in[5];
  const float* b_sym   = (const float*)d_in[6];
  const float* W_score = (const float*)d_in[7];
  const float* b_score = (const float*)d_in[8];
  const float* W_cross = (const float*)d_in[9];
  const float* b_cross = (const float*)d_in[10];
  const float* W_atom  = (const float*)d_in[11];
  const float* b_atom  = (const float*)d_in[12];
  const float* W_q     = (const float*)d_in[13];
  const float* b_q     = (const float*)d_in[14];
  const float* W_k     = (const float*)d_in[15];
  const float* b_k     = (const float*)d_in[16];
  const float* W_v     = (const float*)d_in[17];
  const float* b_v     = (const float*)d_in[18];
  const float* W_o     = (const float*)d_in[19];
  const float* b_o     = (const float*)d_in[20];
  const int*   pp      = (const int*)d_in[21];
  const int*   occ     = (const int*)d_in[24];
  float* out = (float*)d_out;
  char* wsb = (char*)d_ws;
  ushort* qb  = (ushort*)(wsb + OFFB_QB);
  ushort* kbf = (ushort*)(wsb + OFFB_KB);
  ushort* vtb = (ushort*)(wsb + OFFB_VB);
  ushort* xb  = (ushort*)(wsb + OFFB_XB);
  ushort* wqb = (ushort*)(wsb + OFFB_WQB);
  ushort* wkb = (ushort*)(wsb + OFFB_WKB);
  ushort* wvb = (ushort*)(wsb + OFFB_WVB);
  ushort* wvar = (ushort*)(wsb + OFFB_WVAR);
  ushort* wsym = (ushort*)(wsb + OFFB_WSYM);
  ushort* vrows = (ushort*)(wsb + OFFB_VROWS);
  float* sraw = (float*)(wsb + OFFB_SRAW);
  float* diag = (float*)(wsb + OFFB_DIAG);
  float4* bias4 = (float4*)(wsb + OFFB_BIAS4);
  int* plist = (int*)(wsb + OFFB_PLIST);
  int* pcnt  = (int*)(wsb + OFFB_PCNT);
  float* sumw = (float*)(wsb + OFFB_SUMW);
  float* zz   = (float*)(wsb + OFFB_ZZ);
  float* tv   = (float*)(wsb + OFFB_TV);
  float* pm   = (float*)(wsb + OFFB_PM);

  k_pred<<<BB, 64, 0, stream>>>(pp, plist, pcnt, sumw, sraw, diag, zz);
  // f32 -> bf16 conversions
  k_cvt<<<(BB * NN * HH / 4 + 255) / 256, 256, 0, stream>>>(x, xb, BB * NN * HH / 4);
  k_cvt5<<<dim3(HH * HH / 4 / 256, 5), 256, 0, stream>>>(W_q, W_k, W_v, W_var, W_sym,
                                                          wqb, wkb, wvb, wvar, wsym);
  // gather var_in rows (bf16, compact)
  k_gather<<<dim3(PRMAX / 4, BB), 256, 0, stream>>>(xb, pp, plist, pcnt, vrows);
  // score path (bf16 MFMA, fused var+sym over 1536 cols)
  k_score_mf<<<dim3(12, 8, BB), 256, 0, stream>>>(xb, vrows, plist, pcnt, wvar, wsym,
                                                  b_var, b_sym, W_score, sraw);
  k_cross<<<BB * MM / 4, 256, 0, stream>>>(x, occ, W_cross, b_cross, diag);
  k_bias<<<BB * NN / 256, 256, 0, stream>>>(pp, sraw, diag, b_score, bias4);
  // fused QKV MFMA GEMM (bf16); V written transposed; Q scaled into exp2 domain
  k_gemm_bf<<<dim3(64, 6, 3), 256, 0, stream>>>(xb, wqb, wkb, wvb, b_q, b_k, b_v, qb, kbf, vtb);
  // MFMA flash attention (128 q-rows/block, 8 waves); grid x=(h,b) for XCD L2 reuse
  k_attn2<<<dim3(NHD * BB, NN / 128), 512, 0, stream>>>(qb, kbf, vtb, bias4, pp, zz);
  k_f1<<<dim3(24, BB), 256, 0, stream>>>(W_o, b_o, zz, sumw, tv);
  k_f2<<<dim3(24, BB), 256, 0, stream>>>(W_atom, b_atom, tv, pm);
  k_bcast<<<BB * NN * HH / 1024, 256, 0, stream>>>(pm, out);
}

// Round 9
// 172.392 us; speedup vs baseline: 8.2045x; 1.1029x over previous
//
#include <hip/hip_runtime.h>
#include <hip/hip_bf16.h>

// ================= problem constants =================
#define BB 8
#define NN 1024
#define HH 768
#define NHD 12
#define ASZ 64
#define MM 256
#define QSCALE 0.125f   // AS^-0.5
#define NSLOPE 0.02f
#define LOG2E 1.44269504f
#define PRMAX 384       // padded predicate rows per batch

typedef __attribute__((ext_vector_type(8))) short bf16x8;
typedef __attribute__((ext_vector_type(4))) float f32x4;

#define EXP2F(x) __builtin_amdgcn_exp2f(x)
#define RCPF(x)  __builtin_amdgcn_rcpf(x)

// ============ workspace layout (byte offsets, all 16B-aligned) ============
#define OFFB_QB    ((size_t)0)            // 8*1024*768 bf16
#define OFFB_KB    ((size_t)12582912)
#define OFFB_VB    ((size_t)25165824)     // V^T: [b][h][d][n] bf16
#define OFFB_XB    ((size_t)37748736)     // x in bf16
#define OFFB_WQB   ((size_t)50331648)     // 768*768 bf16
#define OFFB_WKB   ((size_t)51511296)
#define OFFB_WVB   ((size_t)52690944)
#define OFFB_WVAR  ((size_t)53870592)     // W_var bf16
#define OFFB_WSYM  ((size_t)55050240)     // W_sym bf16
#define OFFB_SRAW  ((size_t)56229888)     // 8192 f32
#define OFFB_DIAG  ((size_t)56262656)     // 8192 f32
#define OFFB_BIAS4 ((size_t)56295424)     // 8192 float4
#define OFFB_PLIST ((size_t)56426496)     // 8192 i32
#define OFFB_PCNT  ((size_t)56459264)
#define OFFB_SUMW  ((size_t)56459296)
#define OFFB_ZZ    ((size_t)56459328)     // 2*8*768 f32
#define OFFB_TV    ((size_t)56508480)
#define OFFB_PM    ((size_t)56557632)
#define OFFB_VROWS ((size_t)56582208)     // 8*384*768 bf16 gathered var rows

__device__ __forceinline__ float lrelu(float v) { return v >= 0.f ? v : NSLOPE * v; }

__device__ __forceinline__ ushort f2bf(float f) {  // round-half-up f32->bf16 (2 ops)
  return (ushort)((__float_as_uint(f) + 0x8000u) >> 16);
}
__device__ __forceinline__ float bf2f(ushort u) {
  union { unsigned u; float f; } v; v.u = (unsigned)u << 16;
  return v.f;
}
__device__ __forceinline__ unsigned packbf2(float lo, float hi) {  // (bf(hi)<<16)|bf(lo)
  unsigned a = __float_as_uint(hi) + 0x8000u;
  unsigned b = __float_as_uint(lo) + 0x8000u;
  return __builtin_amdgcn_perm(a, b, 0x07060302u);
}
__device__ __forceinline__ float fast_tanh(float x) {  // exp2-domain, saturates to +-1
  float e = EXP2F(x * (2.f * LOG2E));
  return 1.f - 2.f * RCPF(e + 1.f);
}

// weights for the final weighted row-sums of y (derived from pm algebra).
__device__ __forceinline__ void coefs(const int* ppb, int j, float& c1, float& c2) {
  auto pred = [&](int tt) { return tt >= 0 && tt < NN && ppb[tt] == 1; };
  auto single = [&](int tt) { return tt == 0 || (tt >= 2 && ppb[tt - 2] == 1); };
  auto wgt = [&](int tt) {
    if (!pred(tt)) return 0.f;
    bool tri = (tt >= 1) && (tt <= 1 || !single(tt));
    return tri ? 3.f : 2.f;
  };
  float a = 0.f;
  if (pred(j + 1)) a += wgt(j + 1) * (single(j + 1) ? 0.f : 0.5f);
  if (j >= 1 && pred(j - 1)) a += wgt(j - 1) * (single(j - 1) ? 1.f : 0.5f);
  c1 = a;
  c2 = wgt(j);
}

// ============ K_cvt: f32 -> bf16 (vectorized) ============
__global__ void k_cvt(const float* __restrict__ src, ushort* __restrict__ dst, int n4) {
  int i = blockIdx.x * 256 + threadIdx.x;
  if (i >= n4) return;
  float4 v = ((const float4*)src)[i];
  ushort4 o;
  o.x = f2bf(v.x); o.y = f2bf(v.y); o.z = f2bf(v.z); o.w = f2bf(v.w);
  ((ushort4*)dst)[i] = o;
}

// ============ K_cvt5: five HHxHH weights in one dispatch ============
__global__ void k_cvt5(const float* __restrict__ s0, const float* __restrict__ s1,
                       const float* __restrict__ s2, const float* __restrict__ s3,
                       const float* __restrict__ s4,
                       ushort* __restrict__ d0, ushort* __restrict__ d1,
                       ushort* __restrict__ d2, ushort* __restrict__ d3,
                       ushort* __restrict__ d4) {
  int z = blockIdx.y;
  const float* src = z == 0 ? s0 : z == 1 ? s1 : z == 2 ? s2 : z == 3 ? s3 : s4;
  ushort* dst = z == 0 ? d0 : z == 1 ? d1 : z == 2 ? d2 : z == 3 ? d3 : d4;
  int i = blockIdx.x * 256 + threadIdx.x;   // HH*HH/4 = 147456, grid.x = 576
  float4 v = ((const float4*)src)[i];
  ushort4 o;
  o.x = f2bf(v.x); o.y = f2bf(v.y); o.z = f2bf(v.z); o.w = f2bf(v.w);
  ((ushort4*)dst)[i] = o;
}

// ============ K_pred: compact predicate list + sum of weights + ws zeroing ============
__global__ void k_pred(const int* __restrict__ pp, int* __restrict__ plist,
                       int* __restrict__ pcnt, float* __restrict__ sumw,
                       float* __restrict__ sraw, float* __restrict__ diag,
                       float* __restrict__ zz) {
  int b = blockIdx.x;
  int lane = threadIdx.x;  // blockDim 64
  const int* ppb = pp + b * NN;
  int base = 0;
  float wacc = 0.f;
  for (int c = 0; c < NN; c += 64) {
    int i = c + lane;
    bool isp = ppb[i] == 1;
    unsigned long long mask = __ballot(isp);
    if (isp) {
      int pos = base + __popcll(mask & ((1ull << lane) - 1ull));
      plist[b * NN + pos] = i;
      bool sing = (i == 0) || (i >= 2 && ppb[i - 2] == 1);
      bool tri = (i >= 1) && (i <= 1 || !sing);
      wacc += tri ? 3.f : 2.f;
    }
    base += __popcll(mask);
  }
  for (int off = 32; off; off >>= 1) wacc += __shfl_xor(wacc, off);
  if (lane == 0) { pcnt[b] = base; sumw[b] = wacc; }
  // zero this batch's accumulators (replaces hipMemsetAsync)
  for (int c = lane; c < NN; c += 64) { sraw[b * NN + c] = 0.f; diag[b * NN + c] = 0.f; }
  for (int c = lane; c < HH; c += 64) {
    zz[b * HH + c] = 0.f;
    zz[BB * HH + b * HH + c] = 0.f;
  }
}

// ============ K_gather: compact var_in rows (bf16) for the score GEMM ============
__global__ void k_gather(const ushort* __restrict__ xb, const int* __restrict__ pp,
                         const int* __restrict__ plist, const int* __restrict__ pcnt,
                         ushort* __restrict__ vrows) {
  int b = blockIdx.y;
  int j = blockIdx.x * 4 + (threadIdx.x >> 6);
  int lane = threadIdx.x & 63;
  if (j >= pcnt[b]) return;
  int i = plist[b * NN + j];
  bool sing = (i == 0) || (i >= 2 && pp[b * NN + i - 2] == 1);
  float wa = sing ? 0.f : 0.5f, wb = sing ? 1.f : 0.5f;
  const ushort* rp = xb + (size_t)(b * NN + ((i - 1) & (NN - 1))) * HH;
  const ushort* rn = xb + (size_t)(b * NN + ((i + 1) & (NN - 1))) * HH;
  ushort* dst = vrows + ((size_t)b * PRMAX + j) * HH;
#pragma unroll
  for (int it = 0; it < 3; ++it) {
    int d4 = lane + it * 64;   // HH/4 = 192 ushort4 groups
    ushort4 p4 = ((const ushort4*)rp)[d4];
    ushort4 n4 = ((const ushort4*)rn)[d4];
    ushort4 o;
    o.x = f2bf(wa * bf2f(p4.x) + wb * bf2f(n4.x));
    o.y = f2bf(wa * bf2f(p4.y) + wb * bf2f(n4.y));
    o.z = f2bf(wa * bf2f(p4.z) + wb * bf2f(n4.z));
    o.w = f2bf(wa * bf2f(p4.w) + wb * bf2f(n4.w));
    ((ushort4*)dst)[d4] = o;
  }
}

// ============ K_cross: occurrence-pair scores -> diag ============
__global__ void k_cross(const float* __restrict__ x, const int* __restrict__ occ,
                        const float* __restrict__ Wc, const float* __restrict__ bc,
                        float* __restrict__ diag) {
  int g = blockIdx.x * 4 + (threadIdx.x >> 6);
  int lane = threadIdx.x & 63;
  int b = g >> 8, m = g & (MM - 1);
  int o0 = occ[(b * MM + m) * 2 + 0];
  int o1 = occ[(b * MM + m) * 2 + 1];
  const float* x0 = x + (size_t)(b * NN + o0) * HH;
  const float* x1 = x + (size_t)(b * NN + o1) * HH;
  float acc = 0.f;
  for (int d = lane; d < HH; d += 64) acc += 0.5f * (x0[d] + x1[d]) * Wc[d];
  for (int off = 32; off; off >>= 1) acc += __shfl_xor(acc, off);
  if (lane == 0) {
    float sc = lrelu(acc + bc[0]);
    float sq = sc * sc;
    diag[b * NN + o0] = sq;
    diag[b * NN + o1] = sq;
  }
}

// ============ K_score_mf: bf16 MFMA score GEMM, register-prefetched ============
// grid (12, 6, BB): 64-row y-tiles, 128-col x-tiles over [0,1536).
// Cols [0,768): vrows @ W_var^T + b_var ; [768,1536): x @ W_sym^T + b_sym.
// Epilogue: sum_cols fast_tanh(feat)*W_score[col] -> atomicAdd s_raw[b][i].
__global__ __launch_bounds__(256, 2) void k_score_mf(
    const ushort* __restrict__ xb, const ushort* __restrict__ vrows,
    const int* __restrict__ plist, const int* __restrict__ pcnt,
    const ushort* __restrict__ Wvar, const ushort* __restrict__ Wsym,
    const float* __restrict__ bvar, const float* __restrict__ bsym,
    const float* __restrict__ wscore, float* __restrict__ s_raw) {
  const int b = blockIdx.z;
  const int cnt = pcnt[b];
  const int j0 = blockIdx.y * 64;
  if (j0 >= cnt) return;
  const int n0g = blockIdx.x * 128;           // global col in [0,1536)
  const bool symh = n0g >= HH;
  const int n0 = symh ? n0g - HH : n0g;
  const ushort* W = symh ? Wsym : Wvar;
  const float* bias = symh ? bsym : bvar;
  __shared__ ushort As[64 * 64];
  __shared__ ushort Bs[128 * 64];
  __shared__ int pl[64];
  __shared__ float red[64];
  const int t = threadIdx.x;
  const int w = t >> 6, lane = t & 63, lg = lane >> 4, lm = lane & 15;
  const int wm = (w >> 1) * 32, wn = (w & 1) * 64;
  if (t < 64) {
    int j = j0 + t;
    pl[t] = (j < cnt) ? plist[b * NN + j] : 2;
    red[t] = 0.f;
  }
  __syncthreads();
  const int r0 = t >> 3, c = t & 7;   // r0 in [0,32), staging rows r0 and r0+32 (A); +32*it (B)
  const ushort* ap0; const ushort* ap1;
  if (symh) {
    const ushort* xbb = xb + (size_t)b * NN * HH;
    ap0 = xbb + (size_t)pl[r0] * HH + c * 8;
    ap1 = xbb + (size_t)pl[r0 + 32] * HH + c * 8;
  } else {
    const ushort* vrb = vrows + ((size_t)b * PRMAX + j0) * HH;
    ap0 = vrb + (size_t)r0 * HH + c * 8;
    ap1 = vrb + (size_t)(r0 + 32) * HH + c * 8;
  }
  const ushort* bp = W + (size_t)(n0 + r0) * HH + c * 8;
  uint4 ar0 = *(const uint4*)ap0;
  uint4 ar1 = *(const uint4*)ap1;
  uint4 br0 = *(const uint4*)bp;
  uint4 br1 = *(const uint4*)(bp + (size_t)32 * HH);
  uint4 br2 = *(const uint4*)(bp + (size_t)64 * HH);
  uint4 br3 = *(const uint4*)(bp + (size_t)96 * HH);
  f32x4 acc[2][4] = {};
  const int ssw = (c ^ (r0 & 7)) * 8;   // swizzle invariant under row+32
  for (int k0 = 0; k0 < HH; k0 += 64) {
    if (k0) __syncthreads();
    *(uint4*)&As[r0 * 64 + ssw] = ar0;
    *(uint4*)&As[(r0 + 32) * 64 + ssw] = ar1;
    *(uint4*)&Bs[r0 * 64 + ssw] = br0;
    *(uint4*)&Bs[(r0 + 32) * 64 + ssw] = br1;
    *(uint4*)&Bs[(r0 + 64) * 64 + ssw] = br2;
    *(uint4*)&Bs[(r0 + 96) * 64 + ssw] = br3;
    __syncthreads();
    if (k0 + 64 < HH) {   // prefetch next K-step into registers
      ap0 += 64; ap1 += 64; bp += 64;
      ar0 = *(const uint4*)ap0;
      ar1 = *(const uint4*)ap1;
      br0 = *(const uint4*)bp;
      br1 = *(const uint4*)(bp + (size_t)32 * HH);
      br2 = *(const uint4*)(bp + (size_t)64 * HH);
      br3 = *(const uint4*)(bp + (size_t)96 * HH);
    }
    bf16x8 af[2][2], bfr[4][2];
#pragma unroll
    for (int mt = 0; mt < 2; ++mt)
#pragma unroll
      for (int kt = 0; kt < 2; ++kt) {
        int row = wm + mt * 16 + lm, ch = lg + kt * 4;
        af[mt][kt] = *(bf16x8*)&As[row * 64 + ((ch ^ (row & 7)) * 8)];
      }
#pragma unroll
    for (int nt = 0; nt < 4; ++nt)
#pragma unroll
      for (int kt = 0; kt < 2; ++kt) {
        int row = wn + nt * 16 + lm, ch = lg + kt * 4;
        bfr[nt][kt] = *(bf16x8*)&Bs[row * 64 + ((ch ^ (row & 7)) * 8)];
      }
#pragma unroll
    for (int mt = 0; mt < 2; ++mt)
#pragma unroll
      for (int nt = 0; nt < 4; ++nt)
#pragma unroll
        for (int kt = 0; kt < 2; ++kt)
          acc[mt][nt] = __builtin_amdgcn_mfma_f32_16x16x32_bf16(af[mt][kt], bfr[nt][kt], acc[mt][nt], 0, 0, 0);
  }
  // epilogue: fast tanh + dot with W_score, reduce over cols
  float bcol[4], wcol[4];
#pragma unroll
  for (int nt = 0; nt < 4; ++nt) {
    int cl = wn + nt * 16 + lm;
    bcol[nt] = bias[n0 + cl];
    wcol[nt] = wscore[n0g + cl];
  }
#pragma unroll
  for (int mt = 0; mt < 2; ++mt)
#pragma unroll
    for (int r = 0; r < 4; ++r) {
      float p = 0.f;
#pragma unroll
      for (int nt = 0; nt < 4; ++nt)
        p += fast_tanh(acc[mt][nt][r] + bcol[nt]) * wcol[nt];
      p += __shfl_xor(p, 1); p += __shfl_xor(p, 2);
      p += __shfl_xor(p, 4); p += __shfl_xor(p, 8);
      if (lm == 0) atomicAdd(&red[wm + mt * 16 + lg * 4 + r], p);
    }
  __syncthreads();
  if (t < 64) {
    int j2 = j0 + t;
    if (j2 < cnt) atomicAdd(&s_raw[b * NN + pl[t]], red[t]);
  }
}

// ============ K_bias: per-row sparse bias window (scaled by log2e for exp2 softmax) ============
__global__ void k_bias(const int* __restrict__ pp, const float* __restrict__ s_raw,
                       const float* __restrict__ diag, const float* __restrict__ b_score,
                       float4* __restrict__ bias4) {
  int g = blockIdx.x * 256 + threadIdx.x;
  int b = g >> 10, r = g & (NN - 1);
  const int* ppb = pp + b * NN;
  int i = -1;
  if (ppb[r] == 1) i = r;
  else if (r + 1 < NN && ppb[r + 1] == 1) i = r + 1;
  else if (r >= 1 && ppb[r - 1] == 1) i = r - 1;
  float v0 = 0.f, v1 = 0.f, v2 = 0.f; int cw = r;
  if (i >= 1 && i + 1 < NN) {
    float s = lrelu(s_raw[b * NN + i] + b_score[0]);
    float s2 = s * s;
    cw = i - 1;
    if (i == r) { v0 = 0.2f * s; v1 = 1.6f * s2; v2 = 0.2f * s; }
    else       { v0 = 0.8f * s2; v1 = 0.2f * s; v2 = 0.8f * s2; }
  }
  int slot = r - cw;
  float d = diag[g];
  if (slot == 0) v0 += d; else if (slot == 1) v1 += d; else v2 += d;
  bias4[g] = make_float4(__int_as_float(cw), v0 * LOG2E, v1 * LOG2E, v2 * LOG2E);
}

// ============ K_gemm_bf: fused QKV bf16 MFMA GEMM ============
// z=0: Q row-major *(QSCALE*log2e) ; z=1: K row-major ; z=2: V^T [b][h][d][n]
__global__ __launch_bounds__(256, 2) void k_gemm_bf(
    const ushort* __restrict__ X,
    const ushort* __restrict__ W0, const ushort* __restrict__ W1, const ushort* __restrict__ W2,
    const float* __restrict__ b0, const float* __restrict__ b1, const float* __restrict__ b2,
    ushort* __restrict__ C0, ushort* __restrict__ C1, ushort* __restrict__ C2) {
  const int z = blockIdx.z;
  const ushort* W = z == 0 ? W0 : (z == 1 ? W1 : W2);
  const float* bias = z == 0 ? b0 : (z == 1 ? b1 : b2);
  ushort* C = z == 0 ? C0 : (z == 1 ? C1 : C2);
  const float alpha = z == 0 ? QSCALE * LOG2E : 1.f;
  __shared__ ushort As[128 * 64];
  __shared__ ushort Bs[128 * 64];
  const int m0 = blockIdx.x * 128, n0 = blockIdx.y * 128;
  const int t = threadIdx.x;
  const int w = t >> 6, lane = t & 63, lg = lane >> 4, lm = lane & 15;
  const int wm = (w >> 1) * 64, wn = (w & 1) * 64;
  f32x4 acc[4][4] = {};
  for (int k0 = 0; k0 < HH; k0 += 64) {
    __syncthreads();
#pragma unroll
    for (int it = 0; it < 4; ++it) {
      int slot = t + it * 256;
      int row = slot >> 3, c = slot & 7;
      uint4 va = *(const uint4*)(X + (size_t)(m0 + row) * HH + k0 + c * 8);
      *(uint4*)&As[row * 64 + ((c ^ (row & 7)) * 8)] = va;
      uint4 vb = *(const uint4*)(W + (size_t)(n0 + row) * HH + k0 + c * 8);
      *(uint4*)&Bs[row * 64 + ((c ^ (row & 7)) * 8)] = vb;
    }
    __syncthreads();
    bf16x8 af[4][2], bfr[4][2];
#pragma unroll
    for (int mt = 0; mt < 4; ++mt)
#pragma unroll
      for (int kt = 0; kt < 2; ++kt) {
        int row = wm + mt * 16 + lm, ch = lg + kt * 4;
        af[mt][kt] = *(bf16x8*)&As[row * 64 + ((ch ^ (row & 7)) * 8)];
      }
#pragma unroll
    for (int nt = 0; nt < 4; ++nt)
#pragma unroll
      for (int kt = 0; kt < 2; ++kt) {
        int row = wn + nt * 16 + lm, ch = lg + kt * 4;
        bfr[nt][kt] = *(bf16x8*)&Bs[row * 64 + ((ch ^ (row & 7)) * 8)];
      }
#pragma unroll
    for (int mt = 0; mt < 4; ++mt)
#pragma unroll
      for (int nt = 0; nt < 4; ++nt)
#pragma unroll
        for (int kt = 0; kt < 2; ++kt)
          acc[mt][nt] = __builtin_amdgcn_mfma_f32_16x16x32_bf16(af[mt][kt], bfr[nt][kt], acc[mt][nt], 0, 0, 0);
  }
  if (z == 2) {
#pragma unroll
    for (int nt = 0; nt < 4; ++nt) {
      int col = n0 + wn + nt * 16 + lm;
      int hh = col >> 6, dd = col & 63;
      float bcol = bias[col];
#pragma unroll
      for (int mt = 0; mt < 4; ++mt) {
        int row0 = m0 + wm + mt * 16 + lg * 4;
        int bb2 = row0 >> 10, nr = row0 & (NN - 1);
        ushort4 o;
        o.x = f2bf(acc[mt][nt][0] + bcol);
        o.y = f2bf(acc[mt][nt][1] + bcol);
        o.z = f2bf(acc[mt][nt][2] + bcol);
        o.w = f2bf(acc[mt][nt][3] + bcol);
        *(ushort4*)(C + ((size_t)(bb2 * NHD + hh) * ASZ + dd) * NN + nr) = o;
      }
    }
  } else {
#pragma unroll
    for (int nt = 0; nt < 4; ++nt) {
      int col = n0 + wn + nt * 16 + lm;
      float bcol = bias[col];
#pragma unroll
      for (int mt = 0; mt < 4; ++mt)
#pragma unroll
        for (int r = 0; r < 4; ++r) {
          int row = m0 + wm + mt * 16 + lg * 4 + r;
          C[(size_t)row * HH + col] = f2bf((acc[mt][nt][r] + bcol) * alpha);
        }
    }
  }
}

// ============ K_attn2: swapped-QK^T MFMA flash attention, in-register P ============
// 8 waves x 16 q-rows (128 q/block). exp2-domain softmax; v_perm P-pack;
// next-tile K/V prefetched into registers during compute.
__global__ __launch_bounds__(512, 2) void k_attn2(
    const ushort* __restrict__ qg, const ushort* __restrict__ kg, const ushort* __restrict__ vtg,
    const float4* __restrict__ bias4, const int* __restrict__ pp, float* __restrict__ zz) {
  __shared__ ushort Ks[64 * 64];
  __shared__ ushort Vts[64 * 64];
  const int rb = blockIdx.y, h = blockIdx.x >> 3, b = blockIdx.x & 7;
  const int n0 = rb * 128;
  const int t = threadIdx.x, w = t >> 6, lane = t & 63, lg = lane >> 4, lm = lane & 15;
  const int qbase = n0 + w * 16;
  const ushort* qrow = qg + (size_t)(b * NN + qbase + lm) * HH + h * ASZ;
  bf16x8 qf[2];
  qf[0] = *(const bf16x8*)(qrow + lg * 8);
  qf[1] = *(const bf16x8*)(qrow + lg * 8 + 32);
  float4 bz = bias4[b * NN + qbase + lm];
  const int cwq = __float_as_int(bz.x);
  float mr = -1e30f, lr = 0.f;   // exp2-domain online softmax state for q = qbase+lm
  f32x4 y[4] = {};
  const ushort* kb = kg + (size_t)(b * NN) * HH + h * ASZ;
  const ushort* vtb = vtg + (size_t)(b * NHD + h) * ASZ * NN;
  const int srow = t >> 3, sc = t & 7;   // 512 threads = 64 rows x 8 chunks
  const int arow = (srow & 35) | ((srow & 4) << 2) | ((srow & 24) >> 1);  // K row permutation
  const ushort* kptr = kb + (size_t)srow * HH + sc * 8;
  const ushort* vptr = vtb + (size_t)srow * NN + sc * 8;
  uint4 kreg = *(const uint4*)kptr;
  uint4 vreg = *(const uint4*)vptr;
  for (int tile = 0; tile < 16; ++tile) {
    const int c0 = tile * 64;
    *(uint4*)&Ks[arow * 64 + ((sc ^ (arow & 7)) * 8)] = kreg;
    *(uint4*)&Vts[srow * 64 + ((sc ^ (srow & 7)) * 8)] = vreg;
    __syncthreads();
    if (tile < 15) {   // prefetch next tile into registers (latency hides under compute)
      kptr += 64 * HH; vptr += 64;
      kreg = *(const uint4*)kptr;
      vreg = *(const uint4*)vptr;
    }
    f32x4 s[4] = {};
#pragma unroll
    for (int nt = 0; nt < 4; ++nt) {
      int krow = lm + nt * 16, sw = krow & 7;
#pragma unroll
      for (int kt = 0; kt < 2; ++kt) {
        bf16x8 kf = *(bf16x8*)&Ks[krow * 64 + (((lg + kt * 4) ^ sw) * 8)];
        s[nt] = __builtin_amdgcn_mfma_f32_16x16x32_bf16(kf, qf[kt], s[nt], 0, 0, 0);
      }
    }
    // sparse bias: token of s[nt][r] = c0 + (nt>>1)*32 + lg*8 + (nt&1)*4 + r
    if (c0 <= qbase + 17 && qbase <= c0 + 65) {
#pragma unroll
      for (int nt = 0; nt < 4; ++nt) {
        int kb2 = c0 + (nt >> 1) * 32 + lg * 8 + (nt & 1) * 4;
#pragma unroll
        for (int r = 0; r < 4; ++r) {
          int dd = kb2 + r - cwq;
          if (dd >= 0 && dd < 3) s[nt][r] += (dd == 0) ? bz.y : (dd == 1 ? bz.z : bz.w);
        }
      }
    }
    // online softmax (exp2 domain): row lane-local + 2 shfl
    f32x4 m4;
#pragma unroll
    for (int e = 0; e < 4; ++e)
      m4[e] = fmaxf(fmaxf(s[0][e], s[1][e]), fmaxf(s[2][e], s[3][e]));
    float tm = fmaxf(fmaxf(m4[0], m4[1]), fmaxf(m4[2], m4[3]));
    tm = fmaxf(tm, __shfl_xor(tm, 16));
    tm = fmaxf(tm, __shfl_xor(tm, 32));
    int need = tm > mr;
    if (__any(need)) {
      float mn = fmaxf(mr, tm);
      float f = EXP2F(mr - mn);
      mr = mn;
      lr *= f;
      float fr[4];
#pragma unroll
      for (int r = 0; r < 4; ++r) fr[r] = __shfl(f, lg * 4 + r);
#pragma unroll
      for (int nt = 0; nt < 4; ++nt)
#pragma unroll
        for (int r = 0; r < 4; ++r) y[nt][r] *= fr[r];
    }
    f32x4 sum4 = {0.f, 0.f, 0.f, 0.f};
#pragma unroll
    for (int nt = 0; nt < 4; ++nt)
#pragma unroll
      for (int e = 0; e < 4; ++e) {
        float p = EXP2F(s[nt][e] - mr);
        s[nt][e] = p;
        sum4[e] += p;
      }
    float ts = (sum4[0] + sum4[1]) + (sum4[2] + sum4[3]);
    ts += __shfl_xor(ts, 16);
    ts += __shfl_xor(ts, 32);
    lr += ts;
    // pack P into PV A-frags via v_perm (register-local)
    union { unsigned u[4]; bf16x8 v; } pk[2];
#pragma unroll
    for (int kt = 0; kt < 2; ++kt) {
      pk[kt].u[0] = packbf2(s[2 * kt][0], s[2 * kt][1]);
      pk[kt].u[1] = packbf2(s[2 * kt][2], s[2 * kt][3]);
      pk[kt].u[2] = packbf2(s[2 * kt + 1][0], s[2 * kt + 1][1]);
      pk[kt].u[3] = packbf2(s[2 * kt + 1][2], s[2 * kt + 1][3]);
    }
#pragma unroll
    for (int nt = 0; nt < 4; ++nt) {
      int vrow = lm + nt * 16, sw = vrow & 7;
#pragma unroll
      for (int kt = 0; kt < 2; ++kt) {
        bf16x8 vf = *(bf16x8*)&Vts[vrow * 64 + (((lg + kt * 4) ^ sw) * 8)];
        y[nt] = __builtin_amdgcn_mfma_f32_16x16x32_bf16(pk[kt].v, vf, y[nt], 0, 0, 0);
      }
    }
    __syncthreads();
  }
  // epilogue: weighted row-sums into z1/z2 (y: col lm = d, row lg*4+r = q)
  float invl = 1.f / lr;
  float invq[4], c1v[4], c2v[4];
#pragma unroll
  for (int r = 0; r < 4; ++r) {
    invq[r] = __shfl(invl, lg * 4 + r);
    coefs(pp + b * NN, qbase + lg * 4 + r, c1v[r], c2v[r]);
  }
  float a1[4], a2[4];
#pragma unroll
  for (int nt = 0; nt < 4; ++nt) {
    float u1 = 0.f, u2 = 0.f;
#pragma unroll
    for (int r = 0; r < 4; ++r) {
      float yv = y[nt][r] * invq[r];
      u1 += c1v[r] * yv;
      u2 += c2v[r] * yv;
    }
    u1 += __shfl_xor(u1, 16); u1 += __shfl_xor(u1, 32);
    u2 += __shfl_xor(u2, 16); u2 += __shfl_xor(u2, 32);
    a1[nt] = u1; a2[nt] = u2;
  }
  if (lg == 0) {
#pragma unroll
    for (int nt = 0; nt < 4; ++nt) {
      atomicAdd(&zz[b * HH + h * ASZ + nt * 16 + lm], a1[nt]);
      atomicAdd(&zz[BB * HH + b * HH + h * ASZ + nt * 16 + lm], a2[nt]);
    }
  }
}

// ============ F1: t_s = W_o @ (z_s / sumw) + b_o ============
__global__ void k_f1(const float* __restrict__ Wo, const float* __restrict__ bo,
                     const float* __restrict__ zz, const float* __restrict__ sumw,
                     float* __restrict__ tvec) {
  int b = blockIdx.y;
  int w = threadIdx.x >> 6, lane = threadIdx.x & 63;
  float inv = 1.f / sumw[b];
  const float* z1 = zz + b * HH;
  const float* z2 = zz + BB * HH + b * HH;
  float zr1[12], zr2[12];
#pragma unroll
  for (int m = 0; m < 12; ++m) { zr1[m] = z1[lane + 64 * m] * inv; zr2[m] = z2[lane + 64 * m] * inv; }
  for (int j = 0; j < 8; ++j) {
    int o = blockIdx.x * 32 + w * 8 + j;
    const float* wrow = Wo + (size_t)o * HH;
    float a1 = 0.f, a2 = 0.f;
#pragma unroll
    for (int m = 0; m < 12; ++m) { float wv = wrow[lane + 64 * m]; a1 += wv * zr1[m]; a2 += wv * zr2[m]; }
    for (int mask = 32; mask; mask >>= 1) { a1 += __shfl_xor(a1, mask); a2 += __shfl_xor(a2, mask); }
    if (lane == 0) { tvec[b * HH + o] = a1 + bo[o]; tvec[BB * HH + b * HH + o] = a2 + bo[o]; }
  }
}

// ============ F2: pm = WL @ t1 + WR @ t2 + b_atom ============
__global__ void k_f2(const float* __restrict__ Wa, const float* __restrict__ ba,
                     const float* __restrict__ tvec, float* __restrict__ pm) {
  int b = blockIdx.y;
  int w = threadIdx.x >> 6, lane = threadIdx.x & 63;
  const float* t1 = tvec + b * HH;
  const float* t2 = tvec + BB * HH + b * HH;
  float r1[12], r2[12];
#pragma unroll
  for (int m = 0; m < 12; ++m) { r1[m] = t1[lane + 64 * m]; r2[m] = t2[lane + 64 * m]; }
  for (int j = 0; j < 8; ++j) {
    int o = blockIdx.x * 32 + w * 8 + j;
    const float* wrow = Wa + (size_t)o * (2 * HH);
    float a = 0.f;
#pragma unroll
    for (int m = 0; m < 12; ++m) a += wrow[lane + 64 * m] * r1[m];
#pragma unroll
    for (int m = 0; m < 12; ++m) a += wrow[HH + lane + 64 * m] * r2[m];
    for (int mask = 32; mask; mask >>= 1) a += __shfl_xor(a, mask);
    if (lane == 0) pm[b * HH + o] = a + ba[o];
  }
}

// ============ F3: broadcast pm to (B,N,H) ============
__global__ void k_bcast(const float* __restrict__ pm, float* __restrict__ out) {
  size_t g = (size_t)blockIdx.x * 256 + threadIdx.x;
  int b = (int)(g / ((size_t)NN * HH / 4));
  int hh4 = (int)(g % (HH / 4));
  float4 val = *(const float4*)(pm + b * HH + hh4 * 4);
  *(float4*)(out + g * 4) = val;
}

// ================= launcher =================
extern "C" void kernel_launch(void* const* d_in, const int* in_sizes, int n_in,
                              void* d_out, int out_size, void* d_ws, size_t ws_size,
                              hipStream_t stream) {
  (void)in_sizes; (void)n_in; (void)out_size; (void)ws_size;
  const float* x       = (const float*)d_in[0];
  const float* W_var   = (const float*)d_in[3];
  const float* b_var   = (const float*)d_in[4];
  const float* W_sym   = (const float*)d_in[5];
  const float* b_sym   = (const float*)d_in[6];
  const float* W_score = (const float*)d_in[7];
  const float* b_score = (const float*)d_in[8];
  const float* W_cross = (const float*)d_in[9];
  const float* b_cross = (const float*)d_in[10];
  const float* W_atom  = (const float*)d_in[11];
  const float* b_atom  = (const float*)d_in[12];
  const float* W_q     = (const float*)d_in[13];
  const float* b_q     = (const float*)d_in[14];
  const float* W_k     = (const float*)d_in[15];
  const float* b_k     = (const float*)d_in[16];
  const float* W_v     = (const float*)d_in[17];
  const float* b_v     = (const float*)d_in[18];
  const float* W_o     = (const float*)d_in[19];
  const float* b_o     = (const float*)d_in[20];
  const int*   pp      = (const int*)d_in[21];
  const int*   occ     = (const int*)d_in[24];
  float* out = (float*)d_out;
  char* wsb = (char*)d_ws;
  ushort* qb  = (ushort*)(wsb + OFFB_QB);
  ushort* kbf = (ushort*)(wsb + OFFB_KB);
  ushort* vtb = (ushort*)(wsb + OFFB_VB);
  ushort* xb  = (ushort*)(wsb + OFFB_XB);
  ushort* wqb = (ushort*)(wsb + OFFB_WQB);
  ushort* wkb = (ushort*)(wsb + OFFB_WKB);
  ushort* wvb = (ushort*)(wsb + OFFB_WVB);
  ushort* wvar = (ushort*)(wsb + OFFB_WVAR);
  ushort* wsym = (ushort*)(wsb + OFFB_WSYM);
  ushort* vrows = (ushort*)(wsb + OFFB_VROWS);
  float* sraw = (float*)(wsb + OFFB_SRAW);
  float* diag = (float*)(wsb + OFFB_DIAG);
  float4* bias4 = (float4*)(wsb + OFFB_BIAS4);
  int* plist = (int*)(wsb + OFFB_PLIST);
  int* pcnt  = (int*)(wsb + OFFB_PCNT);
  float* sumw = (float*)(wsb + OFFB_SUMW);
  float* zz   = (float*)(wsb + OFFB_ZZ);
  float* tv   = (float*)(wsb + OFFB_TV);
  float* pm   = (float*)(wsb + OFFB_PM);

  k_pred<<<BB, 64, 0, stream>>>(pp, plist, pcnt, sumw, sraw, diag, zz);
  // f32 -> bf16 conversions
  k_cvt<<<(BB * NN * HH / 4 + 255) / 256, 256, 0, stream>>>(x, xb, BB * NN * HH / 4);
  k_cvt5<<<dim3(HH * HH / 4 / 256, 5), 256, 0, stream>>>(W_q, W_k, W_v, W_var, W_sym,
                                                          wqb, wkb, wvb, wvar, wsym);
  // gather var_in rows (bf16, compact)
  k_gather<<<dim3(PRMAX / 4, BB), 256, 0, stream>>>(xb, pp, plist, pcnt, vrows);
  // score path (bf16 MFMA, register-prefetched, 64-row tiles over 1536 cols)
  k_score_mf<<<dim3(12, 6, BB), 256, 0, stream>>>(xb, vrows, plist, pcnt, wvar, wsym,
                                                  b_var, b_sym, W_score, sraw);
  k_cross<<<BB * MM / 4, 256, 0, stream>>>(x, occ, W_cross, b_cross, diag);
  k_bias<<<BB * NN / 256, 256, 0, stream>>>(pp, sraw, diag, b_score, bias4);
  // fused QKV MFMA GEMM (bf16); V written transposed; Q scaled into exp2 domain
  k_gemm_bf<<<dim3(64, 6, 3), 256, 0, stream>>>(xb, wqb, wkb, wvb, b_q, b_k, b_v, qb, kbf, vtb);
  // MFMA flash attention (128 q-rows/block, 8 waves); grid x=(h,b) for XCD L2 reuse
  k_attn2<<<dim3(NHD * BB, NN / 128), 512, 0, stream>>>(qb, kbf, vtb, bias4, pp, zz);
  k_f1<<<dim3(24, BB), 256, 0, stream>>>(W_o, b_o, zz, sumw, tv);
  k_f2<<<dim3(24, BB), 256, 0, stream>>>(W_atom, b_atom, tv, pm);
  k_bcast<<<BB * NN * HH / 1024, 256, 0, stream>>>(pm, out);
}

// Round 10
// 168.387 us; speedup vs baseline: 8.3996x; 1.0238x over previous
//
#include <hip/hip_runtime.h>
#include <hip/hip_bf16.h>

// ================= problem constants =================
#define BB 8
#define NN 1024
#define HH 768
#define NHD 12
#define ASZ 64
#define MM 256
#define QSCALE 0.125f   // AS^-0.5
#define NSLOPE 0.02f
#define LOG2E 1.44269504f
#define PRMAX 384       // padded predicate rows per batch

typedef __attribute__((ext_vector_type(8))) short bf16x8;
typedef __attribute__((ext_vector_type(4))) float f32x4;

#define EXP2F(x) __builtin_amdgcn_exp2f(x)
#define RCPF(x)  __builtin_amdgcn_rcpf(x)

// ============ workspace layout (byte offsets, all 16B-aligned) ============
#define OFFB_QB    ((size_t)0)            // 8*1024*768 bf16
#define OFFB_KB    ((size_t)12582912)
#define OFFB_VB    ((size_t)25165824)     // V^T: [b][h][d][n] bf16
#define OFFB_XB    ((size_t)37748736)     // x in bf16
#define OFFB_WQB   ((size_t)50331648)     // 768*768 bf16
#define OFFB_WKB   ((size_t)51511296)
#define OFFB_WVB   ((size_t)52690944)
#define OFFB_WVAR  ((size_t)53870592)     // W_var bf16
#define OFFB_WSYM  ((size_t)55050240)     // W_sym bf16
#define OFFB_SRAW  ((size_t)56229888)     // 8192 f32
#define OFFB_DIAG  ((size_t)56262656)     // 8192 f32
#define OFFB_BIAS4 ((size_t)56295424)     // 8192 float4
#define OFFB_PLIST ((size_t)56426496)     // 8192 i32
#define OFFB_PCNT  ((size_t)56459264)
#define OFFB_SUMW  ((size_t)56459296)
#define OFFB_ZZ    ((size_t)56459328)     // 2*8*768 f32
#define OFFB_TV    ((size_t)56508480)
#define OFFB_PM    ((size_t)56557632)
#define OFFB_VROWS ((size_t)56582208)     // 8*384*768 bf16 gathered var rows

__device__ __forceinline__ float lrelu(float v) { return v >= 0.f ? v : NSLOPE * v; }

__device__ __forceinline__ ushort f2bf(float f) {  // round-half-up f32->bf16 (2 ops)
  return (ushort)((__float_as_uint(f) + 0x8000u) >> 16);
}
__device__ __forceinline__ float bf2f(ushort u) {
  union { unsigned u; float f; } v; v.u = (unsigned)u << 16;
  return v.f;
}
__device__ __forceinline__ unsigned packbf2(float lo, float hi) {  // (bf(hi)<<16)|bf(lo)
  unsigned a = __float_as_uint(hi) + 0x8000u;
  unsigned b = __float_as_uint(lo) + 0x8000u;
  return __builtin_amdgcn_perm(a, b, 0x07060302u);
}
__device__ __forceinline__ float fast_tanh(float x) {  // exp2-domain, saturates to +-1
  float e = EXP2F(x * (2.f * LOG2E));
  return 1.f - 2.f * RCPF(e + 1.f);
}

// weights for the final weighted row-sums of y (derived from pm algebra).
__device__ __forceinline__ void coefs(const int* ppb, int j, float& c1, float& c2) {
  auto pred = [&](int tt) { return tt >= 0 && tt < NN && ppb[tt] == 1; };
  auto single = [&](int tt) { return tt == 0 || (tt >= 2 && ppb[tt - 2] == 1); };
  auto wgt = [&](int tt) {
    if (!pred(tt)) return 0.f;
    bool tri = (tt >= 1) && (tt <= 1 || !single(tt));
    return tri ? 3.f : 2.f;
  };
  float a = 0.f;
  if (pred(j + 1)) a += wgt(j + 1) * (single(j + 1) ? 0.f : 0.5f);
  if (j >= 1 && pred(j - 1)) a += wgt(j - 1) * (single(j - 1) ? 1.f : 0.5f);
  c1 = a;
  c2 = wgt(j);
}

// ============ K_cvt: f32 -> bf16 (vectorized) ============
__global__ void k_cvt(const float* __restrict__ src, ushort* __restrict__ dst, int n4) {
  int i = blockIdx.x * 256 + threadIdx.x;
  if (i >= n4) return;
  float4 v = ((const float4*)src)[i];
  ushort4 o;
  o.x = f2bf(v.x); o.y = f2bf(v.y); o.z = f2bf(v.z); o.w = f2bf(v.w);
  ((ushort4*)dst)[i] = o;
}

// ============ K_cvt5: five HHxHH weights in one dispatch ============
__global__ void k_cvt5(const float* __restrict__ s0, const float* __restrict__ s1,
                       const float* __restrict__ s2, const float* __restrict__ s3,
                       const float* __restrict__ s4,
                       ushort* __restrict__ d0, ushort* __restrict__ d1,
                       ushort* __restrict__ d2, ushort* __restrict__ d3,
                       ushort* __restrict__ d4) {
  int z = blockIdx.y;
  const float* src = z == 0 ? s0 : z == 1 ? s1 : z == 2 ? s2 : z == 3 ? s3 : s4;
  ushort* dst = z == 0 ? d0 : z == 1 ? d1 : z == 2 ? d2 : z == 3 ? d3 : d4;
  int i = blockIdx.x * 256 + threadIdx.x;   // HH*HH/4 = 147456, grid.x = 576
  float4 v = ((const float4*)src)[i];
  ushort4 o;
  o.x = f2bf(v.x); o.y = f2bf(v.y); o.z = f2bf(v.z); o.w = f2bf(v.w);
  ((ushort4*)dst)[i] = o;
}

// ============ K_pred: compact predicate list + sum of weights + ws zeroing ============
__global__ void k_pred(const int* __restrict__ pp, int* __restrict__ plist,
                       int* __restrict__ pcnt, float* __restrict__ sumw,
                       float* __restrict__ sraw, float* __restrict__ diag,
                       float* __restrict__ zz) {
  int b = blockIdx.x;
  int lane = threadIdx.x;  // blockDim 64
  const int* ppb = pp + b * NN;
  int base = 0;
  float wacc = 0.f;
  for (int c = 0; c < NN; c += 64) {
    int i = c + lane;
    bool isp = ppb[i] == 1;
    unsigned long long mask = __ballot(isp);
    if (isp) {
      int pos = base + __popcll(mask & ((1ull << lane) - 1ull));
      plist[b * NN + pos] = i;
      bool sing = (i == 0) || (i >= 2 && ppb[i - 2] == 1);
      bool tri = (i >= 1) && (i <= 1 || !sing);
      wacc += tri ? 3.f : 2.f;
    }
    base += __popcll(mask);
  }
  for (int off = 32; off; off >>= 1) wacc += __shfl_xor(wacc, off);
  if (lane == 0) { pcnt[b] = base; sumw[b] = wacc; }
  // zero this batch's accumulators (replaces hipMemsetAsync)
  for (int c = lane; c < NN; c += 64) { sraw[b * NN + c] = 0.f; diag[b * NN + c] = 0.f; }
  for (int c = lane; c < HH; c += 64) {
    zz[b * HH + c] = 0.f;
    zz[BB * HH + b * HH + c] = 0.f;
  }
}

// ============ K_gather: compact var_in rows (bf16) for the score GEMM ============
__global__ void k_gather(const ushort* __restrict__ xb, const int* __restrict__ pp,
                         const int* __restrict__ plist, const int* __restrict__ pcnt,
                         ushort* __restrict__ vrows) {
  int b = blockIdx.y;
  int j = blockIdx.x * 4 + (threadIdx.x >> 6);
  int lane = threadIdx.x & 63;
  if (j >= pcnt[b]) return;
  int i = plist[b * NN + j];
  bool sing = (i == 0) || (i >= 2 && pp[b * NN + i - 2] == 1);
  float wa = sing ? 0.f : 0.5f, wb = sing ? 1.f : 0.5f;
  const ushort* rp = xb + (size_t)(b * NN + ((i - 1) & (NN - 1))) * HH;
  const ushort* rn = xb + (size_t)(b * NN + ((i + 1) & (NN - 1))) * HH;
  ushort* dst = vrows + ((size_t)b * PRMAX + j) * HH;
#pragma unroll
  for (int it = 0; it < 3; ++it) {
    int d4 = lane + it * 64;   // HH/4 = 192 ushort4 groups
    ushort4 p4 = ((const ushort4*)rp)[d4];
    ushort4 n4 = ((const ushort4*)rn)[d4];
    ushort4 o;
    o.x = f2bf(wa * bf2f(p4.x) + wb * bf2f(n4.x));
    o.y = f2bf(wa * bf2f(p4.y) + wb * bf2f(n4.y));
    o.z = f2bf(wa * bf2f(p4.z) + wb * bf2f(n4.z));
    o.w = f2bf(wa * bf2f(p4.w) + wb * bf2f(n4.w));
    ((ushort4*)dst)[d4] = o;
  }
}

// ============ K_cross: occurrence-pair scores -> diag ============
__global__ void k_cross(const float* __restrict__ x, const int* __restrict__ occ,
                        const float* __restrict__ Wc, const float* __restrict__ bc,
                        float* __restrict__ diag) {
  int g = blockIdx.x * 4 + (threadIdx.x >> 6);
  int lane = threadIdx.x & 63;
  int b = g >> 8, m = g & (MM - 1);
  int o0 = occ[(b * MM + m) * 2 + 0];
  int o1 = occ[(b * MM + m) * 2 + 1];
  const float* x0 = x + (size_t)(b * NN + o0) * HH;
  const float* x1 = x + (size_t)(b * NN + o1) * HH;
  float acc = 0.f;
  for (int d = lane; d < HH; d += 64) acc += 0.5f * (x0[d] + x1[d]) * Wc[d];
  for (int off = 32; off; off >>= 1) acc += __shfl_xor(acc, off);
  if (lane == 0) {
    float sc = lrelu(acc + bc[0]);
    float sq = sc * sc;
    diag[b * NN + o0] = sq;
    diag[b * NN + o1] = sq;
  }
}

// ============ K_score_mf: bf16 MFMA score GEMM, register-prefetched ============
__global__ __launch_bounds__(256, 2) void k_score_mf(
    const ushort* __restrict__ xb, const ushort* __restrict__ vrows,
    const int* __restrict__ plist, const int* __restrict__ pcnt,
    const ushort* __restrict__ Wvar, const ushort* __restrict__ Wsym,
    const float* __restrict__ bvar, const float* __restrict__ bsym,
    const float* __restrict__ wscore, float* __restrict__ s_raw) {
  const int b = blockIdx.z;
  const int cnt = pcnt[b];
  const int j0 = blockIdx.y * 64;
  if (j0 >= cnt) return;
  const int n0g = blockIdx.x * 128;           // global col in [0,1536)
  const bool symh = n0g >= HH;
  const int n0 = symh ? n0g - HH : n0g;
  const ushort* W = symh ? Wsym : Wvar;
  const float* bias = symh ? bsym : bvar;
  __shared__ ushort As[64 * 64];
  __shared__ ushort Bs[128 * 64];
  __shared__ int pl[64];
  __shared__ float red[64];
  const int t = threadIdx.x;
  const int w = t >> 6, lane = t & 63, lg = lane >> 4, lm = lane & 15;
  const int wm = (w >> 1) * 32, wn = (w & 1) * 64;
  if (t < 64) {
    int j = j0 + t;
    pl[t] = (j < cnt) ? plist[b * NN + j] : 2;
    red[t] = 0.f;
  }
  __syncthreads();
  const int r0 = t >> 3, c = t & 7;
  const ushort* ap0; const ushort* ap1;
  if (symh) {
    const ushort* xbb = xb + (size_t)b * NN * HH;
    ap0 = xbb + (size_t)pl[r0] * HH + c * 8;
    ap1 = xbb + (size_t)pl[r0 + 32] * HH + c * 8;
  } else {
    const ushort* vrb = vrows + ((size_t)b * PRMAX + j0) * HH;
    ap0 = vrb + (size_t)r0 * HH + c * 8;
    ap1 = vrb + (size_t)(r0 + 32) * HH + c * 8;
  }
  const ushort* bp = W + (size_t)(n0 + r0) * HH + c * 8;
  uint4 ar0 = *(const uint4*)ap0;
  uint4 ar1 = *(const uint4*)ap1;
  uint4 br0 = *(const uint4*)bp;
  uint4 br1 = *(const uint4*)(bp + (size_t)32 * HH);
  uint4 br2 = *(const uint4*)(bp + (size_t)64 * HH);
  uint4 br3 = *(const uint4*)(bp + (size_t)96 * HH);
  f32x4 acc[2][4] = {};
  const int ssw = (c ^ (r0 & 7)) * 8;   // swizzle invariant under row+32
  for (int k0 = 0; k0 < HH; k0 += 64) {
    if (k0) __syncthreads();
    *(uint4*)&As[r0 * 64 + ssw] = ar0;
    *(uint4*)&As[(r0 + 32) * 64 + ssw] = ar1;
    *(uint4*)&Bs[r0 * 64 + ssw] = br0;
    *(uint4*)&Bs[(r0 + 32) * 64 + ssw] = br1;
    *(uint4*)&Bs[(r0 + 64) * 64 + ssw] = br2;
    *(uint4*)&Bs[(r0 + 96) * 64 + ssw] = br3;
    __syncthreads();
    if (k0 + 64 < HH) {   // prefetch next K-step into registers
      ap0 += 64; ap1 += 64; bp += 64;
      ar0 = *(const uint4*)ap0;
      ar1 = *(const uint4*)ap1;
      br0 = *(const uint4*)bp;
      br1 = *(const uint4*)(bp + (size_t)32 * HH);
      br2 = *(const uint4*)(bp + (size_t)64 * HH);
      br3 = *(const uint4*)(bp + (size_t)96 * HH);
    }
    bf16x8 af[2][2], bfr[4][2];
#pragma unroll
    for (int mt = 0; mt < 2; ++mt)
#pragma unroll
      for (int kt = 0; kt < 2; ++kt) {
        int row = wm + mt * 16 + lm, ch = lg + kt * 4;
        af[mt][kt] = *(bf16x8*)&As[row * 64 + ((ch ^ (row & 7)) * 8)];
      }
#pragma unroll
    for (int nt = 0; nt < 4; ++nt)
#pragma unroll
      for (int kt = 0; kt < 2; ++kt) {
        int row = wn + nt * 16 + lm, ch = lg + kt * 4;
        bfr[nt][kt] = *(bf16x8*)&Bs[row * 64 + ((ch ^ (row & 7)) * 8)];
      }
#pragma unroll
    for (int mt = 0; mt < 2; ++mt)
#pragma unroll
      for (int nt = 0; nt < 4; ++nt)
#pragma unroll
        for (int kt = 0; kt < 2; ++kt)
          acc[mt][nt] = __builtin_amdgcn_mfma_f32_16x16x32_bf16(af[mt][kt], bfr[nt][kt], acc[mt][nt], 0, 0, 0);
  }
  // epilogue: fast tanh + dot with W_score, reduce over cols
  float bcol[4], wcol[4];
#pragma unroll
  for (int nt = 0; nt < 4; ++nt) {
    int cl = wn + nt * 16 + lm;
    bcol[nt] = bias[n0 + cl];
    wcol[nt] = wscore[n0g + cl];
  }
#pragma unroll
  for (int mt = 0; mt < 2; ++mt)
#pragma unroll
    for (int r = 0; r < 4; ++r) {
      float p = 0.f;
#pragma unroll
      for (int nt = 0; nt < 4; ++nt)
        p += fast_tanh(acc[mt][nt][r] + bcol[nt]) * wcol[nt];
      p += __shfl_xor(p, 1); p += __shfl_xor(p, 2);
      p += __shfl_xor(p, 4); p += __shfl_xor(p, 8);
      if (lm == 0) atomicAdd(&red[wm + mt * 16 + lg * 4 + r], p);
    }
  __syncthreads();
  if (t < 64) {
    int j2 = j0 + t;
    if (j2 < cnt) atomicAdd(&s_raw[b * NN + pl[t]], red[t]);
  }
}

// ============ K_bias: per-row sparse bias window (scaled by log2e for exp2 softmax) ============
__global__ void k_bias(const int* __restrict__ pp, const float* __restrict__ s_raw,
                       const float* __restrict__ diag, const float* __restrict__ b_score,
                       float4* __restrict__ bias4) {
  int g = blockIdx.x * 256 + threadIdx.x;
  int b = g >> 10, r = g & (NN - 1);
  const int* ppb = pp + b * NN;
  int i = -1;
  if (ppb[r] == 1) i = r;
  else if (r + 1 < NN && ppb[r + 1] == 1) i = r + 1;
  else if (r >= 1 && ppb[r - 1] == 1) i = r - 1;
  float v0 = 0.f, v1 = 0.f, v2 = 0.f; int cw = r;
  if (i >= 1 && i + 1 < NN) {
    float s = lrelu(s_raw[b * NN + i] + b_score[0]);
    float s2 = s * s;
    cw = i - 1;
    if (i == r) { v0 = 0.2f * s; v1 = 1.6f * s2; v2 = 0.2f * s; }
    else       { v0 = 0.8f * s2; v1 = 0.2f * s; v2 = 0.8f * s2; }
  }
  int slot = r - cw;
  float d = diag[g];
  if (slot == 0) v0 += d; else if (slot == 1) v1 += d; else v2 += d;
  bias4[g] = make_float4(__int_as_float(cw), v0 * LOG2E, v1 * LOG2E, v2 * LOG2E);
}

// ============ K_gemm_bf: fused QKV bf16 MFMA GEMM, register-prefetched ============
// z=0: Q row-major *(QSCALE*log2e) ; z=1: K row-major ; z=2: V^T [b][h][d][n]
__global__ __launch_bounds__(256, 2) void k_gemm_bf(
    const ushort* __restrict__ X,
    const ushort* __restrict__ W0, const ushort* __restrict__ W1, const ushort* __restrict__ W2,
    const float* __restrict__ b0, const float* __restrict__ b1, const float* __restrict__ b2,
    ushort* __restrict__ C0, ushort* __restrict__ C1, ushort* __restrict__ C2) {
  const int z = blockIdx.z;
  const ushort* W = z == 0 ? W0 : (z == 1 ? W1 : W2);
  const float* bias = z == 0 ? b0 : (z == 1 ? b1 : b2);
  ushort* C = z == 0 ? C0 : (z == 1 ? C1 : C2);
  const float alpha = z == 0 ? QSCALE * LOG2E : 1.f;
  __shared__ ushort As[128 * 64];
  __shared__ ushort Bs[128 * 64];
  const int m0 = blockIdx.x * 128, n0 = blockIdx.y * 128;
  const int t = threadIdx.x;
  const int w = t >> 6, lane = t & 63, lg = lane >> 4, lm = lane & 15;
  const int wm = (w >> 1) * 64, wn = (w & 1) * 64;
  const int r0 = t >> 3, c = t & 7;
  const int ssw = (c ^ (r0 & 7)) * 8;   // swizzle invariant under row+32k
  const ushort* Xp = X + (size_t)(m0 + r0) * HH + c * 8;
  const ushort* Wp = W + (size_t)(n0 + r0) * HH + c * 8;
  uint4 xa0 = *(const uint4*)Xp;
  uint4 xa1 = *(const uint4*)(Xp + (size_t)32 * HH);
  uint4 xa2 = *(const uint4*)(Xp + (size_t)64 * HH);
  uint4 xa3 = *(const uint4*)(Xp + (size_t)96 * HH);
  uint4 wb0 = *(const uint4*)Wp;
  uint4 wb1 = *(const uint4*)(Wp + (size_t)32 * HH);
  uint4 wb2 = *(const uint4*)(Wp + (size_t)64 * HH);
  uint4 wb3 = *(const uint4*)(Wp + (size_t)96 * HH);
  f32x4 acc[4][4] = {};
  for (int k0 = 0; k0 < HH; k0 += 64) {
    if (k0) __syncthreads();
    *(uint4*)&As[r0 * 64 + ssw] = xa0;
    *(uint4*)&As[(r0 + 32) * 64 + ssw] = xa1;
    *(uint4*)&As[(r0 + 64) * 64 + ssw] = xa2;
    *(uint4*)&As[(r0 + 96) * 64 + ssw] = xa3;
    *(uint4*)&Bs[r0 * 64 + ssw] = wb0;
    *(uint4*)&Bs[(r0 + 32) * 64 + ssw] = wb1;
    *(uint4*)&Bs[(r0 + 64) * 64 + ssw] = wb2;
    *(uint4*)&Bs[(r0 + 96) * 64 + ssw] = wb3;
    __syncthreads();
    if (k0 + 64 < HH) {   // prefetch next K-step into registers
      Xp += 64; Wp += 64;
      xa0 = *(const uint4*)Xp;
      xa1 = *(const uint4*)(Xp + (size_t)32 * HH);
      xa2 = *(const uint4*)(Xp + (size_t)64 * HH);
      xa3 = *(const uint4*)(Xp + (size_t)96 * HH);
      wb0 = *(const uint4*)Wp;
      wb1 = *(const uint4*)(Wp + (size_t)32 * HH);
      wb2 = *(const uint4*)(Wp + (size_t)64 * HH);
      wb3 = *(const uint4*)(Wp + (size_t)96 * HH);
    }
    bf16x8 af[4][2], bfr[4][2];
#pragma unroll
    for (int mt = 0; mt < 4; ++mt)
#pragma unroll
      for (int kt = 0; kt < 2; ++kt) {
        int row = wm + mt * 16 + lm, ch = lg + kt * 4;
        af[mt][kt] = *(bf16x8*)&As[row * 64 + ((ch ^ (row & 7)) * 8)];
      }
#pragma unroll
    for (int nt = 0; nt < 4; ++nt)
#pragma unroll
      for (int kt = 0; kt < 2; ++kt) {
        int row = wn + nt * 16 + lm, ch = lg + kt * 4;
        bfr[nt][kt] = *(bf16x8*)&Bs[row * 64 + ((ch ^ (row & 7)) * 8)];
      }
#pragma unroll
    for (int mt = 0; mt < 4; ++mt)
#pragma unroll
      for (int nt = 0; nt < 4; ++nt)
#pragma unroll
        for (int kt = 0; kt < 2; ++kt)
          acc[mt][nt] = __builtin_amdgcn_mfma_f32_16x16x32_bf16(af[mt][kt], bfr[nt][kt], acc[mt][nt], 0, 0, 0);
  }
  if (z == 2) {
#pragma unroll
    for (int nt = 0; nt < 4; ++nt) {
      int col = n0 + wn + nt * 16 + lm;
      int hh = col >> 6, dd = col & 63;
      float bcol = bias[col];
#pragma unroll
      for (int mt = 0; mt < 4; ++mt) {
        int row0 = m0 + wm + mt * 16 + lg * 4;
        int bb2 = row0 >> 10, nr = row0 & (NN - 1);
        ushort4 o;
        o.x = f2bf(acc[mt][nt][0] + bcol);
        o.y = f2bf(acc[mt][nt][1] + bcol);
        o.z = f2bf(acc[mt][nt][2] + bcol);
        o.w = f2bf(acc[mt][nt][3] + bcol);
        *(ushort4*)(C + ((size_t)(bb2 * NHD + hh) * ASZ + dd) * NN + nr) = o;
      }
    }
  } else {
#pragma unroll
    for (int nt = 0; nt < 4; ++nt) {
      int col = n0 + wn + nt * 16 + lm;
      float bcol = bias[col];
#pragma unroll
      for (int mt = 0; mt < 4; ++mt)
#pragma unroll
        for (int r = 0; r < 4; ++r) {
          int row = m0 + wm + mt * 16 + lg * 4 + r;
          C[(size_t)row * HH + col] = f2bf((acc[mt][nt][r] + bcol) * alpha);
        }
    }
  }
}

// ============ K_attn2: swapped-QK^T MFMA flash attention, dbuf LDS ============
// 8 waves x 16 q-rows (128 q/block). exp2-domain softmax; v_perm P-pack;
// double-buffered LDS (1 barrier/tile); K/V prefetched 2 tiles ahead in regs.
__global__ __launch_bounds__(512, 2) void k_attn2(
    const ushort* __restrict__ qg, const ushort* __restrict__ kg, const ushort* __restrict__ vtg,
    const float4* __restrict__ bias4, const int* __restrict__ pp, float* __restrict__ zz) {
  __shared__ ushort Ks[2][64 * 64];
  __shared__ ushort Vts[2][64 * 64];
  const int rb = blockIdx.y, h = blockIdx.x >> 3, b = blockIdx.x & 7;
  const int n0 = rb * 128;
  const int t = threadIdx.x, w = t >> 6, lane = t & 63, lg = lane >> 4, lm = lane & 15;
  const int qbase = n0 + w * 16;
  const ushort* qrow = qg + (size_t)(b * NN + qbase + lm) * HH + h * ASZ;
  bf16x8 qf[2];
  qf[0] = *(const bf16x8*)(qrow + lg * 8);
  qf[1] = *(const bf16x8*)(qrow + lg * 8 + 32);
  float4 bz = bias4[b * NN + qbase + lm];
  const int cwq = __float_as_int(bz.x);
  float mr = -1e30f, lr = 0.f;   // exp2-domain online softmax state for q = qbase+lm
  f32x4 y[4] = {};
  const ushort* kb = kg + (size_t)(b * NN) * HH + h * ASZ;
  const ushort* vtb = vtg + (size_t)(b * NHD + h) * ASZ * NN;
  const int srow = t >> 3, sc = t & 7;   // 512 threads = 64 rows x 8 chunks
  const int arow = (srow & 35) | ((srow & 4) << 2) | ((srow & 24) >> 1);  // K row permutation
  const int kssw = (sc ^ (arow & 7)) * 8;
  const int vssw = (sc ^ (srow & 7)) * 8;
  const ushort* kptr = kb + (size_t)srow * HH + sc * 8;
  const ushort* vptr = vtb + (size_t)srow * NN + sc * 8;
  // prologue: stage tile 0 into buf 0, prefetch tile 1 into regs
  uint4 kreg = *(const uint4*)kptr;
  uint4 vreg = *(const uint4*)vptr;
  *(uint4*)&Ks[0][arow * 64 + kssw] = kreg;
  *(uint4*)&Vts[0][srow * 64 + vssw] = vreg;
  kptr += 64 * HH; vptr += 64;
  kreg = *(const uint4*)kptr;
  vreg = *(const uint4*)vptr;
  __syncthreads();
  for (int tile = 0; tile < 16; ++tile) {
    const int c0 = tile * 64;
    const int cur = tile & 1;
    if (tile < 15) {   // write next tile into the other buffer (overlaps compute)
      *(uint4*)&Ks[cur ^ 1][arow * 64 + kssw] = kreg;
      *(uint4*)&Vts[cur ^ 1][srow * 64 + vssw] = vreg;
    }
    if (tile < 14) {   // prefetch tile+2 into registers
      kptr += 64 * HH; vptr += 64;
      kreg = *(const uint4*)kptr;
      vreg = *(const uint4*)vptr;
    }
    f32x4 s[4] = {};
#pragma unroll
    for (int nt = 0; nt < 4; ++nt) {
      int krow = lm + nt * 16, sw = krow & 7;
#pragma unroll
      for (int kt = 0; kt < 2; ++kt) {
        bf16x8 kf = *(bf16x8*)&Ks[cur][krow * 64 + (((lg + kt * 4) ^ sw) * 8)];
        s[nt] = __builtin_amdgcn_mfma_f32_16x16x32_bf16(kf, qf[kt], s[nt], 0, 0, 0);
      }
    }
    // sparse bias: token of s[nt][r] = c0 + (nt>>1)*32 + lg*8 + (nt&1)*4 + r
    if (c0 <= qbase + 17 && qbase <= c0 + 65) {
#pragma unroll
      for (int nt = 0; nt < 4; ++nt) {
        int kb2 = c0 + (nt >> 1) * 32 + lg * 8 + (nt & 1) * 4;
#pragma unroll
        for (int r = 0; r < 4; ++r) {
          int dd = kb2 + r - cwq;
          if (dd >= 0 && dd < 3) s[nt][r] += (dd == 0) ? bz.y : (dd == 1 ? bz.z : bz.w);
        }
      }
    }
    // online softmax (exp2 domain): row lane-local + 2 shfl
    f32x4 m4;
#pragma unroll
    for (int e = 0; e < 4; ++e)
      m4[e] = fmaxf(fmaxf(s[0][e], s[1][e]), fmaxf(s[2][e], s[3][e]));
    float tm = fmaxf(fmaxf(m4[0], m4[1]), fmaxf(m4[2], m4[3]));
    tm = fmaxf(tm, __shfl_xor(tm, 16));
    tm = fmaxf(tm, __shfl_xor(tm, 32));
    int need = tm > mr;
    if (__any(need)) {
      float mn = fmaxf(mr, tm);
      float f = EXP2F(mr - mn);
      mr = mn;
      lr *= f;
      float fr[4];
#pragma unroll
      for (int r = 0; r < 4; ++r) fr[r] = __shfl(f, lg * 4 + r);
#pragma unroll
      for (int nt = 0; nt < 4; ++nt)
#pragma unroll
        for (int r = 0; r < 4; ++r) y[nt][r] *= fr[r];
    }
    f32x4 sum4 = {0.f, 0.f, 0.f, 0.f};
#pragma unroll
    for (int nt = 0; nt < 4; ++nt)
#pragma unroll
      for (int e = 0; e < 4; ++e) {
        float p = EXP2F(s[nt][e] - mr);
        s[nt][e] = p;
        sum4[e] += p;
      }
    float ts = (sum4[0] + sum4[1]) + (sum4[2] + sum4[3]);
    ts += __shfl_xor(ts, 16);
    ts += __shfl_xor(ts, 32);
    lr += ts;
    // pack P into PV A-frags via v_perm (register-local)
    union { unsigned u[4]; bf16x8 v; } pk[2];
#pragma unroll
    for (int kt = 0; kt < 2; ++kt) {
      pk[kt].u[0] = packbf2(s[2 * kt][0], s[2 * kt][1]);
      pk[kt].u[1] = packbf2(s[2 * kt][2], s[2 * kt][3]);
      pk[kt].u[2] = packbf2(s[2 * kt + 1][0], s[2 * kt + 1][1]);
      pk[kt].u[3] = packbf2(s[2 * kt + 1][2], s[2 * kt + 1][3]);
    }
#pragma unroll
    for (int nt = 0; nt < 4; ++nt) {
      int vrow = lm + nt * 16, sw = vrow & 7;
#pragma unroll
      for (int kt = 0; kt < 2; ++kt) {
        bf16x8 vf = *(bf16x8*)&Vts[cur][vrow * 64 + (((lg + kt * 4) ^ sw) * 8)];
        y[nt] = __builtin_amdgcn_mfma_f32_16x16x32_bf16(pk[kt].v, vf, y[nt], 0, 0, 0);
      }
    }
    __syncthreads();   // single barrier: readers of buf[cur] done + writes to buf[cur^1] visible
  }
  // epilogue: weighted row-sums into z1/z2 (y: col lm = d, row lg*4+r = q)
  float invl = 1.f / lr;
  float invq[4], c1v[4], c2v[4];
#pragma unroll
  for (int r = 0; r < 4; ++r) {
    invq[r] = __shfl(invl, lg * 4 + r);
    coefs(pp + b * NN, qbase + lg * 4 + r, c1v[r], c2v[r]);
  }
  float a1[4], a2[4];
#pragma unroll
  for (int nt = 0; nt < 4; ++nt) {
    float u1 = 0.f, u2 = 0.f;
#pragma unroll
    for (int r = 0; r < 4; ++r) {
      float yv = y[nt][r] * invq[r];
      u1 += c1v[r] * yv;
      u2 += c2v[r] * yv;
    }
    u1 += __shfl_xor(u1, 16); u1 += __shfl_xor(u1, 32);
    u2 += __shfl_xor(u2, 16); u2 += __shfl_xor(u2, 32);
    a1[nt] = u1; a2[nt] = u2;
  }
  if (lg == 0) {
#pragma unroll
    for (int nt = 0; nt < 4; ++nt) {
      atomicAdd(&zz[b * HH + h * ASZ + nt * 16 + lm], a1[nt]);
      atomicAdd(&zz[BB * HH + b * HH + h * ASZ + nt * 16 + lm], a2[nt]);
    }
  }
}

// ============ F1: t_s = W_o @ (z_s / sumw) + b_o ============
__global__ void k_f1(const float* __restrict__ Wo, const float* __restrict__ bo,
                     const float* __restrict__ zz, const float* __restrict__ sumw,
                     float* __restrict__ tvec) {
  int b = blockIdx.y;
  int w = threadIdx.x >> 6, lane = threadIdx.x & 63;
  float inv = 1.f / sumw[b];
  const float* z1 = zz + b * HH;
  const float* z2 = zz + BB * HH + b * HH;
  float zr1[12], zr2[12];
#pragma unroll
  for (int m = 0; m < 12; ++m) { zr1[m] = z1[lane + 64 * m] * inv; zr2[m] = z2[lane + 64 * m] * inv; }
  for (int j = 0; j < 8; ++j) {
    int o = blockIdx.x * 32 + w * 8 + j;
    const float* wrow = Wo + (size_t)o * HH;
    float a1 = 0.f, a2 = 0.f;
#pragma unroll
    for (int m = 0; m < 12; ++m) { float wv = wrow[lane + 64 * m]; a1 += wv * zr1[m]; a2 += wv * zr2[m]; }
    for (int mask = 32; mask; mask >>= 1) { a1 += __shfl_xor(a1, mask); a2 += __shfl_xor(a2, mask); }
    if (lane == 0) { tvec[b * HH + o] = a1 + bo[o]; tvec[BB * HH + b * HH + o] = a2 + bo[o]; }
  }
}

// ============ F2: pm = WL @ t1 + WR @ t2 + b_atom ============
__global__ void k_f2(const float* __restrict__ Wa, const float* __restrict__ ba,
                     const float* __restrict__ tvec, float* __restrict__ pm) {
  int b = blockIdx.y;
  int w = threadIdx.x >> 6, lane = threadIdx.x & 63;
  const float* t1 = tvec + b * HH;
  const float* t2 = tvec + BB * HH + b * HH;
  float r1[12], r2[12];
#pragma unroll
  for (int m = 0; m < 12; ++m) { r1[m] = t1[lane + 64 * m]; r2[m] = t2[lane + 64 * m]; }
  for (int j = 0; j < 8; ++j) {
    int o = blockIdx.x * 32 + w * 8 + j;
    const float* wrow = Wa + (size_t)o * (2 * HH);
    float a = 0.f;
#pragma unroll
    for (int m = 0; m < 12; ++m) a += wrow[lane + 64 * m] * r1[m];
#pragma unroll
    for (int m = 0; m < 12; ++m) a += wrow[HH + lane + 64 * m] * r2[m];
    for (int mask = 32; mask; mask >>= 1) a += __shfl_xor(a, mask);
    if (lane == 0) pm[b * HH + o] = a + ba[o];
  }
}

// ============ F3: broadcast pm to (B,N,H) ============
__global__ void k_bcast(const float* __restrict__ pm, float* __restrict__ out) {
  size_t g = (size_t)blockIdx.x * 256 + threadIdx.x;
  int b = (int)(g / ((size_t)NN * HH / 4));
  int hh4 = (int)(g % (HH / 4));
  float4 val = *(const float4*)(pm + b * HH + hh4 * 4);
  *(float4*)(out + g * 4) = val;
}

// ================= launcher =================
extern "C" void kernel_launch(void* const* d_in, const int* in_sizes, int n_in,
                              void* d_out, int out_size, void* d_ws, size_t ws_size,
                              hipStream_t stream) {
  (void)in_sizes; (void)n_in; (void)out_size; (void)ws_size;
  const float* x       = (const float*)d_in[0];
  const float* W_var   = (const float*)d_in[3];
  const float* b_var   = (const float*)d_in[4];
  const float* W_sym   = (const float*)d_in[5];
  const float* b_sym   = (const float*)d_in[6];
  const float* W_score = (const float*)d_in[7];
  const float* b_score = (const float*)d_in[8];
  const float* W_cross = (const float*)d_in[9];
  const float* b_cross = (const float*)d_in[10];
  const float* W_atom  = (const float*)d_in[11];
  const float* b_atom  = (const float*)d_in[12];
  const float* W_q     = (const float*)d_in[13];
  const float* b_q     = (const float*)d_in[14];
  const float* W_k     = (const float*)d_in[15];
  const float* b_k     = (const float*)d_in[16];
  const float* W_v     = (const float*)d_in[17];
  const float* b_v     = (const float*)d_in[18];
  const float* W_o     = (const float*)d_in[19];
  const float* b_o     = (const float*)d_in[20];
  const int*   pp      = (const int*)d_in[21];
  const int*   occ     = (const int*)d_in[24];
  float* out = (float*)d_out;
  char* wsb = (char*)d_ws;
  ushort* qb  = (ushort*)(wsb + OFFB_QB);
  ushort* kbf = (ushort*)(wsb + OFFB_KB);
  ushort* vtb = (ushort*)(wsb + OFFB_VB);
  ushort* xb  = (ushort*)(wsb + OFFB_XB);
  ushort* wqb = (ushort*)(wsb + OFFB_WQB);
  ushort* wkb = (ushort*)(wsb + OFFB_WKB);
  ushort* wvb = (ushort*)(wsb + OFFB_WVB);
  ushort* wvar = (ushort*)(wsb + OFFB_WVAR);
  ushort* wsym = (ushort*)(wsb + OFFB_WSYM);
  ushort* vrows = (ushort*)(wsb + OFFB_VROWS);
  float* sraw = (float*)(wsb + OFFB_SRAW);
  float* diag = (float*)(wsb + OFFB_DIAG);
  float4* bias4 = (float4*)(wsb + OFFB_BIAS4);
  int* plist = (int*)(wsb + OFFB_PLIST);
  int* pcnt  = (int*)(wsb + OFFB_PCNT);
  float* sumw = (float*)(wsb + OFFB_SUMW);
  float* zz   = (float*)(wsb + OFFB_ZZ);
  float* tv   = (float*)(wsb + OFFB_TV);
  float* pm   = (float*)(wsb + OFFB_PM);

  k_pred<<<BB, 64, 0, stream>>>(pp, plist, pcnt, sumw, sraw, diag, zz);
  // f32 -> bf16 conversions
  k_cvt<<<(BB * NN * HH / 4 + 255) / 256, 256, 0, stream>>>(x, xb, BB * NN * HH / 4);
  k_cvt5<<<dim3(HH * HH / 4 / 256, 5), 256, 0, stream>>>(W_q, W_k, W_v, W_var, W_sym,
                                                          wqb, wkb, wvb, wvar, wsym);
  // gather var_in rows (bf16, compact)
  k_gather<<<dim3(PRMAX / 4, BB), 256, 0, stream>>>(xb, pp, plist, pcnt, vrows);
  // score path (bf16 MFMA, register-prefetched, 64-row tiles over 1536 cols)
  k_score_mf<<<dim3(12, 6, BB), 256, 0, stream>>>(xb, vrows, plist, pcnt, wvar, wsym,
                                                  b_var, b_sym, W_score, sraw);
  k_cross<<<BB * MM / 4, 256, 0, stream>>>(x, occ, W_cross, b_cross, diag);
  k_bias<<<BB * NN / 256, 256, 0, stream>>>(pp, sraw, diag, b_score, bias4);
  // fused QKV MFMA GEMM (bf16, register-prefetched); V written transposed
  k_gemm_bf<<<dim3(64, 6, 3), 256, 0, stream>>>(xb, wqb, wkb, wvb, b_q, b_k, b_v, qb, kbf, vtb);
  // MFMA flash attention (128 q-rows/block, 8 waves, dbuf LDS); grid x=(h,b) for XCD L2 reuse
  k_attn2<<<dim3(NHD * BB, NN / 128), 512, 0, stream>>>(qb, kbf, vtb, bias4, pp, zz);
  k_f1<<<dim3(24, BB), 256, 0, stream>>>(W_o, b_o, zz, sumw, tv);
  k_f2<<<dim3(24, BB), 256, 0, stream>>>(W_atom, b_atom, tv, pm);
  k_bcast<<<BB * NN * HH / 1024, 256, 0, stream>>>(pm, out);
}

// Round 11
// 162.257 us; speedup vs baseline: 8.7170x; 1.0378x over previous
//
#include <hip/hip_runtime.h>
#include <hip/hip_bf16.h>

// ================= problem constants =================
#define BB 8
#define NN 1024
#define HH 768
#define NHD 12
#define ASZ 64
#define MM 256
#define QSCALE 0.125f   // AS^-0.5
#define NSLOPE 0.02f
#define LOG2E 1.44269504f
#define PRMAX 384       // padded predicate rows per batch

typedef __attribute__((ext_vector_type(8))) short bf16x8;
typedef __attribute__((ext_vector_type(4))) float f32x4;

#define EXP2F(x) __builtin_amdgcn_exp2f(x)
#define RCPF(x)  __builtin_amdgcn_rcpf(x)

// ============ workspace layout (byte offsets, all 16B-aligned) ============
#define OFFB_QB    ((size_t)0)            // 8*1024*768 bf16
#define OFFB_KB    ((size_t)12582912)
#define OFFB_VB    ((size_t)25165824)     // V^T: [b][h][d][n] bf16
#define OFFB_XB    ((size_t)37748736)     // x in bf16
#define OFFB_WQB   ((size_t)50331648)     // 768*768 bf16
#define OFFB_WKB   ((size_t)51511296)
#define OFFB_WVB   ((size_t)52690944)
#define OFFB_WVAR  ((size_t)53870592)     // W_var bf16
#define OFFB_WSYM  ((size_t)55050240)     // W_sym bf16
#define OFFB_SRAW  ((size_t)56229888)     // 8192 f32
#define OFFB_DIAG  ((size_t)56262656)     // 8192 f32
#define OFFB_BIAS4 ((size_t)56295424)     // 8192 float4
#define OFFB_PLIST ((size_t)56426496)     // 8192 i32
#define OFFB_PCNT  ((size_t)56459264)
#define OFFB_SUMW  ((size_t)56459296)
#define OFFB_ZZ    ((size_t)56459328)     // 2*8*768 f32
#define OFFB_TV    ((size_t)56508480)
#define OFFB_PM    ((size_t)56557632)
#define OFFB_VROWS ((size_t)56582208)     // 8*384*768 bf16 gathered var rows

__device__ __forceinline__ float lrelu(float v) { return v >= 0.f ? v : NSLOPE * v; }

__device__ __forceinline__ ushort f2bf(float f) {  // round-half-up f32->bf16 (2 ops)
  return (ushort)((__float_as_uint(f) + 0x8000u) >> 16);
}
__device__ __forceinline__ float bf2f(ushort u) {
  union { unsigned u; float f; } v; v.u = (unsigned)u << 16;
  return v.f;
}
__device__ __forceinline__ unsigned packbf2(float lo, float hi) {  // (bf(hi)<<16)|bf(lo)
  unsigned a = __float_as_uint(hi) + 0x8000u;
  unsigned b = __float_as_uint(lo) + 0x8000u;
  return __builtin_amdgcn_perm(a, b, 0x07060302u);
}
__device__ __forceinline__ float fast_tanh(float x) {  // exp2-domain, saturates to +-1
  float e = EXP2F(x * (2.f * LOG2E));
  return 1.f - 2.f * RCPF(e + 1.f);
}

// weights for the final weighted row-sums of y (derived from pm algebra).
__device__ __forceinline__ void coefs(const int* ppb, int j, float& c1, float& c2) {
  auto pred = [&](int tt) { return tt >= 0 && tt < NN && ppb[tt] == 1; };
  auto single = [&](int tt) { return tt == 0 || (tt >= 2 && ppb[tt - 2] == 1); };
  auto wgt = [&](int tt) {
    if (!pred(tt)) return 0.f;
    bool tri = (tt >= 1) && (tt <= 1 || !single(tt));
    return tri ? 3.f : 2.f;
  };
  float a = 0.f;
  if (pred(j + 1)) a += wgt(j + 1) * (single(j + 1) ? 0.f : 0.5f);
  if (j >= 1 && pred(j - 1)) a += wgt(j - 1) * (single(j - 1) ? 1.f : 0.5f);
  c1 = a;
  c2 = wgt(j);
}

// ============ K_pred: compact predicate list + sum of weights + ws zeroing ============
__global__ void k_pred(const int* __restrict__ pp, int* __restrict__ plist,
                       int* __restrict__ pcnt, float* __restrict__ sumw,
                       float* __restrict__ sraw, float* __restrict__ diag,
                       float* __restrict__ zz) {
  int b = blockIdx.x;
  int lane = threadIdx.x;  // blockDim 64
  const int* ppb = pp + b * NN;
  int base = 0;
  float wacc = 0.f;
  for (int c = 0; c < NN; c += 64) {
    int i = c + lane;
    bool isp = ppb[i] == 1;
    unsigned long long mask = __ballot(isp);
    if (isp) {
      int pos = base + __popcll(mask & ((1ull << lane) - 1ull));
      plist[b * NN + pos] = i;
      bool sing = (i == 0) || (i >= 2 && ppb[i - 2] == 1);
      bool tri = (i >= 1) && (i <= 1 || !sing);
      wacc += tri ? 3.f : 2.f;
    }
    base += __popcll(mask);
  }
  for (int off = 32; off; off >>= 1) wacc += __shfl_xor(wacc, off);
  if (lane == 0) { pcnt[b] = base; sumw[b] = wacc; }
  for (int c = lane; c < NN; c += 64) { sraw[b * NN + c] = 0.f; diag[b * NN + c] = 0.f; }
  for (int c = lane; c < HH; c += 64) {
    zz[b * HH + c] = 0.f;
    zz[BB * HH + b * HH + c] = 0.f;
  }
}

// ============ K_cvtall: x + 5 weights f32->bf16, plus cross scores ============
// blocks [0, NCVT): conversions ; blocks [NCVT, NCVT+512): occurrence-pair scores.
#define NXQ (BB * NN * HH / 4)      // 1572864
#define WQ  (HH * HH / 4)           // 147456
#define NCVT ((NXQ + 5 * WQ) / 256) // 9024
__global__ void k_cvtall(const float* __restrict__ x,
                         const float* __restrict__ s1, const float* __restrict__ s2,
                         const float* __restrict__ s3, const float* __restrict__ s4,
                         const float* __restrict__ s5,
                         ushort* __restrict__ dx,
                         ushort* __restrict__ d1, ushort* __restrict__ d2,
                         ushort* __restrict__ d3, ushort* __restrict__ d4,
                         ushort* __restrict__ d5,
                         const int* __restrict__ occ, const float* __restrict__ Wc,
                         const float* __restrict__ bc, float* __restrict__ diag) {
  if (blockIdx.x < NCVT) {
    int idx = blockIdx.x * 256 + threadIdx.x;
    const float* src; ushort* dst; int off;
    if (idx < NXQ) { src = x; dst = dx; off = idx; }
    else {
      int r = idx - NXQ;
      int z = r / WQ;
      off = r - z * WQ;
      src = z == 0 ? s1 : z == 1 ? s2 : z == 2 ? s3 : z == 3 ? s4 : s5;
      dst = z == 0 ? d1 : z == 1 ? d2 : z == 2 ? d3 : z == 3 ? d4 : d5;
    }
    float4 v = ((const float4*)src)[off];
    ushort4 o;
    o.x = f2bf(v.x); o.y = f2bf(v.y); o.z = f2bf(v.z); o.w = f2bf(v.w);
    ((ushort4*)dst)[off] = o;
  } else {
    int g = (blockIdx.x - NCVT) * 4 + (threadIdx.x >> 6);
    int lane = threadIdx.x & 63;
    int b = g >> 8, m = g & (MM - 1);
    int o0 = occ[(b * MM + m) * 2 + 0];
    int o1 = occ[(b * MM + m) * 2 + 1];
    const float* x0 = x + (size_t)(b * NN + o0) * HH;
    const float* x1 = x + (size_t)(b * NN + o1) * HH;
    float acc = 0.f;
    for (int d = lane; d < HH; d += 64) acc += 0.5f * (x0[d] + x1[d]) * Wc[d];
    for (int off = 32; off; off >>= 1) acc += __shfl_xor(acc, off);
    if (lane == 0) {
      float sc = lrelu(acc + bc[0]);
      float sq = sc * sc;
      diag[b * NN + o0] = sq;
      diag[b * NN + o1] = sq;
    }
  }
}

// ============ K_gather: compact var_in rows (bf16) for the score GEMM ============
__global__ void k_gather(const ushort* __restrict__ xb, const int* __restrict__ pp,
                         const int* __restrict__ plist, const int* __restrict__ pcnt,
                         ushort* __restrict__ vrows) {
  int b = blockIdx.y;
  int j = blockIdx.x * 4 + (threadIdx.x >> 6);
  int lane = threadIdx.x & 63;
  if (j >= pcnt[b]) return;
  int i = plist[b * NN + j];
  bool sing = (i == 0) || (i >= 2 && pp[b * NN + i - 2] == 1);
  float wa = sing ? 0.f : 0.5f, wb = sing ? 1.f : 0.5f;
  const ushort* rp = xb + (size_t)(b * NN + ((i - 1) & (NN - 1))) * HH;
  const ushort* rn = xb + (size_t)(b * NN + ((i + 1) & (NN - 1))) * HH;
  ushort* dst = vrows + ((size_t)b * PRMAX + j) * HH;
#pragma unroll
  for (int it = 0; it < 3; ++it) {
    int d4 = lane + it * 64;
    ushort4 p4 = ((const ushort4*)rp)[d4];
    ushort4 n4 = ((const ushort4*)rn)[d4];
    ushort4 o;
    o.x = f2bf(wa * bf2f(p4.x) + wb * bf2f(n4.x));
    o.y = f2bf(wa * bf2f(p4.y) + wb * bf2f(n4.y));
    o.z = f2bf(wa * bf2f(p4.z) + wb * bf2f(n4.z));
    o.w = f2bf(wa * bf2f(p4.w) + wb * bf2f(n4.w));
    ((ushort4*)dst)[d4] = o;
  }
}

// ============ K_score_mf: bf16 MFMA score GEMM, register-prefetched ============
__global__ __launch_bounds__(256, 2) void k_score_mf(
    const ushort* __restrict__ xb, const ushort* __restrict__ vrows,
    const int* __restrict__ plist, const int* __restrict__ pcnt,
    const ushort* __restrict__ Wvar, const ushort* __restrict__ Wsym,
    const float* __restrict__ bvar, const float* __restrict__ bsym,
    const float* __restrict__ wscore, float* __restrict__ s_raw) {
  const int b = blockIdx.z;
  const int cnt = pcnt[b];
  const int j0 = blockIdx.y * 64;
  if (j0 >= cnt) return;
  const int n0g = blockIdx.x * 128;           // global col in [0,1536)
  const bool symh = n0g >= HH;
  const int n0 = symh ? n0g - HH : n0g;
  const ushort* W = symh ? Wsym : Wvar;
  const float* bias = symh ? bsym : bvar;
  __shared__ ushort As[64 * 64];
  __shared__ ushort Bs[128 * 64];
  __shared__ int pl[64];
  __shared__ float red[64];
  const int t = threadIdx.x;
  const int w = t >> 6, lane = t & 63, lg = lane >> 4, lm = lane & 15;
  const int wm = (w >> 1) * 32, wn = (w & 1) * 64;
  if (t < 64) {
    int j = j0 + t;
    pl[t] = (j < cnt) ? plist[b * NN + j] : 2;
    red[t] = 0.f;
  }
  __syncthreads();
  const int r0 = t >> 3, c = t & 7;
  const ushort* ap0; const ushort* ap1;
  if (symh) {
    const ushort* xbb = xb + (size_t)b * NN * HH;
    ap0 = xbb + (size_t)pl[r0] * HH + c * 8;
    ap1 = xbb + (size_t)pl[r0 + 32] * HH + c * 8;
  } else {
    const ushort* vrb = vrows + ((size_t)b * PRMAX + j0) * HH;
    ap0 = vrb + (size_t)r0 * HH + c * 8;
    ap1 = vrb + (size_t)(r0 + 32) * HH + c * 8;
  }
  const ushort* bp = W + (size_t)(n0 + r0) * HH + c * 8;
  uint4 ar0 = *(const uint4*)ap0;
  uint4 ar1 = *(const uint4*)ap1;
  uint4 br0 = *(const uint4*)bp;
  uint4 br1 = *(const uint4*)(bp + (size_t)32 * HH);
  uint4 br2 = *(const uint4*)(bp + (size_t)64 * HH);
  uint4 br3 = *(const uint4*)(bp + (size_t)96 * HH);
  f32x4 acc[2][4] = {};
  const int ssw = (c ^ (r0 & 7)) * 8;
  for (int k0 = 0; k0 < HH; k0 += 64) {
    if (k0) __syncthreads();
    *(uint4*)&As[r0 * 64 + ssw] = ar0;
    *(uint4*)&As[(r0 + 32) * 64 + ssw] = ar1;
    *(uint4*)&Bs[r0 * 64 + ssw] = br0;
    *(uint4*)&Bs[(r0 + 32) * 64 + ssw] = br1;
    *(uint4*)&Bs[(r0 + 64) * 64 + ssw] = br2;
    *(uint4*)&Bs[(r0 + 96) * 64 + ssw] = br3;
    __syncthreads();
    if (k0 + 64 < HH) {
      ap0 += 64; ap1 += 64; bp += 64;
      ar0 = *(const uint4*)ap0;
      ar1 = *(const uint4*)ap1;
      br0 = *(const uint4*)bp;
      br1 = *(const uint4*)(bp + (size_t)32 * HH);
      br2 = *(const uint4*)(bp + (size_t)64 * HH);
      br3 = *(const uint4*)(bp + (size_t)96 * HH);
    }
    bf16x8 af[2][2], bfr[4][2];
#pragma unroll
    for (int mt = 0; mt < 2; ++mt)
#pragma unroll
      for (int kt = 0; kt < 2; ++kt) {
        int row = wm + mt * 16 + lm, ch = lg + kt * 4;
        af[mt][kt] = *(bf16x8*)&As[row * 64 + ((ch ^ (row & 7)) * 8)];
      }
#pragma unroll
    for (int nt = 0; nt < 4; ++nt)
#pragma unroll
      for (int kt = 0; kt < 2; ++kt) {
        int row = wn + nt * 16 + lm, ch = lg + kt * 4;
        bfr[nt][kt] = *(bf16x8*)&Bs[row * 64 + ((ch ^ (row & 7)) * 8)];
      }
#pragma unroll
    for (int mt = 0; mt < 2; ++mt)
#pragma unroll
      for (int nt = 0; nt < 4; ++nt)
#pragma unroll
        for (int kt = 0; kt < 2; ++kt)
          acc[mt][nt] = __builtin_amdgcn_mfma_f32_16x16x32_bf16(af[mt][kt], bfr[nt][kt], acc[mt][nt], 0, 0, 0);
  }
  float bcol[4], wcol[4];
#pragma unroll
  for (int nt = 0; nt < 4; ++nt) {
    int cl = wn + nt * 16 + lm;
    bcol[nt] = bias[n0 + cl];
    wcol[nt] = wscore[n0g + cl];
  }
#pragma unroll
  for (int mt = 0; mt < 2; ++mt)
#pragma unroll
    for (int r = 0; r < 4; ++r) {
      float p = 0.f;
#pragma unroll
      for (int nt = 0; nt < 4; ++nt)
        p += fast_tanh(acc[mt][nt][r] + bcol[nt]) * wcol[nt];
      p += __shfl_xor(p, 1); p += __shfl_xor(p, 2);
      p += __shfl_xor(p, 4); p += __shfl_xor(p, 8);
      if (lm == 0) atomicAdd(&red[wm + mt * 16 + lg * 4 + r], p);
    }
  __syncthreads();
  if (t < 64) {
    int j2 = j0 + t;
    if (j2 < cnt) atomicAdd(&s_raw[b * NN + pl[t]], red[t]);
  }
}

// ============ K_bias: per-row sparse bias window (log2e-scaled for exp2 softmax) ============
__global__ void k_bias(const int* __restrict__ pp, const float* __restrict__ s_raw,
                       const float* __restrict__ diag, const float* __restrict__ b_score,
                       float4* __restrict__ bias4) {
  int g = blockIdx.x * 256 + threadIdx.x;
  int b = g >> 10, r = g & (NN - 1);
  const int* ppb = pp + b * NN;
  int i = -1;
  if (ppb[r] == 1) i = r;
  else if (r + 1 < NN && ppb[r + 1] == 1) i = r + 1;
  else if (r >= 1 && ppb[r - 1] == 1) i = r - 1;
  float v0 = 0.f, v1 = 0.f, v2 = 0.f; int cw = r;
  if (i >= 1 && i + 1 < NN) {
    float s = lrelu(s_raw[b * NN + i] + b_score[0]);
    float s2 = s * s;
    cw = i - 1;
    if (i == r) { v0 = 0.2f * s; v1 = 1.6f * s2; v2 = 0.2f * s; }
    else       { v0 = 0.8f * s2; v1 = 0.2f * s; v2 = 0.8f * s2; }
  }
  int slot = r - cw;
  float d = diag[g];
  if (slot == 0) v0 += d; else if (slot == 1) v1 += d; else v2 += d;
  bias4[g] = make_float4(__int_as_float(cw), v0 * LOG2E, v1 * LOG2E, v2 * LOG2E);
}

// ============ K_gemm_bf: fused QKV bf16 MFMA GEMM, register-prefetched ============
// z=0: Q row-major *(QSCALE*log2e) ; z=1: K row-major ; z=2: V^T [b][h][d][n]
__global__ __launch_bounds__(256, 2) void k_gemm_bf(
    const ushort* __restrict__ X,
    const ushort* __restrict__ W0, const ushort* __restrict__ W1, const ushort* __restrict__ W2,
    const float* __restrict__ b0, const float* __restrict__ b1, const float* __restrict__ b2,
    ushort* __restrict__ C0, ushort* __restrict__ C1, ushort* __restrict__ C2) {
  const int z = blockIdx.z;
  const ushort* W = z == 0 ? W0 : (z == 1 ? W1 : W2);
  const float* bias = z == 0 ? b0 : (z == 1 ? b1 : b2);
  ushort* C = z == 0 ? C0 : (z == 1 ? C1 : C2);
  const float alpha = z == 0 ? QSCALE * LOG2E : 1.f;
  __shared__ ushort As[128 * 64];
  __shared__ ushort Bs[128 * 64];
  const int m0 = blockIdx.x * 128, n0 = blockIdx.y * 128;
  const int t = threadIdx.x;
  const int w = t >> 6, lane = t & 63, lg = lane >> 4, lm = lane & 15;
  const int wm = (w >> 1) * 64, wn = (w & 1) * 64;
  const int r0 = t >> 3, c = t & 7;
  const int ssw = (c ^ (r0 & 7)) * 8;
  const ushort* Xp = X + (size_t)(m0 + r0) * HH + c * 8;
  const ushort* Wp = W + (size_t)(n0 + r0) * HH + c * 8;
  uint4 xa0 = *(const uint4*)Xp;
  uint4 xa1 = *(const uint4*)(Xp + (size_t)32 * HH);
  uint4 xa2 = *(const uint4*)(Xp + (size_t)64 * HH);
  uint4 xa3 = *(const uint4*)(Xp + (size_t)96 * HH);
  uint4 wb0 = *(const uint4*)Wp;
  uint4 wb1 = *(const uint4*)(Wp + (size_t)32 * HH);
  uint4 wb2 = *(const uint4*)(Wp + (size_t)64 * HH);
  uint4 wb3 = *(const uint4*)(Wp + (size_t)96 * HH);
  f32x4 acc[4][4] = {};
  for (int k0 = 0; k0 < HH; k0 += 64) {
    if (k0) __syncthreads();
    *(uint4*)&As[r0 * 64 + ssw] = xa0;
    *(uint4*)&As[(r0 + 32) * 64 + ssw] = xa1;
    *(uint4*)&As[(r0 + 64) * 64 + ssw] = xa2;
    *(uint4*)&As[(r0 + 96) * 64 + ssw] = xa3;
    *(uint4*)&Bs[r0 * 64 + ssw] = wb0;
    *(uint4*)&Bs[(r0 + 32) * 64 + ssw] = wb1;
    *(uint4*)&Bs[(r0 + 64) * 64 + ssw] = wb2;
    *(uint4*)&Bs[(r0 + 96) * 64 + ssw] = wb3;
    __syncthreads();
    if (k0 + 64 < HH) {
      Xp += 64; Wp += 64;
      xa0 = *(const uint4*)Xp;
      xa1 = *(const uint4*)(Xp + (size_t)32 * HH);
      xa2 = *(const uint4*)(Xp + (size_t)64 * HH);
      xa3 = *(const uint4*)(Xp + (size_t)96 * HH);
      wb0 = *(const uint4*)Wp;
      wb1 = *(const uint4*)(Wp + (size_t)32 * HH);
      wb2 = *(const uint4*)(Wp + (size_t)64 * HH);
      wb3 = *(const uint4*)(Wp + (size_t)96 * HH);
    }
    bf16x8 af[4][2], bfr[4][2];
#pragma unroll
    for (int mt = 0; mt < 4; ++mt)
#pragma unroll
      for (int kt = 0; kt < 2; ++kt) {
        int row = wm + mt * 16 + lm, ch = lg + kt * 4;
        af[mt][kt] = *(bf16x8*)&As[row * 64 + ((ch ^ (row & 7)) * 8)];
      }
#pragma unroll
    for (int nt = 0; nt < 4; ++nt)
#pragma unroll
      for (int kt = 0; kt < 2; ++kt) {
        int row = wn + nt * 16 + lm, ch = lg + kt * 4;
        bfr[nt][kt] = *(bf16x8*)&Bs[row * 64 + ((ch ^ (row & 7)) * 8)];
      }
#pragma unroll
    for (int mt = 0; mt < 4; ++mt)
#pragma unroll
      for (int nt = 0; nt < 4; ++nt)
#pragma unroll
        for (int kt = 0; kt < 2; ++kt)
          acc[mt][nt] = __builtin_amdgcn_mfma_f32_16x16x32_bf16(af[mt][kt], bfr[nt][kt], acc[mt][nt], 0, 0, 0);
  }
  if (z == 2) {
#pragma unroll
    for (int nt = 0; nt < 4; ++nt) {
      int col = n0 + wn + nt * 16 + lm;
      int hh = col >> 6, dd = col & 63;
      float bcol = bias[col];
#pragma unroll
      for (int mt = 0; mt < 4; ++mt) {
        int row0 = m0 + wm + mt * 16 + lg * 4;
        int bb2 = row0 >> 10, nr = row0 & (NN - 1);
        ushort4 o;
        o.x = f2bf(acc[mt][nt][0] + bcol);
        o.y = f2bf(acc[mt][nt][1] + bcol);
        o.z = f2bf(acc[mt][nt][2] + bcol);
        o.w = f2bf(acc[mt][nt][3] + bcol);
        *(ushort4*)(C + ((size_t)(bb2 * NHD + hh) * ASZ + dd) * NN + nr) = o;
      }
    }
  } else {
#pragma unroll
    for (int nt = 0; nt < 4; ++nt) {
      int col = n0 + wn + nt * 16 + lm;
      float bcol = bias[col];
#pragma unroll
      for (int mt = 0; mt < 4; ++mt)
#pragma unroll
        for (int r = 0; r < 4; ++r) {
          int row = m0 + wm + mt * 16 + lg * 4 + r;
          C[(size_t)row * HH + col] = f2bf((acc[mt][nt][r] + bcol) * alpha);
        }
    }
  }
}

// ============ K_attn2: swapped-QK^T MFMA flash attention, KVBLK=128 ============
// 8 waves x 16 q-rows (128 q/block); 8 KV-tiles of 128 tokens; exp2 softmax;
// v_perm P-pack (register-local via 7-bit K-row permutation); reg prefetch; setprio.
__global__ __launch_bounds__(512, 2) void k_attn2(
    const ushort* __restrict__ qg, const ushort* __restrict__ kg, const ushort* __restrict__ vtg,
    const float4* __restrict__ bias4, const int* __restrict__ pp, float* __restrict__ zz) {
  __shared__ ushort Ks[128 * 64];    // [token-slot][d]
  __shared__ ushort Vts[64 * 128];   // [d][token]
  const int rb = blockIdx.y, h = blockIdx.x >> 3, b = blockIdx.x & 7;
  const int n0 = rb * 128;
  const int t = threadIdx.x, w = t >> 6, lane = t & 63, lg = lane >> 4, lm = lane & 15;
  const int qbase = n0 + w * 16;
  const ushort* qrow = qg + (size_t)(b * NN + qbase + lm) * HH + h * ASZ;
  bf16x8 qf[2];
  qf[0] = *(const bf16x8*)(qrow + lg * 8);
  qf[1] = *(const bf16x8*)(qrow + lg * 8 + 32);
  float4 bz = bias4[b * NN + qbase + lm];
  const int cwq = __float_as_int(bz.x);
  float mr = -1e30f, lr = 0.f;   // exp2-domain online softmax state for q = qbase+lm
  f32x4 y[4] = {};
  const ushort* kb = kg + (size_t)(b * NN) * HH + h * ASZ;
  const ushort* vtb = vtg + (size_t)(b * NHD + h) * ASZ * NN;
  // K staging: 512 threads x 2 slots; token rows srow, srow+64
  const int srow = t >> 3, sc = t & 7;
  const int arow = (srow & 35) | ((srow & 4) << 2) | ((srow & 24) >> 1);  // 6-bit perm
  const int kssw = (sc ^ (arow & 7)) * 8;
  // V staging: d rows vd, vd+32; 16 token-chunks per row
  const int vd = t >> 4, vc = t & 15;
  const int vssw = (vc ^ ((vd & 7) << 1)) * 8;
  const ushort* kptr = kb + (size_t)srow * HH + sc * 8;
  const ushort* vptr = vtb + (size_t)vd * NN + vc * 8;
  uint4 ka = *(const uint4*)kptr;
  uint4 kc = *(const uint4*)(kptr + (size_t)64 * HH);
  uint4 va = *(const uint4*)vptr;
  uint4 vb2 = *(const uint4*)(vptr + (size_t)32 * NN);
  for (int tile = 0; tile < 8; ++tile) {
    const int c0 = tile * 128;
    *(uint4*)&Ks[arow * 64 + kssw] = ka;
    *(uint4*)&Ks[(arow + 64) * 64 + kssw] = kc;
    *(uint4*)&Vts[vd * 128 + vssw] = va;
    *(uint4*)&Vts[(vd + 32) * 128 + vssw] = vb2;
    __syncthreads();
    if (tile < 7) {   // prefetch next tile into registers
      kptr += (size_t)128 * HH; vptr += 128;
      ka = *(const uint4*)kptr;
      kc = *(const uint4*)(kptr + (size_t)64 * HH);
      va = *(const uint4*)vptr;
      vb2 = *(const uint4*)(vptr + (size_t)32 * NN);
    }
    f32x4 s[8] = {};
    __builtin_amdgcn_s_setprio(1);
#pragma unroll
    for (int nt = 0; nt < 8; ++nt) {
      int krow = lm + nt * 16, sw = krow & 7;
#pragma unroll
      for (int kt = 0; kt < 2; ++kt) {
        bf16x8 kf = *(bf16x8*)&Ks[krow * 64 + (((lg + kt * 4) ^ sw) * 8)];
        s[nt] = __builtin_amdgcn_mfma_f32_16x16x32_bf16(kf, qf[kt], s[nt], 0, 0, 0);
      }
    }
    __builtin_amdgcn_s_setprio(0);
    // sparse bias: token of s[nt][r] = c0 + (nt>>1)*32 + lg*8 + (nt&1)*4 + r
    if (c0 <= qbase + 17 && qbase <= c0 + 129) {
#pragma unroll
      for (int nt = 0; nt < 8; ++nt) {
        int kb2 = c0 + (nt >> 1) * 32 + lg * 8 + (nt & 1) * 4;
#pragma unroll
        for (int r = 0; r < 4; ++r) {
          int dd = kb2 + r - cwq;
          if (dd >= 0 && dd < 3) s[nt][r] += (dd == 0) ? bz.y : (dd == 1 ? bz.z : bz.w);
        }
      }
    }
    // online softmax (exp2 domain): one chain per 128 tokens
    f32x4 mA, mB;
#pragma unroll
    for (int e = 0; e < 4; ++e) {
      mA[e] = fmaxf(fmaxf(s[0][e], s[1][e]), fmaxf(s[2][e], s[3][e]));
      mB[e] = fmaxf(fmaxf(s[4][e], s[5][e]), fmaxf(s[6][e], s[7][e]));
      mA[e] = fmaxf(mA[e], mB[e]);
    }
    float tm = fmaxf(fmaxf(mA[0], mA[1]), fmaxf(mA[2], mA[3]));
    tm = fmaxf(tm, __shfl_xor(tm, 16));
    tm = fmaxf(tm, __shfl_xor(tm, 32));
    int need = tm > mr;
    if (__any(need)) {
      float mn = fmaxf(mr, tm);
      float f = EXP2F(mr - mn);
      mr = mn;
      lr *= f;
      float fr[4];
#pragma unroll
      for (int r = 0; r < 4; ++r) fr[r] = __shfl(f, lg * 4 + r);
#pragma unroll
      for (int nt = 0; nt < 4; ++nt)
#pragma unroll
        for (int r = 0; r < 4; ++r) y[nt][r] *= fr[r];
    }
    f32x4 sum4 = {0.f, 0.f, 0.f, 0.f};
#pragma unroll
    for (int nt = 0; nt < 8; ++nt)
#pragma unroll
      for (int e = 0; e < 4; ++e) {
        float p = EXP2F(s[nt][e] - mr);
        s[nt][e] = p;
        sum4[e] += p;
      }
    float ts = (sum4[0] + sum4[1]) + (sum4[2] + sum4[3]);
    ts += __shfl_xor(ts, 16);
    ts += __shfl_xor(ts, 32);
    lr += ts;
    // pack P into PV A-frags via v_perm (register-local)
    union { unsigned u[4]; bf16x8 v; } pk[4];
#pragma unroll
    for (int kt = 0; kt < 4; ++kt) {
      pk[kt].u[0] = packbf2(s[2 * kt][0], s[2 * kt][1]);
      pk[kt].u[1] = packbf2(s[2 * kt][2], s[2 * kt][3]);
      pk[kt].u[2] = packbf2(s[2 * kt + 1][0], s[2 * kt + 1][1]);
      pk[kt].u[3] = packbf2(s[2 * kt + 1][2], s[2 * kt + 1][3]);
    }
    __builtin_amdgcn_s_setprio(1);
#pragma unroll
    for (int nt = 0; nt < 4; ++nt) {
      int vrow = lm + nt * 16, sw2 = (vrow & 7) << 1;
#pragma unroll
      for (int kt = 0; kt < 4; ++kt) {
        bf16x8 vf = *(bf16x8*)&Vts[vrow * 128 + (((kt * 4 + lg) ^ sw2) * 8)];
        y[nt] = __builtin_amdgcn_mfma_f32_16x16x32_bf16(pk[kt].v, vf, y[nt], 0, 0, 0);
      }
    }
    __builtin_amdgcn_s_setprio(0);
    __syncthreads();
  }
  // epilogue: weighted row-sums into z1/z2 (y: col lm = d, row lg*4+r = q)
  float invl = 1.f / lr;
  float invq[4], c1v[4], c2v[4];
#pragma unroll
  for (int r = 0; r < 4; ++r) {
    invq[r] = __shfl(invl, lg * 4 + r);
    coefs(pp + b * NN, qbase + lg * 4 + r, c1v[r], c2v[r]);
  }
  float a1[4], a2[4];
#pragma unroll
  for (int nt = 0; nt < 4; ++nt) {
    float u1 = 0.f, u2 = 0.f;
#pragma unroll
    for (int r = 0; r < 4; ++r) {
      float yv = y[nt][r] * invq[r];
      u1 += c1v[r] * yv;
      u2 += c2v[r] * yv;
    }
    u1 += __shfl_xor(u1, 16); u1 += __shfl_xor(u1, 32);
    u2 += __shfl_xor(u2, 16); u2 += __shfl_xor(u2, 32);
    a1[nt] = u1; a2[nt] = u2;
  }
  if (lg == 0) {
#pragma unroll
    for (int nt = 0; nt < 4; ++nt) {
      atomicAdd(&zz[b * HH + h * ASZ + nt * 16 + lm], a1[nt]);
      atomicAdd(&zz[BB * HH + b * HH + h * ASZ + nt * 16 + lm], a2[nt]);
    }
  }
}

// ============ F1: t_s = W_o @ (z_s / sumw) + b_o ============
__global__ void k_f1(const float* __restrict__ Wo, const float* __restrict__ bo,
                     const float* __restrict__ zz, const float* __restrict__ sumw,
                     float* __restrict__ tvec) {
  int b = blockIdx.y;
  int w = threadIdx.x >> 6, lane = threadIdx.x & 63;
  float inv = 1.f / sumw[b];
  const float* z1 = zz + b * HH;
  const float* z2 = zz + BB * HH + b * HH;
  float zr1[12], zr2[12];
#pragma unroll
  for (int m = 0; m < 12; ++m) { zr1[m] = z1[lane + 64 * m] * inv; zr2[m] = z2[lane + 64 * m] * inv; }
  for (int j = 0; j < 8; ++j) {
    int o = blockIdx.x * 32 + w * 8 + j;
    const float* wrow = Wo + (size_t)o * HH;
    float a1 = 0.f, a2 = 0.f;
#pragma unroll
    for (int m = 0; m < 12; ++m) { float wv = wrow[lane + 64 * m]; a1 += wv * zr1[m]; a2 += wv * zr2[m]; }
    for (int mask = 32; mask; mask >>= 1) { a1 += __shfl_xor(a1, mask); a2 += __shfl_xor(a2, mask); }
    if (lane == 0) { tvec[b * HH + o] = a1 + bo[o]; tvec[BB * HH + b * HH + o] = a2 + bo[o]; }
  }
}

// ============ F2: pm = WL @ t1 + WR @ t2 + b_atom ============
__global__ void k_f2(const float* __restrict__ Wa, const float* __restrict__ ba,
                     const float* __restrict__ tvec, float* __restrict__ pm) {
  int b = blockIdx.y;
  int w = threadIdx.x >> 6, lane = threadIdx.x & 63;
  const float* t1 = tvec + b * HH;
  const float* t2 = tvec + BB * HH + b * HH;
  float r1[12], r2[12];
#pragma unroll
  for (int m = 0; m < 12; ++m) { r1[m] = t1[lane + 64 * m]; r2[m] = t2[lane + 64 * m]; }
  for (int j = 0; j < 8; ++j) {
    int o = blockIdx.x * 32 + w * 8 + j;
    const float* wrow = Wa + (size_t)o * (2 * HH);
    float a = 0.f;
#pragma unroll
    for (int m = 0; m < 12; ++m) a += wrow[lane + 64 * m] * r1[m];
#pragma unroll
    for (int m = 0; m < 12; ++m) a += wrow[HH + lane + 64 * m] * r2[m];
    for (int mask = 32; mask; mask >>= 1) a += __shfl_xor(a, mask);
    if (lane == 0) pm[b * HH + o] = a + ba[o];
  }
}

// ============ F3: broadcast pm to (B,N,H) ============
__global__ void k_bcast(const float* __restrict__ pm, float* __restrict__ out) {
  size_t g = (size_t)blockIdx.x * 256 + threadIdx.x;
  int b = (int)(g / ((size_t)NN * HH / 4));
  int hh4 = (int)(g % (HH / 4));
  float4 val = *(const float4*)(pm + b * HH + hh4 * 4);
  *(float4*)(out + g * 4) = val;
}

// ================= launcher =================
extern "C" void kernel_launch(void* const* d_in, const int* in_sizes, int n_in,
                              void* d_out, int out_size, void* d_ws, size_t ws_size,
                              hipStream_t stream) {
  (void)in_sizes; (void)n_in; (void)out_size; (void)ws_size;
  const float* x       = (const float*)d_in[0];
  const float* W_var   = (const float*)d_in[3];
  const float* b_var   = (const float*)d_in[4];
  const float* W_sym   = (const float*)d_in[5];
  const float* b_sym   = (const float*)d_in[6];
  const float* W_score = (const float*)d_in[7];
  const float* b_score = (const float*)d_in[8];
  const float* W_cross = (const float*)d_in[9];
  const float* b_cross = (const float*)d_in[10];
  const float* W_atom  = (const float*)d_in[11];
  const float* b_atom  = (const float*)d_in[12];
  const float* W_q     = (const float*)d_in[13];
  const float* b_q     = (const float*)d_in[14];
  const float* W_k     = (const float*)d_in[15];
  const float* b_k     = (const float*)d_in[16];
  const float* W_v     = (const float*)d_in[17];
  const float* b_v     = (const float*)d_in[18];
  const float* W_o     = (const float*)d_in[19];
  const float* b_o     = (const float*)d_in[20];
  const int*   pp      = (const int*)d_in[21];
  const int*   occ     = (const int*)d_in[24];
  float* out = (float*)d_out;
  char* wsb = (char*)d_ws;
  ushort* qb  = (ushort*)(wsb + OFFB_QB);
  ushort* kbf = (ushort*)(wsb + OFFB_KB);
  ushort* vtb = (ushort*)(wsb + OFFB_VB);
  ushort* xb  = (ushort*)(wsb + OFFB_XB);
  ushort* wqb = (ushort*)(wsb + OFFB_WQB);
  ushort* wkb = (ushort*)(wsb + OFFB_WKB);
  ushort* wvb = (ushort*)(wsb + OFFB_WVB);
  ushort* wvar = (ushort*)(wsb + OFFB_WVAR);
  ushort* wsym = (ushort*)(wsb + OFFB_WSYM);
  ushort* vrows = (ushort*)(wsb + OFFB_VROWS);
  float* sraw = (float*)(wsb + OFFB_SRAW);
  float* diag = (float*)(wsb + OFFB_DIAG);
  float4* bias4 = (float4*)(wsb + OFFB_BIAS4);
  int* plist = (int*)(wsb + OFFB_PLIST);
  int* pcnt  = (int*)(wsb + OFFB_PCNT);
  float* sumw = (float*)(wsb + OFFB_SUMW);
  float* zz   = (float*)(wsb + OFFB_ZZ);
  float* tv   = (float*)(wsb + OFFB_TV);
  float* pm   = (float*)(wsb + OFFB_PM);

  k_pred<<<BB, 64, 0, stream>>>(pp, plist, pcnt, sumw, sraw, diag, zz);
  // f32->bf16 (x + 5 weights) fused with occurrence-pair scores
  k_cvtall<<<NCVT + BB * MM / 4, 256, 0, stream>>>(
      x, W_q, W_k, W_v, W_var, W_sym, xb, wqb, wkb, wvb, wvar, wsym,
      occ, W_cross, b_cross, diag);
  // gather var_in rows (bf16, compact)
  k_gather<<<dim3(PRMAX / 4, BB), 256, 0, stream>>>(xb, pp, plist, pcnt, vrows);
  // score path (bf16 MFMA, register-prefetched, 64-row tiles over 1536 cols)
  k_score_mf<<<dim3(12, 6, BB), 256, 0, stream>>>(xb, vrows, plist, pcnt, wvar, wsym,
                                                  b_var, b_sym, W_score, sraw);
  k_bias<<<BB * NN / 256, 256, 0, stream>>>(pp, sraw, diag, b_score, bias4);
  // fused QKV MFMA GEMM (bf16, register-prefetched); V written transposed
  k_gemm_bf<<<dim3(64, 6, 3), 256, 0, stream>>>(xb, wqb, wkb, wvb, b_q, b_k, b_v, qb, kbf, vtb);
  // MFMA flash attention (128 q-rows/block, 8 waves, KVBLK=128); grid x=(h,b) for XCD L2 reuse
  k_attn2<<<dim3(NHD * BB, NN / 128), 512, 0, stream>>>(qb, kbf, vtb, bias4, pp, zz);
  k_f1<<<dim3(24, BB), 256, 0, stream>>>(W_o, b_o, zz, sumw, tv);
  k_f2<<<dim3(24, BB), 256, 0, stream>>>(W_atom, b_atom, tv, pm);
  k_bcast<<<BB * NN * HH / 1024, 256, 0, stream>>>(pm, out);
}

// Round 12
// 157.857 us; speedup vs baseline: 8.9599x; 1.0279x over previous
//
#include <hip/hip_runtime.h>
#include <hip/hip_bf16.h>

// ================= problem constants =================
#define BB 8
#define NN 1024
#define HH 768
#define NHD 12
#define ASZ 64
#define MM 256
#define QSCALE 0.125f   // AS^-0.5
#define NSLOPE 0.02f
#define LOG2E 1.44269504f
#define PRMAX 384       // padded predicate rows per batch

typedef __attribute__((ext_vector_type(8))) short bf16x8;
typedef __attribute__((ext_vector_type(4))) float f32x4;

#define EXP2F(x) __builtin_amdgcn_exp2f(x)
#define RCPF(x)  __builtin_amdgcn_rcpf(x)

// ============ workspace layout (byte offsets, all 16B-aligned) ============
#define OFFB_QB    ((size_t)0)            // 8*1024*768 bf16
#define OFFB_KB    ((size_t)12582912)
#define OFFB_VB    ((size_t)25165824)     // V^T: [b][h][d][n] bf16
#define OFFB_XB    ((size_t)37748736)     // x in bf16
#define OFFB_WQB   ((size_t)50331648)     // 768*768 bf16
#define OFFB_WKB   ((size_t)51511296)
#define OFFB_WVB   ((size_t)52690944)
#define OFFB_WVAR  ((size_t)53870592)     // W_var bf16
#define OFFB_WSYM  ((size_t)55050240)     // W_sym bf16
#define OFFB_SRAW  ((size_t)56229888)     // 8192 f32
#define OFFB_DIAG  ((size_t)56262656)     // 8192 f32
#define OFFB_BIAS4 ((size_t)56295424)     // 8192 float4
#define OFFB_PLIST ((size_t)56426496)     // 8192 i32
#define OFFB_PCNT  ((size_t)56459264)
#define OFFB_SUMW  ((size_t)56459296)
#define OFFB_ZZ    ((size_t)56459328)     // 2*8*768 f32
#define OFFB_TV    ((size_t)56508480)
#define OFFB_PM    ((size_t)56557632)
#define OFFB_VROWS ((size_t)56582208)     // 8*384*768 bf16 gathered var rows

__device__ __forceinline__ float lrelu(float v) { return v >= 0.f ? v : NSLOPE * v; }

__device__ __forceinline__ ushort f2bf(float f) {  // round-half-up f32->bf16 (2 ops)
  return (ushort)((__float_as_uint(f) + 0x8000u) >> 16);
}
__device__ __forceinline__ float bf2f(ushort u) {
  union { unsigned u; float f; } v; v.u = (unsigned)u << 16;
  return v.f;
}
__device__ __forceinline__ unsigned packbf2(float lo, float hi) {  // (bf(hi)<<16)|bf(lo)
  unsigned a = __float_as_uint(hi) + 0x8000u;
  unsigned b = __float_as_uint(lo) + 0x8000u;
  return __builtin_amdgcn_perm(a, b, 0x07060302u);
}
__device__ __forceinline__ float fast_tanh(float x) {  // exp2-domain, saturates to +-1
  float e = EXP2F(x * (2.f * LOG2E));
  return 1.f - 2.f * RCPF(e + 1.f);
}

// weights for the final weighted row-sums of y (derived from pm algebra).
__device__ __forceinline__ void coefs(const int* ppb, int j, float& c1, float& c2) {
  auto pred = [&](int tt) { return tt >= 0 && tt < NN && ppb[tt] == 1; };
  auto single = [&](int tt) { return tt == 0 || (tt >= 2 && ppb[tt - 2] == 1); };
  auto wgt = [&](int tt) {
    if (!pred(tt)) return 0.f;
    bool tri = (tt >= 1) && (tt <= 1 || !single(tt));
    return tri ? 3.f : 2.f;
  };
  float a = 0.f;
  if (pred(j + 1)) a += wgt(j + 1) * (single(j + 1) ? 0.f : 0.5f);
  if (j >= 1 && pred(j - 1)) a += wgt(j - 1) * (single(j - 1) ? 1.f : 0.5f);
  c1 = a;
  c2 = wgt(j);
}

// ============ K_pred: compact predicate list + sum of weights + ws zeroing ============
__global__ void k_pred(const int* __restrict__ pp, int* __restrict__ plist,
                       int* __restrict__ pcnt, float* __restrict__ sumw,
                       float* __restrict__ sraw, float* __restrict__ diag,
                       float* __restrict__ zz) {
  int b = blockIdx.x;
  int lane = threadIdx.x;  // blockDim 64
  const int* ppb = pp + b * NN;
  int base = 0;
  float wacc = 0.f;
  for (int c = 0; c < NN; c += 64) {
    int i = c + lane;
    bool isp = ppb[i] == 1;
    unsigned long long mask = __ballot(isp);
    if (isp) {
      int pos = base + __popcll(mask & ((1ull << lane) - 1ull));
      plist[b * NN + pos] = i;
      bool sing = (i == 0) || (i >= 2 && ppb[i - 2] == 1);
      bool tri = (i >= 1) && (i <= 1 || !sing);
      wacc += tri ? 3.f : 2.f;
    }
    base += __popcll(mask);
  }
  for (int off = 32; off; off >>= 1) wacc += __shfl_xor(wacc, off);
  if (lane == 0) { pcnt[b] = base; sumw[b] = wacc; }
  for (int c = lane; c < NN; c += 64) { sraw[b * NN + c] = 0.f; diag[b * NN + c] = 0.f; }
  for (int c = lane; c < HH; c += 64) {
    zz[b * HH + c] = 0.f;
    zz[BB * HH + b * HH + c] = 0.f;
  }
}

// ============ K_cvtall: x + 5 weights f32->bf16, plus cross scores ============
#define NXQ (BB * NN * HH / 4)      // 1572864
#define WQ  (HH * HH / 4)           // 147456
#define NCVT ((NXQ + 5 * WQ) / 256) // 9024
__global__ void k_cvtall(const float* __restrict__ x,
                         const float* __restrict__ s1, const float* __restrict__ s2,
                         const float* __restrict__ s3, const float* __restrict__ s4,
                         const float* __restrict__ s5,
                         ushort* __restrict__ dx,
                         ushort* __restrict__ d1, ushort* __restrict__ d2,
                         ushort* __restrict__ d3, ushort* __restrict__ d4,
                         ushort* __restrict__ d5,
                         const int* __restrict__ occ, const float* __restrict__ Wc,
                         const float* __restrict__ bc, float* __restrict__ diag) {
  if (blockIdx.x < NCVT) {
    int idx = blockIdx.x * 256 + threadIdx.x;
    const float* src; ushort* dst; int off;
    if (idx < NXQ) { src = x; dst = dx; off = idx; }
    else {
      int r = idx - NXQ;
      int z = r / WQ;
      off = r - z * WQ;
      src = z == 0 ? s1 : z == 1 ? s2 : z == 2 ? s3 : z == 3 ? s4 : s5;
      dst = z == 0 ? d1 : z == 1 ? d2 : z == 2 ? d3 : z == 3 ? d4 : d5;
    }
    float4 v = ((const float4*)src)[off];
    ushort4 o;
    o.x = f2bf(v.x); o.y = f2bf(v.y); o.z = f2bf(v.z); o.w = f2bf(v.w);
    ((ushort4*)dst)[off] = o;
  } else {
    int g = (blockIdx.x - NCVT) * 4 + (threadIdx.x >> 6);
    int lane = threadIdx.x & 63;
    int b = g >> 8, m = g & (MM - 1);
    int o0 = occ[(b * MM + m) * 2 + 0];
    int o1 = occ[(b * MM + m) * 2 + 1];
    const float* x0 = x + (size_t)(b * NN + o0) * HH;
    const float* x1 = x + (size_t)(b * NN + o1) * HH;
    float acc = 0.f;
    for (int d = lane; d < HH; d += 64) acc += 0.5f * (x0[d] + x1[d]) * Wc[d];
    for (int off = 32; off; off >>= 1) acc += __shfl_xor(acc, off);
    if (lane == 0) {
      float sc = lrelu(acc + bc[0]);
      float sq = sc * sc;
      diag[b * NN + o0] = sq;
      diag[b * NN + o1] = sq;
    }
  }
}

// ============ K_gather: compact var_in rows (bf16) for the score GEMM ============
__global__ void k_gather(const ushort* __restrict__ xb, const int* __restrict__ pp,
                         const int* __restrict__ plist, const int* __restrict__ pcnt,
                         ushort* __restrict__ vrows) {
  int b = blockIdx.y;
  int j = blockIdx.x * 4 + (threadIdx.x >> 6);
  int lane = threadIdx.x & 63;
  if (j >= pcnt[b]) return;
  int i = plist[b * NN + j];
  bool sing = (i == 0) || (i >= 2 && pp[b * NN + i - 2] == 1);
  float wa = sing ? 0.f : 0.5f, wb = sing ? 1.f : 0.5f;
  const ushort* rp = xb + (size_t)(b * NN + ((i - 1) & (NN - 1))) * HH;
  const ushort* rn = xb + (size_t)(b * NN + ((i + 1) & (NN - 1))) * HH;
  ushort* dst = vrows + ((size_t)b * PRMAX + j) * HH;
#pragma unroll
  for (int it = 0; it < 3; ++it) {
    int d4 = lane + it * 64;
    ushort4 p4 = ((const ushort4*)rp)[d4];
    ushort4 n4 = ((const ushort4*)rn)[d4];
    ushort4 o;
    o.x = f2bf(wa * bf2f(p4.x) + wb * bf2f(n4.x));
    o.y = f2bf(wa * bf2f(p4.y) + wb * bf2f(n4.y));
    o.z = f2bf(wa * bf2f(p4.z) + wb * bf2f(n4.z));
    o.w = f2bf(wa * bf2f(p4.w) + wb * bf2f(n4.w));
    ((ushort4*)dst)[d4] = o;
  }
}

// ============ K_bias: per-row sparse bias window (log2e-scaled for exp2 softmax) ============
__global__ void k_bias(const int* __restrict__ pp, const float* __restrict__ s_raw,
                       const float* __restrict__ diag, const float* __restrict__ b_score,
                       float4* __restrict__ bias4) {
  int g = blockIdx.x * 256 + threadIdx.x;
  int b = g >> 10, r = g & (NN - 1);
  const int* ppb = pp + b * NN;
  int i = -1;
  if (ppb[r] == 1) i = r;
  else if (r + 1 < NN && ppb[r + 1] == 1) i = r + 1;
  else if (r >= 1 && ppb[r - 1] == 1) i = r - 1;
  float v0 = 0.f, v1 = 0.f, v2 = 0.f; int cw = r;
  if (i >= 1 && i + 1 < NN) {
    float s = lrelu(s_raw[b * NN + i] + b_score[0]);
    float s2 = s * s;
    cw = i - 1;
    if (i == r) { v0 = 0.2f * s; v1 = 1.6f * s2; v2 = 0.2f * s; }
    else       { v0 = 0.8f * s2; v1 = 0.2f * s; v2 = 0.8f * s2; }
  }
  int slot = r - cw;
  float d = diag[g];
  if (slot == 0) v0 += d; else if (slot == 1) v1 += d; else v2 += d;
  bias4[g] = make_float4(__int_as_float(cw), v0 * LOG2E, v1 * LOG2E, v2 * LOG2E);
}

// ============ K_mats: fused {QKV GEMM (1152 blocks)} + {score GEMM (576 blocks)} ============
// Independent workloads co-scheduled in one dispatch to overlap latency.
#define GEMM_BLKS 1152
__global__ __launch_bounds__(256, 2) void k_mats(
    const ushort* __restrict__ X, const ushort* __restrict__ vrows,
    const int* __restrict__ plist, const int* __restrict__ pcnt,
    const ushort* __restrict__ Wvar, const ushort* __restrict__ Wsym,
    const float* __restrict__ bvar, const float* __restrict__ bsym,
    const float* __restrict__ wscore, float* __restrict__ s_raw,
    const ushort* __restrict__ W0, const ushort* __restrict__ W1, const ushort* __restrict__ W2,
    const float* __restrict__ b0, const float* __restrict__ b1, const float* __restrict__ b2,
    ushort* __restrict__ C0, ushort* __restrict__ C1, ushort* __restrict__ C2) {
  __shared__ ushort Sm[16384];   // 32 KB carve
  __shared__ int pl[64];
  __shared__ float red[64];
  const int t = threadIdx.x;
  const int w = t >> 6, lane = t & 63, lg = lane >> 4, lm = lane & 15;
  const int r0 = t >> 3, c = t & 7;
  const int ssw = (c ^ (r0 & 7)) * 8;
  if (blockIdx.x < GEMM_BLKS) {
    // ---------------- QKV GEMM path ----------------
    const int z = blockIdx.x / 384;
    const int r = blockIdx.x % 384;
    const int m0 = (r & 63) * 128, n0 = (r >> 6) * 128;
    const ushort* W = z == 0 ? W0 : (z == 1 ? W1 : W2);
    const float* bias = z == 0 ? b0 : (z == 1 ? b1 : b2);
    ushort* C = z == 0 ? C0 : (z == 1 ? C1 : C2);
    const float alpha = z == 0 ? QSCALE * LOG2E : 1.f;
    ushort* As = Sm;
    ushort* Bs = Sm + 8192;
    const int wm = (w >> 1) * 64, wn = (w & 1) * 64;
    const ushort* Xp = X + (size_t)(m0 + r0) * HH + c * 8;
    const ushort* Wp = W + (size_t)(n0 + r0) * HH + c * 8;
    uint4 xa0 = *(const uint4*)Xp;
    uint4 xa1 = *(const uint4*)(Xp + (size_t)32 * HH);
    uint4 xa2 = *(const uint4*)(Xp + (size_t)64 * HH);
    uint4 xa3 = *(const uint4*)(Xp + (size_t)96 * HH);
    uint4 wb0 = *(const uint4*)Wp;
    uint4 wb1 = *(const uint4*)(Wp + (size_t)32 * HH);
    uint4 wb2 = *(const uint4*)(Wp + (size_t)64 * HH);
    uint4 wb3 = *(const uint4*)(Wp + (size_t)96 * HH);
    f32x4 acc[4][4] = {};
    for (int k0 = 0; k0 < HH; k0 += 64) {
      if (k0) __syncthreads();
      *(uint4*)&As[r0 * 64 + ssw] = xa0;
      *(uint4*)&As[(r0 + 32) * 64 + ssw] = xa1;
      *(uint4*)&As[(r0 + 64) * 64 + ssw] = xa2;
      *(uint4*)&As[(r0 + 96) * 64 + ssw] = xa3;
      *(uint4*)&Bs[r0 * 64 + ssw] = wb0;
      *(uint4*)&Bs[(r0 + 32) * 64 + ssw] = wb1;
      *(uint4*)&Bs[(r0 + 64) * 64 + ssw] = wb2;
      *(uint4*)&Bs[(r0 + 96) * 64 + ssw] = wb3;
      __syncthreads();
      if (k0 + 64 < HH) {
        Xp += 64; Wp += 64;
        xa0 = *(const uint4*)Xp;
        xa1 = *(const uint4*)(Xp + (size_t)32 * HH);
        xa2 = *(const uint4*)(Xp + (size_t)64 * HH);
        xa3 = *(const uint4*)(Xp + (size_t)96 * HH);
        wb0 = *(const uint4*)Wp;
        wb1 = *(const uint4*)(Wp + (size_t)32 * HH);
        wb2 = *(const uint4*)(Wp + (size_t)64 * HH);
        wb3 = *(const uint4*)(Wp + (size_t)96 * HH);
      }
      bf16x8 af[4][2], bfr[4][2];
#pragma unroll
      for (int mt = 0; mt < 4; ++mt)
#pragma unroll
        for (int kt = 0; kt < 2; ++kt) {
          int row = wm + mt * 16 + lm, ch = lg + kt * 4;
          af[mt][kt] = *(bf16x8*)&As[row * 64 + ((ch ^ (row & 7)) * 8)];
        }
#pragma unroll
      for (int nt = 0; nt < 4; ++nt)
#pragma unroll
        for (int kt = 0; kt < 2; ++kt) {
          int row = wn + nt * 16 + lm, ch = lg + kt * 4;
          bfr[nt][kt] = *(bf16x8*)&Bs[row * 64 + ((ch ^ (row & 7)) * 8)];
        }
#pragma unroll
      for (int mt = 0; mt < 4; ++mt)
#pragma unroll
        for (int nt = 0; nt < 4; ++nt)
#pragma unroll
          for (int kt = 0; kt < 2; ++kt)
            acc[mt][nt] = __builtin_amdgcn_mfma_f32_16x16x32_bf16(af[mt][kt], bfr[nt][kt], acc[mt][nt], 0, 0, 0);
    }
    if (z == 2) {
#pragma unroll
      for (int nt = 0; nt < 4; ++nt) {
        int col = n0 + wn + nt * 16 + lm;
        int hh = col >> 6, dd = col & 63;
        float bcol = bias[col];
#pragma unroll
        for (int mt = 0; mt < 4; ++mt) {
          int row0 = m0 + wm + mt * 16 + lg * 4;
          int bb2 = row0 >> 10, nr = row0 & (NN - 1);
          ushort4 o;
          o.x = f2bf(acc[mt][nt][0] + bcol);
          o.y = f2bf(acc[mt][nt][1] + bcol);
          o.z = f2bf(acc[mt][nt][2] + bcol);
          o.w = f2bf(acc[mt][nt][3] + bcol);
          *(ushort4*)(C + ((size_t)(bb2 * NHD + hh) * ASZ + dd) * NN + nr) = o;
        }
      }
    } else {
#pragma unroll
      for (int nt = 0; nt < 4; ++nt) {
        int col = n0 + wn + nt * 16 + lm;
        float bcol = bias[col];
#pragma unroll
        for (int mt = 0; mt < 4; ++mt)
#pragma unroll
          for (int rr = 0; rr < 4; ++rr) {
            int row = m0 + wm + mt * 16 + lg * 4 + rr;
            C[(size_t)row * HH + col] = f2bf((acc[mt][nt][rr] + bcol) * alpha);
          }
      }
    }
  } else {
    // ---------------- score GEMM path ----------------
    const int bid2 = blockIdx.x - GEMM_BLKS;
    const int b = bid2 / 72;
    const int rem = bid2 % 72;
    const int j0 = (rem / 12) * 64;
    const int n0g = (rem % 12) * 128;
    const int cnt = pcnt[b];
    if (j0 >= cnt) return;
    const bool symh = n0g >= HH;
    const int n0 = symh ? n0g - HH : n0g;
    const ushort* W = symh ? Wsym : Wvar;
    const float* bias = symh ? bsym : bvar;
    ushort* As = Sm;           // 64*64
    ushort* Bs = Sm + 4096;    // 128*64
    const int wm = (w >> 1) * 32, wn = (w & 1) * 64;
    if (t < 64) {
      int j = j0 + t;
      pl[t] = (j < cnt) ? plist[b * NN + j] : 2;
      red[t] = 0.f;
    }
    __syncthreads();
    const ushort* ap0; const ushort* ap1;
    if (symh) {
      const ushort* xbb = X + (size_t)b * NN * HH;
      ap0 = xbb + (size_t)pl[r0] * HH + c * 8;
      ap1 = xbb + (size_t)pl[r0 + 32] * HH + c * 8;
    } else {
      const ushort* vrb = vrows + ((size_t)b * PRMAX + j0) * HH;
      ap0 = vrb + (size_t)r0 * HH + c * 8;
      ap1 = vrb + (size_t)(r0 + 32) * HH + c * 8;
    }
    const ushort* bp = W + (size_t)(n0 + r0) * HH + c * 8;
    uint4 ar0 = *(const uint4*)ap0;
    uint4 ar1 = *(const uint4*)ap1;
    uint4 br0 = *(const uint4*)bp;
    uint4 br1 = *(const uint4*)(bp + (size_t)32 * HH);
    uint4 br2 = *(const uint4*)(bp + (size_t)64 * HH);
    uint4 br3 = *(const uint4*)(bp + (size_t)96 * HH);
    f32x4 acc[2][4] = {};
    for (int k0 = 0; k0 < HH; k0 += 64) {
      if (k0) __syncthreads();
      *(uint4*)&As[r0 * 64 + ssw] = ar0;
      *(uint4*)&As[(r0 + 32) * 64 + ssw] = ar1;
      *(uint4*)&Bs[r0 * 64 + ssw] = br0;
      *(uint4*)&Bs[(r0 + 32) * 64 + ssw] = br1;
      *(uint4*)&Bs[(r0 + 64) * 64 + ssw] = br2;
      *(uint4*)&Bs[(r0 + 96) * 64 + ssw] = br3;
      __syncthreads();
      if (k0 + 64 < HH) {
        ap0 += 64; ap1 += 64; bp += 64;
        ar0 = *(const uint4*)ap0;
        ar1 = *(const uint4*)ap1;
        br0 = *(const uint4*)bp;
        br1 = *(const uint4*)(bp + (size_t)32 * HH);
        br2 = *(const uint4*)(bp + (size_t)64 * HH);
        br3 = *(const uint4*)(bp + (size_t)96 * HH);
      }
      bf16x8 af[2][2], bfr[4][2];
#pragma unroll
      for (int mt = 0; mt < 2; ++mt)
#pragma unroll
        for (int kt = 0; kt < 2; ++kt) {
          int row = wm + mt * 16 + lm, ch = lg + kt * 4;
          af[mt][kt] = *(bf16x8*)&As[row * 64 + ((ch ^ (row & 7)) * 8)];
        }
#pragma unroll
      for (int nt = 0; nt < 4; ++nt)
#pragma unroll
        for (int kt = 0; kt < 2; ++kt) {
          int row = wn + nt * 16 + lm, ch = lg + kt * 4;
          bfr[nt][kt] = *(bf16x8*)&Bs[row * 64 + ((ch ^ (row & 7)) * 8)];
        }
#pragma unroll
      for (int mt = 0; mt < 2; ++mt)
#pragma unroll
        for (int nt = 0; nt < 4; ++nt)
#pragma unroll
          for (int kt = 0; kt < 2; ++kt)
            acc[mt][nt] = __builtin_amdgcn_mfma_f32_16x16x32_bf16(af[mt][kt], bfr[nt][kt], acc[mt][nt], 0, 0, 0);
    }
    float bcol[4], wcol[4];
#pragma unroll
    for (int nt = 0; nt < 4; ++nt) {
      int cl = wn + nt * 16 + lm;
      bcol[nt] = bias[n0 + cl];
      wcol[nt] = wscore[n0g + cl];
    }
#pragma unroll
    for (int mt = 0; mt < 2; ++mt)
#pragma unroll
      for (int rr = 0; rr < 4; ++rr) {
        float p = 0.f;
#pragma unroll
        for (int nt = 0; nt < 4; ++nt)
          p += fast_tanh(acc[mt][nt][rr] + bcol[nt]) * wcol[nt];
        p += __shfl_xor(p, 1); p += __shfl_xor(p, 2);
        p += __shfl_xor(p, 4); p += __shfl_xor(p, 8);
        if (lm == 0) atomicAdd(&red[wm + mt * 16 + lg * 4 + rr], p);
      }
    __syncthreads();
    if (t < 64) {
      int j2 = j0 + t;
      if (j2 < cnt) atomicAdd(&s_raw[b * NN + pl[t]], red[t]);
    }
  }
}

// ============ K_attn2: swapped-QK^T MFMA flash attention, 256-thread blocks ============
// 4 waves x 16 q-rows (64 q/block); KVBLK=64; exp2 softmax; v_perm P-pack
// (register-local via 6-bit K-row permutation); reg prefetch; setprio.
__global__ __launch_bounds__(256, 4) void k_attn2(
    const ushort* __restrict__ qg, const ushort* __restrict__ kg, const ushort* __restrict__ vtg,
    const float4* __restrict__ bias4, const int* __restrict__ pp, float* __restrict__ zz) {
  __shared__ ushort Ks[64 * 64];
  __shared__ ushort Vts[64 * 64];
  const int rb = blockIdx.y, h = blockIdx.x >> 3, b = blockIdx.x & 7;
  const int n0 = rb * 64;
  const int t = threadIdx.x, w = t >> 6, lane = t & 63, lg = lane >> 4, lm = lane & 15;
  const int qbase = n0 + w * 16;
  const ushort* qrow = qg + (size_t)(b * NN + qbase + lm) * HH + h * ASZ;
  bf16x8 qf[2];
  qf[0] = *(const bf16x8*)(qrow + lg * 8);
  qf[1] = *(const bf16x8*)(qrow + lg * 8 + 32);
  float4 bz = bias4[b * NN + qbase + lm];
  const int cwq = __float_as_int(bz.x);
  float mr = -1e30f, lr = 0.f;
  f32x4 y[4] = {};
  const ushort* kb = kg + (size_t)(b * NN) * HH + h * ASZ;
  const ushort* vtb = vtg + (size_t)(b * NHD + h) * ASZ * NN;
  // staging: 256 threads -> rows srow, srow+32 for both K (tokens) and V^T (d)
  const int srow = t >> 3, sc = t & 7;
  const int arow = (srow & 35) | ((srow & 4) << 2) | ((srow & 24) >> 1);  // 6-bit perm (bit5 pass)
  const int kssw = (sc ^ (arow & 7)) * 8;
  const int vssw = (sc ^ (srow & 7)) * 8;
  const ushort* kptr = kb + (size_t)srow * HH + sc * 8;
  const ushort* vptr = vtb + (size_t)srow * NN + sc * 8;
  uint4 ka = *(const uint4*)kptr;
  uint4 kc = *(const uint4*)(kptr + (size_t)32 * HH);
  uint4 va = *(const uint4*)vptr;
  uint4 vb2 = *(const uint4*)(vptr + (size_t)32 * NN);
  for (int tile = 0; tile < 16; ++tile) {
    const int c0 = tile * 64;
    *(uint4*)&Ks[arow * 64 + kssw] = ka;
    *(uint4*)&Ks[(arow + 32) * 64 + kssw] = kc;
    *(uint4*)&Vts[srow * 64 + vssw] = va;
    *(uint4*)&Vts[(srow + 32) * 64 + vssw] = vb2;
    __syncthreads();
    if (tile < 15) {   // prefetch next tile into registers
      kptr += (size_t)64 * HH; vptr += 64;
      ka = *(const uint4*)kptr;
      kc = *(const uint4*)(kptr + (size_t)32 * HH);
      va = *(const uint4*)vptr;
      vb2 = *(const uint4*)(vptr + (size_t)32 * NN);
    }
    f32x4 s[4] = {};
    __builtin_amdgcn_s_setprio(1);
#pragma unroll
    for (int nt = 0; nt < 4; ++nt) {
      int krow = lm + nt * 16, sw = krow & 7;
#pragma unroll
      for (int kt = 0; kt < 2; ++kt) {
        bf16x8 kf = *(bf16x8*)&Ks[krow * 64 + (((lg + kt * 4) ^ sw) * 8)];
        s[nt] = __builtin_amdgcn_mfma_f32_16x16x32_bf16(kf, qf[kt], s[nt], 0, 0, 0);
      }
    }
    __builtin_amdgcn_s_setprio(0);
    // sparse bias: token of s[nt][r] = c0 + (nt>>1)*32 + lg*8 + (nt&1)*4 + r
    if (c0 <= qbase + 17 && qbase <= c0 + 65) {
#pragma unroll
      for (int nt = 0; nt < 4; ++nt) {
        int kb2 = c0 + (nt >> 1) * 32 + lg * 8 + (nt & 1) * 4;
#pragma unroll
        for (int r = 0; r < 4; ++r) {
          int dd = kb2 + r - cwq;
          if (dd >= 0 && dd < 3) s[nt][r] += (dd == 0) ? bz.y : (dd == 1 ? bz.z : bz.w);
        }
      }
    }
    // online softmax (exp2 domain): row lane-local + 2 shfl
    f32x4 m4;
#pragma unroll
    for (int e = 0; e < 4; ++e)
      m4[e] = fmaxf(fmaxf(s[0][e], s[1][e]), fmaxf(s[2][e], s[3][e]));
    float tm = fmaxf(fmaxf(m4[0], m4[1]), fmaxf(m4[2], m4[3]));
    tm = fmaxf(tm, __shfl_xor(tm, 16));
    tm = fmaxf(tm, __shfl_xor(tm, 32));
    int need = tm > mr;
    if (__any(need)) {
      float mn = fmaxf(mr, tm);
      float f = EXP2F(mr - mn);
      mr = mn;
      lr *= f;
      float fr[4];
#pragma unroll
      for (int r = 0; r < 4; ++r) fr[r] = __shfl(f, lg * 4 + r);
#pragma unroll
      for (int nt = 0; nt < 4; ++nt)
#pragma unroll
        for (int r = 0; r < 4; ++r) y[nt][r] *= fr[r];
    }
    f32x4 sum4 = {0.f, 0.f, 0.f, 0.f};
#pragma unroll
    for (int nt = 0; nt < 4; ++nt)
#pragma unroll
      for (int e = 0; e < 4; ++e) {
        float p = EXP2F(s[nt][e] - mr);
        s[nt][e] = p;
        sum4[e] += p;
      }
    float ts = (sum4[0] + sum4[1]) + (sum4[2] + sum4[3]);
    ts += __shfl_xor(ts, 16);
    ts += __shfl_xor(ts, 32);
    lr += ts;
    // pack P into PV A-frags via v_perm (register-local)
    union { unsigned u[4]; bf16x8 v; } pk[2];
#pragma unroll
    for (int kt = 0; kt < 2; ++kt) {
      pk[kt].u[0] = packbf2(s[2 * kt][0], s[2 * kt][1]);
      pk[kt].u[1] = packbf2(s[2 * kt][2], s[2 * kt][3]);
      pk[kt].u[2] = packbf2(s[2 * kt + 1][0], s[2 * kt + 1][1]);
      pk[kt].u[3] = packbf2(s[2 * kt + 1][2], s[2 * kt + 1][3]);
    }
    __builtin_amdgcn_s_setprio(1);
#pragma unroll
    for (int nt = 0; nt < 4; ++nt) {
      int vrow = lm + nt * 16, sw = vrow & 7;
#pragma unroll
      for (int kt = 0; kt < 2; ++kt) {
        bf16x8 vf = *(bf16x8*)&Vts[vrow * 64 + (((lg + kt * 4) ^ sw) * 8)];
        y[nt] = __builtin_amdgcn_mfma_f32_16x16x32_bf16(pk[kt].v, vf, y[nt], 0, 0, 0);
      }
    }
    __builtin_amdgcn_s_setprio(0);
    __syncthreads();
  }
  // epilogue: weighted row-sums into z1/z2 (y: col lm = d, row lg*4+r = q)
  float invl = 1.f / lr;
  float invq[4], c1v[4], c2v[4];
#pragma unroll
  for (int r = 0; r < 4; ++r) {
    invq[r] = __shfl(invl, lg * 4 + r);
    coefs(pp + b * NN, qbase + lg * 4 + r, c1v[r], c2v[r]);
  }
  float a1[4], a2[4];
#pragma unroll
  for (int nt = 0; nt < 4; ++nt) {
    float u1 = 0.f, u2 = 0.f;
#pragma unroll
    for (int r = 0; r < 4; ++r) {
      float yv = y[nt][r] * invq[r];
      u1 += c1v[r] * yv;
      u2 += c2v[r] * yv;
    }
    u1 += __shfl_xor(u1, 16); u1 += __shfl_xor(u1, 32);
    u2 += __shfl_xor(u2, 16); u2 += __shfl_xor(u2, 32);
    a1[nt] = u1; a2[nt] = u2;
  }
  if (lg == 0) {
#pragma unroll
    for (int nt = 0; nt < 4; ++nt) {
      atomicAdd(&zz[b * HH + h * ASZ + nt * 16 + lm], a1[nt]);
      atomicAdd(&zz[BB * HH + b * HH + h * ASZ + nt * 16 + lm], a2[nt]);
    }
  }
}

// ============ F1: t_s = W_o @ (z_s / sumw) + b_o ============
__global__ void k_f1(const float* __restrict__ Wo, const float* __restrict__ bo,
                     const float* __restrict__ zz, const float* __restrict__ sumw,
                     float* __restrict__ tvec) {
  int b = blockIdx.y;
  int w = threadIdx.x >> 6, lane = threadIdx.x & 63;
  float inv = 1.f / sumw[b];
  const float* z1 = zz + b * HH;
  const float* z2 = zz + BB * HH + b * HH;
  float zr1[12], zr2[12];
#pragma unroll
  for (int m = 0; m < 12; ++m) { zr1[m] = z1[lane + 64 * m] * inv; zr2[m] = z2[lane + 64 * m] * inv; }
  for (int j = 0; j < 8; ++j) {
    int o = blockIdx.x * 32 + w * 8 + j;
    const float* wrow = Wo + (size_t)o * HH;
    float a1 = 0.f, a2 = 0.f;
#pragma unroll
    for (int m = 0; m < 12; ++m) { float wv = wrow[lane + 64 * m]; a1 += wv * zr1[m]; a2 += wv * zr2[m]; }
    for (int mask = 32; mask; mask >>= 1) { a1 += __shfl_xor(a1, mask); a2 += __shfl_xor(a2, mask); }
    if (lane == 0) { tvec[b * HH + o] = a1 + bo[o]; tvec[BB * HH + b * HH + o] = a2 + bo[o]; }
  }
}

// ============ F2: pm = WL @ t1 + WR @ t2 + b_atom ============
__global__ void k_f2(const float* __restrict__ Wa, const float* __restrict__ ba,
                     const float* __restrict__ tvec, float* __restrict__ pm) {
  int b = blockIdx.y;
  int w = threadIdx.x >> 6, lane = threadIdx.x & 63;
  const float* t1 = tvec + b * HH;
  const float* t2 = tvec + BB * HH + b * HH;
  float r1[12], r2[12];
#pragma unroll
  for (int m = 0; m < 12; ++m) { r1[m] = t1[lane + 64 * m]; r2[m] = t2[lane + 64 * m]; }
  for (int j = 0; j < 8; ++j) {
    int o = blockIdx.x * 32 + w * 8 + j;
    const float* wrow = Wa + (size_t)o * (2 * HH);
    float a = 0.f;
#pragma unroll
    for (int m = 0; m < 12; ++m) a += wrow[lane + 64 * m] * r1[m];
#pragma unroll
    for (int m = 0; m < 12; ++m) a += wrow[HH + lane + 64 * m] * r2[m];
    for (int mask = 32; mask; mask >>= 1) a += __shfl_xor(a, mask);
    if (lane == 0) pm[b * HH + o] = a + ba[o];
  }
}

// ============ F3: broadcast pm to (B,N,H) ============
__global__ void k_bcast(const float* __restrict__ pm, float* __restrict__ out) {
  size_t g = (size_t)blockIdx.x * 256 + threadIdx.x;
  int b = (int)(g / ((size_t)NN * HH / 4));
  int hh4 = (int)(g % (HH / 4));
  float4 val = *(const float4*)(pm + b * HH + hh4 * 4);
  *(float4*)(out + g * 4) = val;
}

// ================= launcher =================
extern "C" void kernel_launch(void* const* d_in, const int* in_sizes, int n_in,
                              void* d_out, int out_size, void* d_ws, size_t ws_size,
                              hipStream_t stream) {
  (void)in_sizes; (void)n_in; (void)out_size; (void)ws_size;
  const float* x       = (const float*)d_in[0];
  const float* W_var   = (const float*)d_in[3];
  const float* b_var   = (const float*)d_in[4];
  const float* W_sym   = (const float*)d_in[5];
  const float* b_sym   = (const float*)d_in[6];
  const float* W_score = (const float*)d_in[7];
  const float* b_score = (const float*)d_in[8];
  const float* W_cross = (const float*)d_in[9];
  const float* b_cross = (const float*)d_in[10];
  const float* W_atom  = (const float*)d_in[11];
  const float* b_atom  = (const float*)d_in[12];
  const float* W_q     = (const float*)d_in[13];
  const float* b_q     = (const float*)d_in[14];
  const float* W_k     = (const float*)d_in[15];
  const float* b_k     = (const float*)d_in[16];
  const float* W_v     = (const float*)d_in[17];
  const float* b_v     = (const float*)d_in[18];
  const float* W_o     = (const float*)d_in[19];
  const float* b_o     = (const float*)d_in[20];
  const int*   pp      = (const int*)d_in[21];
  const int*   occ     = (const int*)d_in[24];
  float* out = (float*)d_out;
  char* wsb = (char*)d_ws;
  ushort* qb  = (ushort*)(wsb + OFFB_QB);
  ushort* kbf = (ushort*)(wsb + OFFB_KB);
  ushort* vtb = (ushort*)(wsb + OFFB_VB);
  ushort* xb  = (ushort*)(wsb + OFFB_XB);
  ushort* wqb = (ushort*)(wsb + OFFB_WQB);
  ushort* wkb = (ushort*)(wsb + OFFB_WKB);
  ushort* wvb = (ushort*)(wsb + OFFB_WVB);
  ushort* wvar = (ushort*)(wsb + OFFB_WVAR);
  ushort* wsym = (ushort*)(wsb + OFFB_WSYM);
  ushort* vrows = (ushort*)(wsb + OFFB_VROWS);
  float* sraw = (float*)(wsb + OFFB_SRAW);
  float* diag = (float*)(wsb + OFFB_DIAG);
  float4* bias4 = (float4*)(wsb + OFFB_BIAS4);
  int* plist = (int*)(wsb + OFFB_PLIST);
  int* pcnt  = (int*)(wsb + OFFB_PCNT);
  float* sumw = (float*)(wsb + OFFB_SUMW);
  float* zz   = (float*)(wsb + OFFB_ZZ);
  float* tv   = (float*)(wsb + OFFB_TV);
  float* pm   = (float*)(wsb + OFFB_PM);

  k_pred<<<BB, 64, 0, stream>>>(pp, plist, pcnt, sumw, sraw, diag, zz);
  // f32->bf16 (x + 5 weights) fused with occurrence-pair scores
  k_cvtall<<<NCVT + BB * MM / 4, 256, 0, stream>>>(
      x, W_q, W_k, W_v, W_var, W_sym, xb, wqb, wkb, wvb, wvar, wsym,
      occ, W_cross, b_cross, diag);
  // gather var_in rows (bf16, compact)
  k_gather<<<dim3(PRMAX / 4, BB), 256, 0, stream>>>(xb, pp, plist, pcnt, vrows);
  // fused QKV GEMM + score GEMM (independent, co-scheduled)
  k_mats<<<GEMM_BLKS + 576, 256, 0, stream>>>(
      xb, vrows, plist, pcnt, wvar, wsym, b_var, b_sym, W_score, sraw,
      wqb, wkb, wvb, b_q, b_k, b_v, qb, kbf, vtb);
  k_bias<<<BB * NN / 256, 256, 0, stream>>>(pp, sraw, diag, b_score, bias4);
  // MFMA flash attention (64 q-rows/block, 4 waves, 1536 blocks); grid x=(h,b) for XCD L2 reuse
  k_attn2<<<dim3(NHD * BB, NN / 64), 256, 0, stream>>>(qb, kbf, vtb, bias4, pp, zz);
  k_f1<<<dim3(24, BB), 256, 0, stream>>>(W_o, b_o, zz, sumw, tv);
  k_f2<<<dim3(24, BB), 256, 0, stream>>>(W_atom, b_atom, tv, pm);
  k_bcast<<<BB * NN * HH / 1024, 256, 0, stream>>>(pm, out);
}

// Round 13
// 149.157 us; speedup vs baseline: 9.4826x; 1.0583x over previous
//
#include <hip/hip_runtime.h>
#include <hip/hip_bf16.h>

// ================= problem constants =================
#define BB 8
#define NN 1024
#define HH 768
#define NHD 12
#define ASZ 64
#define MM 256
#define QSCALE 0.125f   // AS^-0.5
#define NSLOPE 0.02f
#define LOG2E 1.44269504f
#define PRMAX 384       // padded predicate rows per batch

typedef __attribute__((ext_vector_type(8))) short bf16x8;
typedef __attribute__((ext_vector_type(4))) float f32x4;

#define EXP2F(x) __builtin_amdgcn_exp2f(x)
#define RCPF(x)  __builtin_amdgcn_rcpf(x)

// ============ workspace layout (byte offsets, all 16B-aligned) ============
#define OFFB_QB    ((size_t)0)            // 8*1024*768 bf16
#define OFFB_KB    ((size_t)12582912)
#define OFFB_VB    ((size_t)25165824)     // V^T: [b][h][d][n] bf16
#define OFFB_XB    ((size_t)37748736)     // x in bf16
#define OFFB_WQB   ((size_t)50331648)     // 768*768 bf16
#define OFFB_WKB   ((size_t)51511296)
#define OFFB_WVB   ((size_t)52690944)
#define OFFB_WVAR  ((size_t)53870592)     // W_var bf16
#define OFFB_WSYM  ((size_t)55050240)     // W_sym bf16
#define OFFB_SRAW  ((size_t)56229888)     // 8192 f32
#define OFFB_DIAG  ((size_t)56262656)     // 8192 f32
#define OFFB_BIAS4 ((size_t)56295424)     // 8192 float4
#define OFFB_PLIST ((size_t)56426496)     // 8192 i32
#define OFFB_PCNT  ((size_t)56459264)
#define OFFB_SUMW  ((size_t)56459296)
#define OFFB_ZZ    ((size_t)56459328)     // 2*8*768 f32
#define OFFB_TV    ((size_t)56508480)
#define OFFB_PM    ((size_t)56557632)
#define OFFB_VROWS ((size_t)56582208)     // 8*384*768 bf16 gathered var rows

__device__ __forceinline__ float lrelu(float v) { return v >= 0.f ? v : NSLOPE * v; }

__device__ __forceinline__ ushort f2bf(float f) {  // round-half-up f32->bf16 (2 ops)
  return (ushort)((__float_as_uint(f) + 0x8000u) >> 16);
}
__device__ __forceinline__ float bf2f(ushort u) {
  union { unsigned u; float f; } v; v.u = (unsigned)u << 16;
  return v.f;
}
__device__ __forceinline__ unsigned packbf2(float lo, float hi) {  // (bf(hi)<<16)|bf(lo)
  unsigned a = __float_as_uint(hi) + 0x8000u;
  unsigned b = __float_as_uint(lo) + 0x8000u;
  return __builtin_amdgcn_perm(a, b, 0x07060302u);
}
__device__ __forceinline__ float fast_tanh(float x) {  // exp2-domain, saturates to +-1
  float e = EXP2F(x * (2.f * LOG2E));
  return 1.f - 2.f * RCPF(e + 1.f);
}

// weights for the final weighted row-sums of y (derived from pm algebra).
__device__ __forceinline__ void coefs(const int* ppb, int j, float& c1, float& c2) {
  auto pred = [&](int tt) { return tt >= 0 && tt < NN && ppb[tt] == 1; };
  auto single = [&](int tt) { return tt == 0 || (tt >= 2 && ppb[tt - 2] == 1); };
  auto wgt = [&](int tt) {
    if (!pred(tt)) return 0.f;
    bool tri = (tt >= 1) && (tt <= 1 || !single(tt));
    return tri ? 3.f : 2.f;
  };
  float a = 0.f;
  if (pred(j + 1)) a += wgt(j + 1) * (single(j + 1) ? 0.f : 0.5f);
  if (j >= 1 && pred(j - 1)) a += wgt(j - 1) * (single(j - 1) ? 1.f : 0.5f);
  c1 = a;
  c2 = wgt(j);
}

// ============ K_pred: compact predicate list + sum of weights + ws zeroing ============
__global__ void k_pred(const int* __restrict__ pp, int* __restrict__ plist,
                       int* __restrict__ pcnt, float* __restrict__ sumw,
                       float* __restrict__ sraw, float* __restrict__ diag,
                       float* __restrict__ zz) {
  int b = blockIdx.x;
  int lane = threadIdx.x;  // blockDim 64
  const int* ppb = pp + b * NN;
  int base = 0;
  float wacc = 0.f;
  for (int c = 0; c < NN; c += 64) {
    int i = c + lane;
    bool isp = ppb[i] == 1;
    unsigned long long mask = __ballot(isp);
    if (isp) {
      int pos = base + __popcll(mask & ((1ull << lane) - 1ull));
      plist[b * NN + pos] = i;
      bool sing = (i == 0) || (i >= 2 && ppb[i - 2] == 1);
      bool tri = (i >= 1) && (i <= 1 || !sing);
      wacc += tri ? 3.f : 2.f;
    }
    base += __popcll(mask);
  }
  for (int off = 32; off; off >>= 1) wacc += __shfl_xor(wacc, off);
  if (lane == 0) { pcnt[b] = base; sumw[b] = wacc; }
  for (int c = lane; c < NN; c += 64) { sraw[b * NN + c] = 0.f; diag[b * NN + c] = 0.f; }
  for (int c = lane; c < HH; c += 64) {
    zz[b * HH + c] = 0.f;
    zz[BB * HH + b * HH + c] = 0.f;
  }
}

// ============ K_cvtall: x + 5 weights f32->bf16, plus cross scores ============
#define NXQ (BB * NN * HH / 4)      // 1572864
#define WQ  (HH * HH / 4)           // 147456
#define NCVT ((NXQ + 5 * WQ) / 256) // 9024
__global__ void k_cvtall(const float* __restrict__ x,
                         const float* __restrict__ s1, const float* __restrict__ s2,
                         const float* __restrict__ s3, const float* __restrict__ s4,
                         const float* __restrict__ s5,
                         ushort* __restrict__ dx,
                         ushort* __restrict__ d1, ushort* __restrict__ d2,
                         ushort* __restrict__ d3, ushort* __restrict__ d4,
                         ushort* __restrict__ d5,
                         const int* __restrict__ occ, const float* __restrict__ Wc,
                         const float* __restrict__ bc, float* __restrict__ diag) {
  if (blockIdx.x < NCVT) {
    int idx = blockIdx.x * 256 + threadIdx.x;
    const float* src; ushort* dst; int off;
    if (idx < NXQ) { src = x; dst = dx; off = idx; }
    else {
      int r = idx - NXQ;
      int z = r / WQ;
      off = r - z * WQ;
      src = z == 0 ? s1 : z == 1 ? s2 : z == 2 ? s3 : z == 3 ? s4 : s5;
      dst = z == 0 ? d1 : z == 1 ? d2 : z == 2 ? d3 : z == 3 ? d4 : d5;
    }
    float4 v = ((const float4*)src)[off];
    ushort4 o;
    o.x = f2bf(v.x); o.y = f2bf(v.y); o.z = f2bf(v.z); o.w = f2bf(v.w);
    ((ushort4*)dst)[off] = o;
  } else {
    int g = (blockIdx.x - NCVT) * 4 + (threadIdx.x >> 6);
    int lane = threadIdx.x & 63;
    int b = g >> 8, m = g & (MM - 1);
    int o0 = occ[(b * MM + m) * 2 + 0];
    int o1 = occ[(b * MM + m) * 2 + 1];
    const float* x0 = x + (size_t)(b * NN + o0) * HH;
    const float* x1 = x + (size_t)(b * NN + o1) * HH;
    float acc = 0.f;
    for (int d = lane; d < HH; d += 64) acc += 0.5f * (x0[d] + x1[d]) * Wc[d];
    for (int off = 32; off; off >>= 1) acc += __shfl_xor(acc, off);
    if (lane == 0) {
      float sc = lrelu(acc + bc[0]);
      float sq = sc * sc;
      diag[b * NN + o0] = sq;
      diag[b * NN + o1] = sq;
    }
  }
}

// ============ K_gather: compact var_in rows (bf16) for the score GEMM ============
__global__ void k_gather(const ushort* __restrict__ xb, const int* __restrict__ pp,
                         const int* __restrict__ plist, const int* __restrict__ pcnt,
                         ushort* __restrict__ vrows) {
  int b = blockIdx.y;
  int j = blockIdx.x * 4 + (threadIdx.x >> 6);
  int lane = threadIdx.x & 63;
  if (j >= pcnt[b]) return;
  int i = plist[b * NN + j];
  bool sing = (i == 0) || (i >= 2 && pp[b * NN + i - 2] == 1);
  float wa = sing ? 0.f : 0.5f, wb = sing ? 1.f : 0.5f;
  const ushort* rp = xb + (size_t)(b * NN + ((i - 1) & (NN - 1))) * HH;
  const ushort* rn = xb + (size_t)(b * NN + ((i + 1) & (NN - 1))) * HH;
  ushort* dst = vrows + ((size_t)b * PRMAX + j) * HH;
#pragma unroll
  for (int it = 0; it < 3; ++it) {
    int d4 = lane + it * 64;
    ushort4 p4 = ((const ushort4*)rp)[d4];
    ushort4 n4 = ((const ushort4*)rn)[d4];
    ushort4 o;
    o.x = f2bf(wa * bf2f(p4.x) + wb * bf2f(n4.x));
    o.y = f2bf(wa * bf2f(p4.y) + wb * bf2f(n4.y));
    o.z = f2bf(wa * bf2f(p4.z) + wb * bf2f(n4.z));
    o.w = f2bf(wa * bf2f(p4.w) + wb * bf2f(n4.w));
    ((ushort4*)dst)[d4] = o;
  }
}

// ============ K_bias: per-row sparse bias window (log2e-scaled for exp2 softmax) ============
__global__ void k_bias(const int* __restrict__ pp, const float* __restrict__ s_raw,
                       const float* __restrict__ diag, const float* __restrict__ b_score,
                       float4* __restrict__ bias4) {
  int g = blockIdx.x * 256 + threadIdx.x;
  int b = g >> 10, r = g & (NN - 1);
  const int* ppb = pp + b * NN;
  int i = -1;
  if (ppb[r] == 1) i = r;
  else if (r + 1 < NN && ppb[r + 1] == 1) i = r + 1;
  else if (r >= 1 && ppb[r - 1] == 1) i = r - 1;
  float v0 = 0.f, v1 = 0.f, v2 = 0.f; int cw = r;
  if (i >= 1 && i + 1 < NN) {
    float s = lrelu(s_raw[b * NN + i] + b_score[0]);
    float s2 = s * s;
    cw = i - 1;
    if (i == r) { v0 = 0.2f * s; v1 = 1.6f * s2; v2 = 0.2f * s; }
    else       { v0 = 0.8f * s2; v1 = 0.2f * s; v2 = 0.8f * s2; }
  }
  int slot = r - cw;
  float d = diag[g];
  if (slot == 0) v0 += d; else if (slot == 1) v1 += d; else v2 += d;
  bias4[g] = make_float4(__int_as_float(cw), v0 * LOG2E, v1 * LOG2E, v2 * LOG2E);
}

// ============ K_mats: fused {QKV GEMM (1152 blocks)} + {score GEMM (576 blocks)} ============
#define GEMM_BLKS 1152
__global__ __launch_bounds__(256, 2) void k_mats(
    const ushort* __restrict__ X, const ushort* __restrict__ vrows,
    const int* __restrict__ plist, const int* __restrict__ pcnt,
    const ushort* __restrict__ Wvar, const ushort* __restrict__ Wsym,
    const float* __restrict__ bvar, const float* __restrict__ bsym,
    const float* __restrict__ wscore, float* __restrict__ s_raw,
    const ushort* __restrict__ W0, const ushort* __restrict__ W1, const ushort* __restrict__ W2,
    const float* __restrict__ b0, const float* __restrict__ b1, const float* __restrict__ b2,
    ushort* __restrict__ C0, ushort* __restrict__ C1, ushort* __restrict__ C2) {
  __shared__ ushort Sm[16384];   // 32 KB carve
  __shared__ int pl[64];
  __shared__ float red[64];
  const int t = threadIdx.x;
  const int w = t >> 6, lane = t & 63, lg = lane >> 4, lm = lane & 15;
  const int r0 = t >> 3, c = t & 7;
  const int ssw = (c ^ (r0 & 7)) * 8;
  if (blockIdx.x < GEMM_BLKS) {
    // ---------------- QKV GEMM path ----------------
    const int z = blockIdx.x / 384;
    const int r = blockIdx.x % 384;
    const int m0 = (r & 63) * 128, n0 = (r >> 6) * 128;
    const ushort* W = z == 0 ? W0 : (z == 1 ? W1 : W2);
    const float* bias = z == 0 ? b0 : (z == 1 ? b1 : b2);
    ushort* C = z == 0 ? C0 : (z == 1 ? C1 : C2);
    const float alpha = z == 0 ? QSCALE * LOG2E : 1.f;
    ushort* As = Sm;
    ushort* Bs = Sm + 8192;
    const int wm = (w >> 1) * 64, wn = (w & 1) * 64;
    const ushort* Xp = X + (size_t)(m0 + r0) * HH + c * 8;
    const ushort* Wp = W + (size_t)(n0 + r0) * HH + c * 8;
    uint4 xa0 = *(const uint4*)Xp;
    uint4 xa1 = *(const uint4*)(Xp + (size_t)32 * HH);
    uint4 xa2 = *(const uint4*)(Xp + (size_t)64 * HH);
    uint4 xa3 = *(const uint4*)(Xp + (size_t)96 * HH);
    uint4 wb0 = *(const uint4*)Wp;
    uint4 wb1 = *(const uint4*)(Wp + (size_t)32 * HH);
    uint4 wb2 = *(const uint4*)(Wp + (size_t)64 * HH);
    uint4 wb3 = *(const uint4*)(Wp + (size_t)96 * HH);
    f32x4 acc[4][4] = {};
    for (int k0 = 0; k0 < HH; k0 += 64) {
      if (k0) __syncthreads();
      *(uint4*)&As[r0 * 64 + ssw] = xa0;
      *(uint4*)&As[(r0 + 32) * 64 + ssw] = xa1;
      *(uint4*)&As[(r0 + 64) * 64 + ssw] = xa2;
      *(uint4*)&As[(r0 + 96) * 64 + ssw] = xa3;
      *(uint4*)&Bs[r0 * 64 + ssw] = wb0;
      *(uint4*)&Bs[(r0 + 32) * 64 + ssw] = wb1;
      *(uint4*)&Bs[(r0 + 64) * 64 + ssw] = wb2;
      *(uint4*)&Bs[(r0 + 96) * 64 + ssw] = wb3;
      __syncthreads();
      if (k0 + 64 < HH) {
        Xp += 64; Wp += 64;
        xa0 = *(const uint4*)Xp;
        xa1 = *(const uint4*)(Xp + (size_t)32 * HH);
        xa2 = *(const uint4*)(Xp + (size_t)64 * HH);
        xa3 = *(const uint4*)(Xp + (size_t)96 * HH);
        wb0 = *(const uint4*)Wp;
        wb1 = *(const uint4*)(Wp + (size_t)32 * HH);
        wb2 = *(const uint4*)(Wp + (size_t)64 * HH);
        wb3 = *(const uint4*)(Wp + (size_t)96 * HH);
      }
      bf16x8 af[4][2], bfr[4][2];
#pragma unroll
      for (int mt = 0; mt < 4; ++mt)
#pragma unroll
        for (int kt = 0; kt < 2; ++kt) {
          int row = wm + mt * 16 + lm, ch = lg + kt * 4;
          af[mt][kt] = *(bf16x8*)&As[row * 64 + ((ch ^ (row & 7)) * 8)];
        }
#pragma unroll
      for (int nt = 0; nt < 4; ++nt)
#pragma unroll
        for (int kt = 0; kt < 2; ++kt) {
          int row = wn + nt * 16 + lm, ch = lg + kt * 4;
          bfr[nt][kt] = *(bf16x8*)&Bs[row * 64 + ((ch ^ (row & 7)) * 8)];
        }
#pragma unroll
      for (int mt = 0; mt < 4; ++mt)
#pragma unroll
        for (int nt = 0; nt < 4; ++nt)
#pragma unroll
          for (int kt = 0; kt < 2; ++kt)
            acc[mt][nt] = __builtin_amdgcn_mfma_f32_16x16x32_bf16(af[mt][kt], bfr[nt][kt], acc[mt][nt], 0, 0, 0);
    }
    if (z == 2) {
#pragma unroll
      for (int nt = 0; nt < 4; ++nt) {
        int col = n0 + wn + nt * 16 + lm;
        int hh = col >> 6, dd = col & 63;
        float bcol = bias[col];
#pragma unroll
        for (int mt = 0; mt < 4; ++mt) {
          int row0 = m0 + wm + mt * 16 + lg * 4;
          int bb2 = row0 >> 10, nr = row0 & (NN - 1);
          ushort4 o;
          o.x = f2bf(acc[mt][nt][0] + bcol);
          o.y = f2bf(acc[mt][nt][1] + bcol);
          o.z = f2bf(acc[mt][nt][2] + bcol);
          o.w = f2bf(acc[mt][nt][3] + bcol);
          *(ushort4*)(C + ((size_t)(bb2 * NHD + hh) * ASZ + dd) * NN + nr) = o;
        }
      }
    } else {
#pragma unroll
      for (int nt = 0; nt < 4; ++nt) {
        int col = n0 + wn + nt * 16 + lm;
        float bcol = bias[col];
#pragma unroll
        for (int mt = 0; mt < 4; ++mt)
#pragma unroll
          for (int rr = 0; rr < 4; ++rr) {
            int row = m0 + wm + mt * 16 + lg * 4 + rr;
            C[(size_t)row * HH + col] = f2bf((acc[mt][nt][rr] + bcol) * alpha);
          }
      }
    }
  } else {
    // ---------------- score GEMM path ----------------
    const int bid2 = blockIdx.x - GEMM_BLKS;
    const int b = bid2 / 72;
    const int rem = bid2 % 72;
    const int j0 = (rem / 12) * 64;
    const int n0g = (rem % 12) * 128;
    const int cnt = pcnt[b];
    if (j0 >= cnt) return;
    const bool symh = n0g >= HH;
    const int n0 = symh ? n0g - HH : n0g;
    const ushort* W = symh ? Wsym : Wvar;
    const float* bias = symh ? bsym : bvar;
    ushort* As = Sm;           // 64*64
    ushort* Bs = Sm + 4096;    // 128*64
    const int wm = (w >> 1) * 32, wn = (w & 1) * 64;
    if (t < 64) {
      int j = j0 + t;
      pl[t] = (j < cnt) ? plist[b * NN + j] : 2;
      red[t] = 0.f;
    }
    __syncthreads();
    const ushort* ap0; const ushort* ap1;
    if (symh) {
      const ushort* xbb = X + (size_t)b * NN * HH;
      ap0 = xbb + (size_t)pl[r0] * HH + c * 8;
      ap1 = xbb + (size_t)pl[r0 + 32] * HH + c * 8;
    } else {
      const ushort* vrb = vrows + ((size_t)b * PRMAX + j0) * HH;
      ap0 = vrb + (size_t)r0 * HH + c * 8;
      ap1 = vrb + (size_t)(r0 + 32) * HH + c * 8;
    }
    const ushort* bp = W + (size_t)(n0 + r0) * HH + c * 8;
    uint4 ar0 = *(const uint4*)ap0;
    uint4 ar1 = *(const uint4*)ap1;
    uint4 br0 = *(const uint4*)bp;
    uint4 br1 = *(const uint4*)(bp + (size_t)32 * HH);
    uint4 br2 = *(const uint4*)(bp + (size_t)64 * HH);
    uint4 br3 = *(const uint4*)(bp + (size_t)96 * HH);
    f32x4 acc[2][4] = {};
    for (int k0 = 0; k0 < HH; k0 += 64) {
      if (k0) __syncthreads();
      *(uint4*)&As[r0 * 64 + ssw] = ar0;
      *(uint4*)&As[(r0 + 32) * 64 + ssw] = ar1;
      *(uint4*)&Bs[r0 * 64 + ssw] = br0;
      *(uint4*)&Bs[(r0 + 32) * 64 + ssw] = br1;
      *(uint4*)&Bs[(r0 + 64) * 64 + ssw] = br2;
      *(uint4*)&Bs[(r0 + 96) * 64 + ssw] = br3;
      __syncthreads();
      if (k0 + 64 < HH) {
        ap0 += 64; ap1 += 64; bp += 64;
        ar0 = *(const uint4*)ap0;
        ar1 = *(const uint4*)ap1;
        br0 = *(const uint4*)bp;
        br1 = *(const uint4*)(bp + (size_t)32 * HH);
        br2 = *(const uint4*)(bp + (size_t)64 * HH);
        br3 = *(const uint4*)(bp + (size_t)96 * HH);
      }
      bf16x8 af[2][2], bfr[4][2];
#pragma unroll
      for (int mt = 0; mt < 2; ++mt)
#pragma unroll
        for (int kt = 0; kt < 2; ++kt) {
          int row = wm + mt * 16 + lm, ch = lg + kt * 4;
          af[mt][kt] = *(bf16x8*)&As[row * 64 + ((ch ^ (row & 7)) * 8)];
        }
#pragma unroll
      for (int nt = 0; nt < 4; ++nt)
#pragma unroll
        for (int kt = 0; kt < 2; ++kt) {
          int row = wn + nt * 16 + lm, ch = lg + kt * 4;
          bfr[nt][kt] = *(bf16x8*)&Bs[row * 64 + ((ch ^ (row & 7)) * 8)];
        }
#pragma unroll
      for (int mt = 0; mt < 2; ++mt)
#pragma unroll
        for (int nt = 0; nt < 4; ++nt)
#pragma unroll
          for (int kt = 0; kt < 2; ++kt)
            acc[mt][nt] = __builtin_amdgcn_mfma_f32_16x16x32_bf16(af[mt][kt], bfr[nt][kt], acc[mt][nt], 0, 0, 0);
    }
    float bcol[4], wcol[4];
#pragma unroll
    for (int nt = 0; nt < 4; ++nt) {
      int cl = wn + nt * 16 + lm;
      bcol[nt] = bias[n0 + cl];
      wcol[nt] = wscore[n0g + cl];
    }
#pragma unroll
    for (int mt = 0; mt < 2; ++mt)
#pragma unroll
      for (int rr = 0; rr < 4; ++rr) {
        float p = 0.f;
#pragma unroll
        for (int nt = 0; nt < 4; ++nt)
          p += fast_tanh(acc[mt][nt][rr] + bcol[nt]) * wcol[nt];
        p += __shfl_xor(p, 1); p += __shfl_xor(p, 2);
        p += __shfl_xor(p, 4); p += __shfl_xor(p, 8);
        if (lm == 0) atomicAdd(&red[wm + mt * 16 + lg * 4 + rr], p);
      }
    __syncthreads();
    if (t < 64) {
      int j2 = j0 + t;
      if (j2 < cnt) atomicAdd(&s_raw[b * NN + pl[t]], red[t]);
    }
  }
}

// ============ K_attn2: swapped-QK^T no-max flash attention ============
// 4 waves x 16 q-rows (64 q/block); KVBLK=64; exp2 domain with NO max subtraction
// (logits bounded ~|10| -> no overflow/underflow; y/l division normalizes exactly).
// Zero cross-lane ops in the K-loop; l reduced once in epilogue.
__global__ __launch_bounds__(256, 4) void k_attn2(
    const ushort* __restrict__ qg, const ushort* __restrict__ kg, const ushort* __restrict__ vtg,
    const float4* __restrict__ bias4, const int* __restrict__ pp, float* __restrict__ zz) {
  __shared__ ushort Ks[64 * 64];
  __shared__ ushort Vts[64 * 64];
  const int rb = blockIdx.y, h = blockIdx.x >> 3, b = blockIdx.x & 7;
  const int n0 = rb * 64;
  const int t = threadIdx.x, w = t >> 6, lane = t & 63, lg = lane >> 4, lm = lane & 15;
  const int qbase = n0 + w * 16;
  const ushort* qrow = qg + (size_t)(b * NN + qbase + lm) * HH + h * ASZ;
  bf16x8 qf[2];
  qf[0] = *(const bf16x8*)(qrow + lg * 8);
  qf[1] = *(const bf16x8*)(qrow + lg * 8 + 32);
  float4 bz = bias4[b * NN + qbase + lm];
  const int cwq = __float_as_int(bz.x);
  f32x4 suml = {0.f, 0.f, 0.f, 0.f};   // per-lane partial l (reduced in epilogue)
  f32x4 y[4] = {};
  const ushort* kb = kg + (size_t)(b * NN) * HH + h * ASZ;
  const ushort* vtb = vtg + (size_t)(b * NHD + h) * ASZ * NN;
  const int srow = t >> 3, sc = t & 7;
  const int arow = (srow & 35) | ((srow & 4) << 2) | ((srow & 24) >> 1);  // 6-bit perm
  const int kssw = (sc ^ (arow & 7)) * 8;
  const int vssw = (sc ^ (srow & 7)) * 8;
  const ushort* kptr = kb + (size_t)srow * HH + sc * 8;
  const ushort* vptr = vtb + (size_t)srow * NN + sc * 8;
  uint4 ka = *(const uint4*)kptr;
  uint4 kc = *(const uint4*)(kptr + (size_t)32 * HH);
  uint4 va = *(const uint4*)vptr;
  uint4 vb2 = *(const uint4*)(vptr + (size_t)32 * NN);
  for (int tile = 0; tile < 16; ++tile) {
    const int c0 = tile * 64;
    *(uint4*)&Ks[arow * 64 + kssw] = ka;
    *(uint4*)&Ks[(arow + 32) * 64 + kssw] = kc;
    *(uint4*)&Vts[srow * 64 + vssw] = va;
    *(uint4*)&Vts[(srow + 32) * 64 + vssw] = vb2;
    __syncthreads();
    if (tile < 15) {   // prefetch next tile into registers
      kptr += (size_t)64 * HH; vptr += 64;
      ka = *(const uint4*)kptr;
      kc = *(const uint4*)(kptr + (size_t)32 * HH);
      va = *(const uint4*)vptr;
      vb2 = *(const uint4*)(vptr + (size_t)32 * NN);
    }
    f32x4 s[4] = {};
    __builtin_amdgcn_s_setprio(1);
#pragma unroll
    for (int nt = 0; nt < 4; ++nt) {
      int krow = lm + nt * 16, sw = krow & 7;
#pragma unroll
      for (int kt = 0; kt < 2; ++kt) {
        bf16x8 kf = *(bf16x8*)&Ks[krow * 64 + (((lg + kt * 4) ^ sw) * 8)];
        s[nt] = __builtin_amdgcn_mfma_f32_16x16x32_bf16(kf, qf[kt], s[nt], 0, 0, 0);
      }
    }
    __builtin_amdgcn_s_setprio(0);
    // sparse bias: token of s[nt][r] = c0 + (nt>>1)*32 + lg*8 + (nt&1)*4 + r
    if (c0 <= qbase + 17 && qbase <= c0 + 65) {
#pragma unroll
      for (int nt = 0; nt < 4; ++nt) {
        int kb2 = c0 + (nt >> 1) * 32 + lg * 8 + (nt & 1) * 4;
#pragma unroll
        for (int r = 0; r < 4; ++r) {
          int dd = kb2 + r - cwq;
          if (dd >= 0 && dd < 3) s[nt][r] += (dd == 0) ? bz.y : (dd == 1 ? bz.z : bz.w);
        }
      }
    }
    // no-max exp: p = 2^s directly (bounded logits); accumulate per-lane l
#pragma unroll
    for (int nt = 0; nt < 4; ++nt)
#pragma unroll
      for (int e = 0; e < 4; ++e) {
        float p = EXP2F(s[nt][e]);
        s[nt][e] = p;
        suml[e] += p;
      }
    // pack P into PV A-frags via v_perm (register-local)
    union { unsigned u[4]; bf16x8 v; } pk[2];
#pragma unroll
    for (int kt = 0; kt < 2; ++kt) {
      pk[kt].u[0] = packbf2(s[2 * kt][0], s[2 * kt][1]);
      pk[kt].u[1] = packbf2(s[2 * kt][2], s[2 * kt][3]);
      pk[kt].u[2] = packbf2(s[2 * kt + 1][0], s[2 * kt + 1][1]);
      pk[kt].u[3] = packbf2(s[2 * kt + 1][2], s[2 * kt + 1][3]);
    }
    __builtin_amdgcn_s_setprio(1);
#pragma unroll
    for (int nt = 0; nt < 4; ++nt) {
      int vrow = lm + nt * 16, sw = vrow & 7;
#pragma unroll
      for (int kt = 0; kt < 2; ++kt) {
        bf16x8 vf = *(bf16x8*)&Vts[vrow * 64 + (((lg + kt * 4) ^ sw) * 8)];
        y[nt] = __builtin_amdgcn_mfma_f32_16x16x32_bf16(pk[kt].v, vf, y[nt], 0, 0, 0);
      }
    }
    __builtin_amdgcn_s_setprio(0);
    __syncthreads();
  }
  // epilogue: reduce l once, then weighted row-sums into z1/z2
  float ts = (suml[0] + suml[1]) + (suml[2] + suml[3]);
  ts += __shfl_xor(ts, 16);
  ts += __shfl_xor(ts, 32);
  float invl = 1.f / ts;                 // l for q = qbase+lm
  float invq[4], c1v[4], c2v[4];
#pragma unroll
  for (int r = 0; r < 4; ++r) {
    invq[r] = __shfl(invl, lg * 4 + r);
    coefs(pp + b * NN, qbase + lg * 4 + r, c1v[r], c2v[r]);
  }
  float a1[4], a2[4];
#pragma unroll
  for (int nt = 0; nt < 4; ++nt) {
    float u1 = 0.f, u2 = 0.f;
#pragma unroll
    for (int r = 0; r < 4; ++r) {
      float yv = y[nt][r] * invq[r];
      u1 += c1v[r] * yv;
      u2 += c2v[r] * yv;
    }
    u1 += __shfl_xor(u1, 16); u1 += __shfl_xor(u1, 32);
    u2 += __shfl_xor(u2, 16); u2 += __shfl_xor(u2, 32);
    a1[nt] = u1; a2[nt] = u2;
  }
  if (lg == 0) {
#pragma unroll
    for (int nt = 0; nt < 4; ++nt) {
      atomicAdd(&zz[b * HH + h * ASZ + nt * 16 + lm], a1[nt]);
      atomicAdd(&zz[BB * HH + b * HH + h * ASZ + nt * 16 + lm], a2[nt]);
    }
  }
}

// ============ F1: t_s = W_o @ (z_s / sumw) + b_o ============
__global__ void k_f1(const float* __restrict__ Wo, const float* __restrict__ bo,
                     const float* __restrict__ zz, const float* __restrict__ sumw,
                     float* __restrict__ tvec) {
  int b = blockIdx.y;
  int w = threadIdx.x >> 6, lane = threadIdx.x & 63;
  float inv = 1.f / sumw[b];
  const float* z1 = zz + b * HH;
  const float* z2 = zz + BB * HH + b * HH;
  float zr1[12], zr2[12];
#pragma unroll
  for (int m = 0; m < 12; ++m) { zr1[m] = z1[lane + 64 * m] * inv; zr2[m] = z2[lane + 64 * m] * inv; }
  for (int j = 0; j < 8; ++j) {
    int o = blockIdx.x * 32 + w * 8 + j;
    const float* wrow = Wo + (size_t)o * HH;
    float a1 = 0.f, a2 = 0.f;
#pragma unroll
    for (int m = 0; m < 12; ++m) { float wv = wrow[lane + 64 * m]; a1 += wv * zr1[m]; a2 += wv * zr2[m]; }
    for (int mask = 32; mask; mask >>= 1) { a1 += __shfl_xor(a1, mask); a2 += __shfl_xor(a2, mask); }
    if (lane == 0) { tvec[b * HH + o] = a1 + bo[o]; tvec[BB * HH + b * HH + o] = a2 + bo[o]; }
  }
}

// ============ F2: pm = WL @ t1 + WR @ t2 + b_atom ============
__global__ void k_f2(const float* __restrict__ Wa, const float* __restrict__ ba,
                     const float* __restrict__ tvec, float* __restrict__ pm) {
  int b = blockIdx.y;
  int w = threadIdx.x >> 6, lane = threadIdx.x & 63;
  const float* t1 = tvec + b * HH;
  const float* t2 = tvec + BB * HH + b * HH;
  float r1[12], r2[12];
#pragma unroll
  for (int m = 0; m < 12; ++m) { r1[m] = t1[lane + 64 * m]; r2[m] = t2[lane + 64 * m]; }
  for (int j = 0; j < 8; ++j) {
    int o = blockIdx.x * 32 + w * 8 + j;
    const float* wrow = Wa + (size_t)o * (2 * HH);
    float a = 0.f;
#pragma unroll
    for (int m = 0; m < 12; ++m) a += wrow[lane + 64 * m] * r1[m];
#pragma unroll
    for (int m = 0; m < 12; ++m) a += wrow[HH + lane + 64 * m] * r2[m];
    for (int mask = 32; mask; mask >>= 1) a += __shfl_xor(a, mask);
    if (lane == 0) pm[b * HH + o] = a + ba[o];
  }
}

// ============ F3: broadcast pm to (B,N,H) ============
__global__ void k_bcast(const float* __restrict__ pm, float* __restrict__ out) {
  size_t g = (size_t)blockIdx.x * 256 + threadIdx.x;
  int b = (int)(g / ((size_t)NN * HH / 4));
  int hh4 = (int)(g % (HH / 4));
  float4 val = *(const float4*)(pm + b * HH + hh4 * 4);
  *(float4*)(out + g * 4) = val;
}

// ================= launcher =================
extern "C" void kernel_launch(void* const* d_in, const int* in_sizes, int n_in,
                              void* d_out, int out_size, void* d_ws, size_t ws_size,
                              hipStream_t stream) {
  (void)in_sizes; (void)n_in; (void)out_size; (void)ws_size;
  const float* x       = (const float*)d_in[0];
  const float* W_var   = (const float*)d_in[3];
  const float* b_var   = (const float*)d_in[4];
  const float* W_sym   = (const float*)d_in[5];
  const float* b_sym   = (const float*)d_in[6];
  const float* W_score = (const float*)d_in[7];
  const float* b_score = (const float*)d_in[8];
  const float* W_cross = (const float*)d_in[9];
  const float* b_cross = (const float*)d_in[10];
  const float* W_atom  = (const float*)d_in[11];
  const float* b_atom  = (const float*)d_in[12];
  const float* W_q     = (const float*)d_in[13];
  const float* b_q     = (const float*)d_in[14];
  const float* W_k     = (const float*)d_in[15];
  const float* b_k     = (const float*)d_in[16];
  const float* W_v     = (const float*)d_in[17];
  const float* b_v     = (const float*)d_in[18];
  const float* W_o     = (const float*)d_in[19];
  const float* b_o     = (const float*)d_in[20];
  const int*   pp      = (const int*)d_in[21];
  const int*   occ     = (const int*)d_in[24];
  float* out = (float*)d_out;
  char* wsb = (char*)d_ws;
  ushort* qb  = (ushort*)(wsb + OFFB_QB);
  ushort* kbf = (ushort*)(wsb + OFFB_KB);
  ushort* vtb = (ushort*)(wsb + OFFB_VB);
  ushort* xb  = (ushort*)(wsb + OFFB_XB);
  ushort* wqb = (ushort*)(wsb + OFFB_WQB);
  ushort* wkb = (ushort*)(wsb + OFFB_WKB);
  ushort* wvb = (ushort*)(wsb + OFFB_WVB);
  ushort* wvar = (ushort*)(wsb + OFFB_WVAR);
  ushort* wsym = (ushort*)(wsb + OFFB_WSYM);
  ushort* vrows = (ushort*)(wsb + OFFB_VROWS);
  float* sraw = (float*)(wsb + OFFB_SRAW);
  float* diag = (float*)(wsb + OFFB_DIAG);
  float4* bias4 = (float4*)(wsb + OFFB_BIAS4);
  int* plist = (int*)(wsb + OFFB_PLIST);
  int* pcnt  = (int*)(wsb + OFFB_PCNT);
  float* sumw = (float*)(wsb + OFFB_SUMW);
  float* zz   = (float*)(wsb + OFFB_ZZ);
  float* tv   = (float*)(wsb + OFFB_TV);
  float* pm   = (float*)(wsb + OFFB_PM);

  k_pred<<<BB, 64, 0, stream>>>(pp, plist, pcnt, sumw, sraw, diag, zz);
  // f32->bf16 (x + 5 weights) fused with occurrence-pair scores
  k_cvtall<<<NCVT + BB * MM / 4, 256, 0, stream>>>(
      x, W_q, W_k, W_v, W_var, W_sym, xb, wqb, wkb, wvb, wvar, wsym,
      occ, W_cross, b_cross, diag);
  // gather var_in rows (bf16, compact)
  k_gather<<<dim3(PRMAX / 4, BB), 256, 0, stream>>>(xb, pp, plist, pcnt, vrows);
  // fused QKV GEMM + score GEMM (independent, co-scheduled)
  k_mats<<<GEMM_BLKS + 576, 256, 0, stream>>>(
      xb, vrows, plist, pcnt, wvar, wsym, b_var, b_sym, W_score, sraw,
      wqb, wkb, wvb, b_q, b_k, b_v, qb, kbf, vtb);
  k_bias<<<BB * NN / 256, 256, 0, stream>>>(pp, sraw, diag, b_score, bias4);
  // MFMA flash attention (64 q-rows/block, 4 waves, no-max exp2 softmax)
  k_attn2<<<dim3(NHD * BB, NN / 64), 256, 0, stream>>>(qb, kbf, vtb, bias4, pp, zz);
  k_f1<<<dim3(24, BB), 256, 0, stream>>>(W_o, b_o, zz, sumw, tv);
  k_f2<<<dim3(24, BB), 256, 0, stream>>>(W_atom, b_atom, tv, pm);
  k_bcast<<<BB * NN * HH / 1024, 256, 0, stream>>>(pm, out);
}